// Round 9
// baseline (279.214 us; speedup 1.0000x reference)
//
#include <hip/hip_runtime.h>
#include <math.h>

#define B_   2
#define S_   4096
#define HID_ 768
#define H_   12
#define D_   64
#define M_   64
#define CK_  33
#define BH_  (B_*H_)   // 24
#define KD_  768
#define NCH_ 32        // k3v S-chunks
#define SC_  128       // keys per chunk

typedef float  f32x4  __attribute__((ext_vector_type(4)));
typedef _Float16 f16x8 __attribute__((ext_vector_type(8)));
typedef unsigned short u16;

__device__ __forceinline__ u16 f2h_bits(float f) {
  union { _Float16 h; u16 u; } c; c.h = (_Float16)f; return c.u;
}
__device__ __forceinline__ float h2f(u16 b) {
  union { _Float16 h; u16 u; } c; c.u = b; return (float)c.h;
}
// two float4 -> f16x8 hi + f16x8 lo residual
__device__ __forceinline__ void cvt8_hl(const float4 a, const float4 b,
                                        f16x8* hi, f16x8* lo) {
  const float v[8] = {a.x, a.y, a.z, a.w, b.x, b.y, b.z, b.w};
  f16x8 H, L;
#pragma unroll
  for (int e = 0; e < 8; ++e) {
    const _Float16 hh = (_Float16)v[e];
    H[e] = hh;
    L[e] = (_Float16)(v[e] - (float)hh);
  }
  *hi = H; *lo = L;
}

__device__ __forceinline__ void gld16(const void* g, void* l) {
  __builtin_amdgcn_global_load_lds(
      (const __attribute__((address_space(1))) void*)g,
      (__attribute__((address_space(3))) void*)l, 16, 0, 0);
}

// =============================================================
// Downcast: x -> Xh, qkv_w -> Wqh, out_w -> Woh (fp16 hi only)
// =============================================================
#define N8X  786432
#define N8WQ 221184
#define N8WO 73728
__global__ __launch_bounds__(256) void split3(
    const float* __restrict__ x, const float* __restrict__ qkv_w,
    const float* __restrict__ out_w,
    u16* __restrict__ Xh, u16* __restrict__ Wqh, u16* __restrict__ Woh)
{
  const int i = blockIdx.x * 256 + threadIdx.x;
  const float* src; u16* dst; int j;
  if (i < N8X)                 { src = x;     dst = Xh;  j = i; }
  else if (i < N8X + N8WQ)     { src = qkv_w; dst = Wqh; j = i - N8X; }
  else if (i < N8X + N8WQ + N8WO) { src = out_w; dst = Woh; j = i - N8X - N8WQ; }
  else return;
  const float4 a = ((const float4*)src)[2 * j], b = ((const float4*)src)[2 * j + 1];
  const float v[8] = {a.x, a.y, a.z, a.w, b.x, b.y, b.z, b.w};
  union { u16 u[8]; uint4 q; } hv;
#pragma unroll
  for (int e = 0; e < 8; ++e) hv.u[e] = f2h_bits(v[e]);
  ((uint4*)dst)[j] = hv.q;
}

// =============================================================
// fp16 MFMA GEMM: C = A @ W^T (+bias)
// PROD=1: C = ah.bh.  PROD=2: C = ah.bh + al.bh.
// MODE 0: scatter Q/K/V as fp16 [B,H,S,D], fused landmark means
//         (Ql,Kl f32 + Klh fp16).  MODE 1: row-major f32 out.
// =============================================================
template<int MODE, int PROD>
__global__ __launch_bounds__(256) void gemm_mfma(
    const u16* __restrict__ Ahg, const u16* __restrict__ Alg,
    const u16* __restrict__ Bhg,
    const float* __restrict__ bias,
    float* __restrict__ oF, u16* __restrict__ oQ, u16* __restrict__ oK,
    u16* __restrict__ oV,
    float* __restrict__ Ql, float* __restrict__ Kl, u16* __restrict__ Klh)
{
  __shared__ __align__(16) u16 lds[2][PROD + 1][4096];

  constexpr int NBX = (MODE == 0) ? 18 : 6;
  constexpr int CPX = (NBX * 64) / 8;
  constexpr int NT  = KD_ / 32;

  const int tid = threadIdx.x;
  const int lin = blockIdx.y * NBX + blockIdx.x;
  const int swb = (lin & 7) * CPX + (lin >> 3);    // XCD-contiguous chunks
  const int m0 = (swb / NBX) * 128;
  const int n0 = (swb % NBX) * 128;

  const int wave = tid >> 6, lane = tid & 63;
  const int wm = wave >> 1, wn = wave & 1;
  const int lr = lane & 15, kg = lane >> 4;

  const int srow = tid >> 2;
  const int swz_s = (tid >> 3) & 3;                // (row>>1)&3
  const int sk = ((tid & 3) ^ swz_s) * 8;

  const u16* pAh = Ahg + (size_t)(m0 + srow) * KD_ + sk;
  const u16* pAl = (PROD == 2) ? (Alg + (size_t)(m0 + srow) * KD_ + sk) : nullptr;
  const u16* pBh = Bhg + (size_t)(n0 + srow) * KD_ + sk;

  f32x4 acc[4][4];
#pragma unroll
  for (int i = 0; i < 4; ++i)
#pragma unroll
    for (int j = 0; j < 4; ++j) acc[i][j] = (f32x4){0.f, 0.f, 0.f, 0.f};

  const int rsw = (lr >> 1) & 3;
  const int kq = (kg ^ rsw) * 8;
  const int abase = (wm * 64 + lr) * 32 + kq;
  const int bbase = (wn * 64 + lr) * 32 + kq;

#define STAGE_(buf, kt) do {                                          \
    const size_t go_ = (size_t)(kt) * 32;                             \
    u16* L_ = &lds[buf][0][0];                                        \
    gld16(pAh + go_,            L_ + tid * 8);                        \
    gld16(pAh + go_ + 64 * KD_, L_ + 2048 + tid * 8);                 \
    if (PROD == 2) {                                                  \
      gld16(pAl + go_,            L_ + 4096 + tid * 8);               \
      gld16(pAl + go_ + 64 * KD_, L_ + 6144 + tid * 8);               \
    }                                                                 \
    gld16(pBh + go_,            L_ + PROD * 4096 + tid * 8);          \
    gld16(pBh + go_ + 64 * KD_, L_ + PROD * 4096 + 2048 + tid * 8);   \
  } while (0)

  STAGE_(0, 0);
  __syncthreads();

  int cur = 0;
  for (int kt = 0; kt < NT; ++kt) {
    if (kt + 1 < NT) STAGE_(cur ^ 1, kt + 1);

    const u16* LAh = &lds[cur][0][0];
    const u16* LAl = &lds[cur][1][0];
    const u16* LBh = &lds[cur][PROD][0];
    f16x8 ah[4], al[4], bh[4];
#pragma unroll
    for (int f = 0; f < 4; ++f) {
      ah[f] = *(const f16x8*)&LAh[abase + f * 512];
      if (PROD == 2) al[f] = *(const f16x8*)&LAl[abase + f * 512];
      bh[f] = *(const f16x8*)&LBh[bbase + f * 512];
    }
#pragma unroll
    for (int i = 0; i < 4; ++i)
#pragma unroll
      for (int j = 0; j < 4; ++j) {
        acc[i][j] = __builtin_amdgcn_mfma_f32_16x16x32_f16(ah[i], bh[j], acc[i][j], 0, 0, 0);
        if (PROD == 2)
          acc[i][j] = __builtin_amdgcn_mfma_f32_16x16x32_f16(al[i], bh[j], acc[i][j], 0, 0, 0);
      }

    __syncthreads();
    cur ^= 1;
  }
#undef STAGE_

  // ---- epilogue ----
#pragma unroll
  for (int i = 0; i < 4; ++i) {
    const int mbase = m0 + wm * 64 + i * 16 + kg * 4;
#pragma unroll
    for (int j = 0; j < 4; ++j) {
      const int ncol = n0 + wn * 64 + j * 16 + lr;
      const float bv = bias[ncol];
      if (MODE == 0) {
        const int part = (ncol >= 1536) ? 2 : (ncol >= 768 ? 1 : 0);
        const int within = ncol - part * 768;
        const int h0 = within >> 6, d = within & 63;
        u16* base = (part == 0) ? oQ : ((part == 1) ? oK : oV);
#pragma unroll
        for (int r = 0; r < 4; ++r) {
          const int row = mbase + r;
          const int b = row >> 12, s = row & (S_ - 1);
          base[(((size_t)(b * H_ + h0) * S_ + s) << 6) + d] = f2h_bits(acc[i][j][r] + bv);
        }
      } else {
#pragma unroll
        for (int r = 0; r < 4; ++r) {
          const int row = mbase + r;
          oF[(size_t)row * HID_ + ncol] = acc[i][j][r] + bv;
        }
      }
    }
  }

  if (MODE == 0) {
    const int part = n0 / 768;
    if (part < 2) {
      const int within0 = n0 - part * 768;
      const int h = (within0 >> 6) + wn;
      const int rowseg = m0 + wm * 64;
      const int b = rowseg >> 12;
      const int seg = (rowseg & (S_ - 1)) >> 6;
      const int bh = b * H_ + h;
      float* dst = (part == 0) ? Ql : Kl;
#pragma unroll
      for (int j = 0; j < 4; ++j) {
        float sj = 0.f;
#pragma unroll
        for (int i = 0; i < 4; ++i)
#pragma unroll
          for (int r = 0; r < 4; ++r) sj += acc[i][j][r];
        sj += __shfl_xor(sj, 16);
        sj += __shfl_xor(sj, 32);
        if (kg == 0) {
          const int d = j * 16 + lr;
          const int ncol = n0 + wn * 64 + j * 16 + lr;
          const float lm = sj * (1.f / 64.f) + bias[ncol];
          dst[((size_t)bh * M_ + seg) * 64 + d] = lm;
          if (part == 1) Klh[((size_t)bh * M_ + seg) * 64 + d] = f2h_bits(lm);
        }
      }
    }
  }
}

// =============================================================
// kernel_2 softmax + per-(b,h) max col/row sums
// =============================================================
__global__ __launch_bounds__(256) void kernel2_softmax(
    const float* __restrict__ Ql, const float* __restrict__ Kl,
    float* __restrict__ K2, float* __restrict__ colmax, float* __restrict__ rowmax)
{
  __shared__ float Qs[64][68], Ks[64][68], S2[64][68];
  __shared__ float red1[64], red2[64];
  const int bh = blockIdx.x, tid = threadIdx.x;
  for (int idx = tid; idx < 4096; idx += 256) {
    const int r = idx >> 6, c = idx & 63;
    Qs[r][c] = Ql[(size_t)bh * 4096 + idx];
    Ks[r][c] = Kl[(size_t)bh * 4096 + idx];
  }
  __syncthreads();
  for (int idx = tid; idx < 4096; idx += 256) {
    const int r = idx >> 6, c = idx & 63;
    float dot = 0.f;
#pragma unroll
    for (int k = 0; k < 64; k += 4) {
      const float4 a = *(const float4*)&Qs[r][k];
      const float4 b = *(const float4*)&Ks[c][k];
      dot += a.x * b.x + a.y * b.y + a.z * b.z + a.w * b.w;
    }
    S2[r][c] = dot * 0.125f;
  }
  __syncthreads();
  if (tid < 64) {
    const int r = tid;
    float mx = -1e30f;
    for (int c = 0; c < 64; ++c) mx = fmaxf(mx, S2[r][c]);
    float sum = 0.f;
    for (int c = 0; c < 64; ++c) { const float e = expf(S2[r][c] - mx); S2[r][c] = e; sum += e; }
    const float inv = 1.f / sum;
    for (int c = 0; c < 64; ++c) S2[r][c] *= inv;
  }
  __syncthreads();
  for (int idx = tid; idx < 4096; idx += 256)
    K2[(size_t)bh * 4096 + idx] = S2[idx >> 6][idx & 63];
  if (tid < 64) {
    float cs = 0.f, rs = 0.f;
    for (int m = 0; m < 64; ++m) { cs += S2[m][tid]; rs += S2[tid][m]; }
    red1[tid] = cs; red2[tid] = rs;
  }
  __syncthreads();
  if (tid == 0) {
    float mc = 0.f, mr = 0.f;
    for (int i = 0; i < 64; ++i) { mc = fmaxf(mc, red1[i]); mr = fmaxf(mr, red2[i]); }
    colmax[bh] = mc; rowmax[bh] = mr;
  }
}

// 64x64x64 matmul in LDS, 512 threads (2x4 per thread)
__device__ inline void mm64w(float (*C)[68], float (*A)[68], float (*B)[68], int tid)
{
  const int r0 = (tid >> 4) * 2;
  const int c0 = (tid & 15) * 4;
  float acc[2][4];
#pragma unroll
  for (int i = 0; i < 2; ++i)
#pragma unroll
    for (int j = 0; j < 4; ++j) acc[i][j] = 0.f;
  for (int k = 0; k < 64; k += 4) {
    float4 a[2], b[4];
#pragma unroll
    for (int i = 0; i < 2; ++i) a[i] = *(const float4*)&A[r0 + i][k];
#pragma unroll
    for (int j = 0; j < 4; ++j) b[j] = *(const float4*)&B[k + j][c0];
    const float bb[4][4] = {{b[0].x, b[0].y, b[0].z, b[0].w},
                            {b[1].x, b[1].y, b[1].z, b[1].w},
                            {b[2].x, b[2].y, b[2].z, b[2].w},
                            {b[3].x, b[3].y, b[3].z, b[3].w}};
    const float aa[2][4] = {{a[0].x, a[0].y, a[0].z, a[0].w},
                            {a[1].x, a[1].y, a[1].z, a[1].w}};
#pragma unroll
    for (int i = 0; i < 2; ++i)
#pragma unroll
      for (int j = 0; j < 4; ++j)
#pragma unroll
        for (int kk = 0; kk < 4; ++kk) acc[i][j] += aa[i][kk] * bb[kk][j];
  }
#pragma unroll
  for (int i = 0; i < 2; ++i)
    *(float4*)&C[r0 + i][c0] = make_float4(acc[i][0], acc[i][1], acc[i][2], acc[i][3]);
}

// =============================================================
// FUSED: Newton-Schulz pinv + k3v combine + W2 = Vinv @ W1
// =============================================================
__global__ __launch_bounds__(512) void newton_combine(
    const float* __restrict__ K2, const float* __restrict__ colmax,
    const float* __restrict__ rowmax,
    const float* __restrict__ Opart, const float* __restrict__ mpart,
    const float* __restrict__ lpart, float* __restrict__ W2)
{
  __shared__ float A_[64][68], V_[64][68], KV_[64][68], T_[64][68], U_[64][68];
  __shared__ float scale_s;
  const int bh = blockIdx.x, tid = threadIdx.x;
  if (tid == 0) {
    float mc = 0.f, mr = 0.f;
    for (int i = 0; i < BH_; ++i) { mc = fmaxf(mc, colmax[i]); mr = fmaxf(mr, rowmax[i]); }
    scale_s = 1.f / (mc * mr);
  }
  for (int idx = tid; idx < 4096; idx += 512)
    A_[idx >> 6][idx & 63] = K2[(size_t)bh * 4096 + idx];
  __syncthreads();
  const float scale = scale_s;
  for (int idx = tid; idx < 4096; idx += 512) {
    const int r = idx >> 6, c = idx & 63;
    V_[r][c] = scale * A_[c][r];
  }
  __syncthreads();
  for (int it = 0; it < 6; ++it) {
    mm64w(KV_, A_, V_, tid); __syncthreads();
    for (int idx = tid; idx < 4096; idx += 512) {
      const int r = idx >> 6, c = idx & 63;
      T_[r][c] = (r == c ? 7.f : 0.f) - KV_[r][c];
    }
    __syncthreads();
    mm64w(U_, KV_, T_, tid); __syncthreads();
    for (int idx = tid; idx < 4096; idx += 512) {
      const int r = idx >> 6, c = idx & 63;
      T_[r][c] = (r == c ? 15.f : 0.f) - U_[r][c];
    }
    __syncthreads();
    mm64w(U_, KV_, T_, tid); __syncthreads();
    for (int idx = tid; idx < 4096; idx += 512) {
      const int r = idx >> 6, c = idx & 63;
      T_[r][c] = (r == c ? 13.f : 0.f) - U_[r][c];
    }
    __syncthreads();
    mm64w(U_, V_, T_, tid); __syncthreads();
    for (int idx = tid; idx < 4096; idx += 512) {
      const int r = idx >> 6, c = idx & 63;
      V_[r][c] = 0.25f * U_[r][c];
    }
    __syncthreads();
  }
  float (*W1s)[68] = A_;
  float (*C_)[68]  = KV_;
  float (*w_)[68]  = T_;
  if (tid < 64) {
    const int m = tid;
    float M = -1e30f;
    for (int j = 0; j < NCH_; ++j)
      M = fmaxf(M, mpart[((size_t)bh * NCH_ + j) * 64 + m]);
    float denom = 0.f;
    for (int j = 0; j < NCH_; ++j)
      denom += expf(mpart[((size_t)bh * NCH_ + j) * 64 + m] - M) *
               lpart[((size_t)bh * NCH_ + j) * 64 + m];
    const float inv = 1.f / denom;
    for (int j = 0; j < NCH_; ++j)
      w_[m][j] = expf(mpart[((size_t)bh * NCH_ + j) * 64 + m] - M) * inv;
  }
  __syncthreads();
  const int mgB = tid >> 4, dq = (tid & 15) * 4;
#pragma unroll
  for (int i = 0; i < 2; ++i) {
    const int m = mgB + 32 * i;
    float4 acc = make_float4(0.f, 0.f, 0.f, 0.f);
    for (int j = 0; j < NCH_; ++j) {
      const float ww = w_[m][j];
      const float4 o = *(const float4*)&Opart[(((size_t)bh * NCH_ + j) * 64 + m) * 64 + dq];
      acc.x += ww * o.x; acc.y += ww * o.y; acc.z += ww * o.z; acc.w += ww * o.w;
    }
    *(float4*)&W1s[m][dq] = acc;
  }
  __syncthreads();
  mm64w(C_, V_, W1s, tid);
  __syncthreads();
  for (int idx = tid; idx < 4096; idx += 512)
    W2[(size_t)bh * 4096 + idx] = C_[idx >> 6][idx & 63];
}

// =============================================================
// k3v pass 1: S = Ql @ K_chunk^T / 8 (fp16 MFMA, K/V fp16),
// partial softmax + O_j = exp(S-m_j) @ V_chunk (fp32 VALU)
// =============================================================
__global__ __launch_bounds__(256) void k3v_pass1(
    const float* __restrict__ Ql, const u16* __restrict__ Kh,
    const u16* __restrict__ Vh, float* __restrict__ Opart,
    float* __restrict__ mpart, float* __restrict__ lpart)
{
  __shared__ float P[64][129];
  __shared__ float red1[64][4], red2[64][4];

  const int ch = blockIdx.x;     // 0..31
  const int bh = blockIdx.y;     // 0..23
  const int tid = threadIdx.x;
  const int wave = tid >> 6, lane = tid & 63;
  const int lr = lane & 15, kg = lane >> 4;

  const float* Qlb = Ql + (size_t)bh * 4096;
  const u16*   Kb  = Kh + (size_t)bh * S_ * 64;
  const u16*   Vb  = Vh + (size_t)bh * S_ * 64;

  f16x8 ah[4][2], al[4][2];
#pragma unroll
  for (int mt = 0; mt < 4; ++mt)
#pragma unroll
    for (int kk = 0; kk < 2; ++kk) {
      const float* qr = Qlb + (size_t)(mt * 16 + lr) * 64 + kk * 32 + kg * 8;
      cvt8_hl(*(const float4*)qr, *(const float4*)(qr + 4), &ah[mt][kk], &al[mt][kk]);
    }

#pragma unroll
  for (int t = 0; t < 2; ++t) {
    const int s0 = (wave * 2 + t) * 16;
    const int srow = ch * SC_ + s0 + lr;
    f32x4 acc[4];
#pragma unroll
    for (int mt = 0; mt < 4; ++mt) acc[mt] = (f32x4){0.f, 0.f, 0.f, 0.f};
#pragma unroll
    for (int kk = 0; kk < 2; ++kk) {
      const f16x8 bhf = *(const f16x8*)&Kb[(size_t)srow * 64 + kk * 32 + kg * 8];
#pragma unroll
      for (int mt = 0; mt < 4; ++mt) {
        acc[mt] = __builtin_amdgcn_mfma_f32_16x16x32_f16(ah[mt][kk], bhf, acc[mt], 0, 0, 0);
        acc[mt] = __builtin_amdgcn_mfma_f32_16x16x32_f16(al[mt][kk], bhf, acc[mt], 0, 0, 0);
      }
    }
#pragma unroll
    for (int mt = 0; mt < 4; ++mt)
#pragma unroll
      for (int r = 0; r < 4; ++r)
        P[mt * 16 + kg * 4 + r][s0 + lr] = acc[mt][r] * 0.125f;
  }
  __syncthreads();

  const int r = tid >> 2, q = tid & 3;
  {
    float mx = -1e30f;
#pragma unroll
    for (int s = 0; s < 32; ++s) mx = fmaxf(mx, P[r][q * 32 + s]);
    red1[r][q] = mx;
  }
  __syncthreads();
  const float rowmax = fmaxf(fmaxf(red1[r][0], red1[r][1]),
                             fmaxf(red1[r][2], red1[r][3]));
  {
    float sum = 0.f;
#pragma unroll
    for (int s = 0; s < 32; ++s) {
      const float e = expf(P[r][q * 32 + s] - rowmax);
      P[r][q * 32 + s] = e;
      sum += e;
    }
    red2[r][q] = sum;
  }
  __syncthreads();
  if (q == 0) {
    const float rowsum = red2[r][0] + red2[r][1] + red2[r][2] + red2[r][3];
    mpart[((size_t)bh * NCH_ + ch) * 64 + r] = rowmax;
    lpart[((size_t)bh * NCH_ + ch) * 64 + r] = rowsum;
  }

  const int mg = tid >> 4, dq = (tid & 15) * 4;
  float4 oacc[4];
#pragma unroll
  for (int i = 0; i < 4; ++i) oacc[i] = make_float4(0.f, 0.f, 0.f, 0.f);
  for (int s = 0; s < SC_; ++s) {
    const ushort4 vv = *(const ushort4*)&Vb[(size_t)(ch * SC_ + s) * 64 + dq];
    const float4 v = make_float4(h2f(vv.x), h2f(vv.y), h2f(vv.z), h2f(vv.w));
#pragma unroll
    for (int i = 0; i < 4; ++i) {
      const float p = P[mg * 4 + i][s];
      oacc[i].x += p * v.x; oacc[i].y += p * v.y;
      oacc[i].z += p * v.z; oacc[i].w += p * v.w;
    }
  }
#pragma unroll
  for (int i = 0; i < 4; ++i) {
    const size_t o = (((size_t)bh * NCH_ + ch) * 64 + mg * 4 + i) * 64 + dq;
    *(float4*)&Opart[o] = oacc[i];
  }
}

// =============================================================
// FUSED attention + conv, v2 (MFMA scores, reg-blocked PV):
// one block per (bh, 128-row chunk) = 768 blocks, 256 threads.
//   scores: MFMA from global Qh/Klh fragments -> P (LDS, /8)
//   softmax: 2 threads/row
//   PV: thread (rq,dq) owns 8 rows x 4 cols, W2 f32 from LDS
//   conv: register sliding window over fp16 V, + PV result,
//         write split-fp16 Xch/Xcl
// =============================================================
__global__ __launch_bounds__(256) void attn_conv_fused(
    const u16* __restrict__ Qh, const u16* __restrict__ Klh,
    const float* __restrict__ W2, const u16* __restrict__ Vh,
    const float* __restrict__ cw,
    u16* __restrict__ Xch, u16* __restrict__ Xcl)
{
  __shared__ float P[128][69];
  __shared__ float W2s[64][68];
  __shared__ float cws[33];

  const int ch = blockIdx.x;     // 0..31
  const int bh = blockIdx.y;     // 0..23
  const int tid = threadIdx.x;
  const int wave = tid >> 6, lane = tid & 63;
  const int lr = lane & 15, kg = lane >> 4;
  const int b = bh / H_, h = bh % H_;
  const int s0 = ch * 128;

  if (tid < 33) cws[tid] = cw[h * 33 + tid];
  for (int idx = tid; idx < 4096; idx += 256)
    W2s[idx >> 6][idx & 63] = W2[(size_t)bh * 4096 + idx];

  // ---- scores: Q(fp16) @ Kl(fp16)^T via MFMA ----
  const u16* Klb = Klh + (size_t)bh * 4096;
  const u16* Qb  = Qh + (size_t)bh * S_ * 64;
  f16x8 bf[4][2];
#pragma unroll
  for (int nt = 0; nt < 4; ++nt)
#pragma unroll
    for (int kk = 0; kk < 2; ++kk)
      bf[nt][kk] = *(const f16x8*)&Klb[(size_t)(nt * 16 + lr) * 64 + kk * 32 + kg * 8];

#pragma unroll
  for (int t = 0; t < 2; ++t) {
    const int rloc = wave * 32 + t * 16;
    f16x8 af[2];
#pragma unroll
    for (int kk = 0; kk < 2; ++kk)
      af[kk] = *(const f16x8*)&Qb[(size_t)(s0 + rloc + lr) * 64 + kk * 32 + kg * 8];
    f32x4 acc[4];
#pragma unroll
    for (int nt = 0; nt < 4; ++nt) acc[nt] = (f32x4){0.f, 0.f, 0.f, 0.f};
#pragma unroll
    for (int kk = 0; kk < 2; ++kk)
#pragma unroll
      for (int nt = 0; nt < 4; ++nt)
        acc[nt] = __builtin_amdgcn_mfma_f32_16x16x32_f16(af[kk], bf[nt][kk], acc[nt], 0, 0, 0);
#pragma unroll
    for (int nt = 0; nt < 4; ++nt)
#pragma unroll
      for (int r = 0; r < 4; ++r)
        P[rloc + kg * 4 + r][nt * 16 + lr] = acc[nt][r] * 0.125f;
  }
  __syncthreads();

  // ---- softmax: 2 threads per row ----
  {
    const int r = tid >> 1, q = (tid & 1) * 32;
    float mx = -1e30f;
#pragma unroll
    for (int s = 0; s < 32; ++s) mx = fmaxf(mx, P[r][q + s]);
    mx = fmaxf(mx, __shfl_xor(mx, 1));
    float sum = 0.f;
#pragma unroll
    for (int s = 0; s < 32; ++s) {
      const float e = expf(P[r][q + s] - mx);
      P[r][q + s] = e;
      sum += e;
    }
    sum += __shfl_xor(sum, 1);
    const float inv = 1.f / sum;
#pragma unroll
    for (int s = 0; s < 32; ++s) P[r][q + s] *= inv;
  }
  __syncthreads();

  // ---- PV: thread (rq, dq) -> 8 rows x 4 cols, fp32 ----
  const int rq = tid >> 4, dq = (tid & 15) * 4;
  float4 o[8];
#pragma unroll
  for (int i = 0; i < 8; ++i) o[i] = make_float4(0.f, 0.f, 0.f, 0.f);
  for (int m = 0; m < 64; ++m) {
    const float4 w = *(const float4*)&W2s[m][dq];
#pragma unroll
    for (int i = 0; i < 8; ++i) {
      const float p = P[rq * 8 + i][m];
      o[i].x += p * w.x; o[i].y += p * w.y; o[i].z += p * w.z; o[i].w += p * w.w;
    }
  }
  __syncthreads();
#pragma unroll
  for (int i = 0; i < 8; ++i) {
    const int r = rq * 8 + i;
    P[r][dq] = o[i].x; P[r][dq + 1] = o[i].y;
    P[r][dq + 2] = o[i].z; P[r][dq + 3] = o[i].w;
  }
  __syncthreads();

  // ---- conv (sliding window over fp16 V) + combine + split write ----
  const int d = tid & 63, rg = tid >> 6;        // 4 groups x 32 rows
  const int rbase = s0 + rg * 32;
  const u16* Vd = Vh + (size_t)bh * S_ * 64 + d;

  float v[40];
#pragma unroll
  for (int j = 0; j < 40; ++j) {
    const int sv = rbase - 16 + j;
    v[j] = (sv >= 0 && sv < S_) ? h2f(Vd[(size_t)sv * 64]) : 0.f;
  }

#pragma unroll
  for (int c = 0; c < 4; ++c) {                 // 4 chunks of 8 rows
#pragma unroll
    for (int rr = 0; rr < 8; ++rr) {
      float acc = 0.f;
#pragma unroll
      for (int t = 0; t < 33; ++t) acc += v[rr + t] * cws[t];
      const int row = rg * 32 + c * 8 + rr;     // row within chunk (0..127)
      const float oo = P[row][d] + acc;
      const size_t idx = ((size_t)(b * S_ + s0 + row)) * HID_ + h * 64 + d;
      const u16 hh = f2h_bits(oo);
      Xch[idx] = hh;
      Xcl[idx] = f2h_bits(oo - h2f(hh));
    }
    if (c < 3) {
#pragma unroll
      for (int j = 0; j < 32; ++j) v[j] = v[j + 8];
#pragma unroll
      for (int j = 0; j < 8; ++j) {
        const int sv = rbase + 24 + c * 8 + j;
        v[32 + j] = (sv >= 0 && sv < S_) ? h2f(Vd[(size_t)sv * 64]) : 0.f;
      }
    }
  }
}

// =============================================================
extern "C" void kernel_launch(void* const* d_in, const int* in_sizes, int n_in,
                              void* d_out, int out_size, void* d_ws, size_t ws_size,
                              hipStream_t stream)
{
  (void)in_sizes; (void)n_in; (void)out_size; (void)ws_size;
  const float* x      = (const float*)d_in[0];
  const float* qkv_w  = (const float*)d_in[1];
  const float* qkv_b  = (const float*)d_in[2];
  const float* conv_w = (const float*)d_in[3];
  const float* out_w  = (const float*)d_in[4];
  const float* out_b  = (const float*)d_in[5];
  float* out = (float*)d_out;

  float* ws = (float*)d_ws;
  // fp16 QKV region (u16): 3 x 6291456
  u16* Qh = (u16*)ws;
  u16* Kh = Qh + 6291456;
  u16* Vh = Kh + 6291456;                  // = 9437184 f32 total
  // f32 region
  float* Ql = ws + 9437184;
  float* Kl = Ql + 98304;
  float* K2 = Kl + 98304;
  float* W2 = K2 + 98304;
  float* colmax = W2 + 98304;
  float* rowmax = colmax + 32;
  u16* Klh = (u16*)(rowmax + 32);          // 98304 u16 = 49152 f32
  float* nxt = rowmax + 32 + 49152;
  // fp16 staging region
  u16* Xh  = (u16*)nxt;                    // 6291456 u16
  u16* Xl  = Xh + 6291456;
  u16* Wqh = Xl + 6291456;                 // 1769472
  u16* Woh = Wqh + 1769472;                // 589824
  // aliases (stream-ordered safe):
  u16* Xch = Xh;                           // Xh dead after QKV GEMM
  u16* Xcl = Xl;
  float* Opart = (float*)Xh;               // consumed before Xch write
  float* mpart = (float*)Xl;
  float* lpart = mpart + BH_ * NCH_ * 64;

  split3<<<(N8X + N8WQ + N8WO + 255) / 256, 256, 0, stream>>>(
      x, qkv_w, out_w, Xh, Wqh, Woh);

  gemm_mfma<0, 1><<<dim3(18, 64), 256, 0, stream>>>(
      Xh, nullptr, Wqh, qkv_b, nullptr, Qh, Kh, Vh, Ql, Kl, Klh);

  kernel2_softmax<<<BH_, 256, 0, stream>>>(Ql, Kl, K2, colmax, rowmax);

  k3v_pass1<<<dim3(NCH_, BH_), 256, 0, stream>>>(Ql, Kh, Vh, Opart, mpart, lpart);

  newton_combine<<<BH_, 512, 0, stream>>>(K2, colmax, rowmax,
                                          Opart, mpart, lpart, W2);

  attn_conv_fused<<<dim3(NCH_, BH_), 256, 0, stream>>>(
      Qh, Klh, W2, Vh, conv_w, Xch, Xcl);

  gemm_mfma<1, 2><<<dim3(6, 64), 256, 0, stream>>>(
      Xch, Xcl, Woh, out_b, out, nullptr, nullptr, nullptr,
      nullptr, nullptr, nullptr);
}

// Round 10
// 266.064 us; speedup vs baseline: 1.0494x; 1.0494x over previous
//
#include <hip/hip_runtime.h>
#include <math.h>

#define B_   2
#define S_   4096
#define HID_ 768
#define H_   12
#define D_   64
#define M_   64
#define CK_  33
#define BH_  (B_*H_)   // 24
#define KD_  768
#define NCH_ 32        // k3v S-chunks
#define SC_  128       // keys per chunk

typedef float  f32x4  __attribute__((ext_vector_type(4)));
typedef _Float16 f16x8 __attribute__((ext_vector_type(8)));
typedef unsigned short u16;

__device__ __forceinline__ u16 f2h_bits(float f) {
  union { _Float16 h; u16 u; } c; c.h = (_Float16)f; return c.u;
}
__device__ __forceinline__ float h2f(u16 b) {
  union { _Float16 h; u16 u; } c; c.u = b; return (float)c.h;
}
__device__ __forceinline__ void cvt8_hl(const float4 a, const float4 b,
                                        f16x8* hi, f16x8* lo) {
  const float v[8] = {a.x, a.y, a.z, a.w, b.x, b.y, b.z, b.w};
  f16x8 H, L;
#pragma unroll
  for (int e = 0; e < 8; ++e) {
    const _Float16 hh = (_Float16)v[e];
    H[e] = hh;
    L[e] = (_Float16)(v[e] - (float)hh);
  }
  *hi = H; *lo = L;
}

__device__ __forceinline__ void gld16(const void* g, void* l) {
  __builtin_amdgcn_global_load_lds(
      (const __attribute__((address_space(1))) void*)g,
      (__attribute__((address_space(3))) void*)l, 16, 0, 0);
}

// =============================================================
// Downcast: x -> Xh, qkv_w -> Wqh, out_w -> Woh (fp16 hi only)
// =============================================================
#define N8X  786432
#define N8WQ 221184
#define N8WO 73728
__global__ __launch_bounds__(256) void split3(
    const float* __restrict__ x, const float* __restrict__ qkv_w,
    const float* __restrict__ out_w,
    u16* __restrict__ Xh, u16* __restrict__ Wqh, u16* __restrict__ Woh)
{
  const int i = blockIdx.x * 256 + threadIdx.x;
  const float* src; u16* dst; int j;
  if (i < N8X)                 { src = x;     dst = Xh;  j = i; }
  else if (i < N8X + N8WQ)     { src = qkv_w; dst = Wqh; j = i - N8X; }
  else if (i < N8X + N8WQ + N8WO) { src = out_w; dst = Woh; j = i - N8X - N8WQ; }
  else return;
  const float4 a = ((const float4*)src)[2 * j], b = ((const float4*)src)[2 * j + 1];
  const float v[8] = {a.x, a.y, a.z, a.w, b.x, b.y, b.z, b.w};
  union { u16 u[8]; uint4 q; } hv;
#pragma unroll
  for (int e = 0; e < 8; ++e) hv.u[e] = f2h_bits(v[e]);
  ((uint4*)dst)[j] = hv.q;
}

// =============================================================
// fp16 MFMA GEMM: C = A @ W^T (+bias)
// MODE 0: tile 128x64 (2304 blocks), PROD=1, scatter Q/K/V fp16,
//         fused landmarks (wave = one full 64-row segment, one head).
// MODE 1: tile 64x128 (768 blocks), PROD=2, row-major f32 out.
// =============================================================
template<int MODE, int PROD>
__global__ __launch_bounds__(256) void gemm_mfma(
    const u16* __restrict__ Ahg, const u16* __restrict__ Alg,
    const u16* __restrict__ Bhg,
    const float* __restrict__ bias,
    float* __restrict__ oF, u16* __restrict__ oQ, u16* __restrict__ oK,
    u16* __restrict__ oV,
    float* __restrict__ Ql, float* __restrict__ Kl, u16* __restrict__ Klh)
{
  constexpr int BM = (MODE == 0) ? 128 : 64;
  constexpr int BN = (MODE == 0) ? 64 : 128;
  constexpr int NBX = (MODE == 0) ? 36 : 6;      // total-N / BN
  constexpr int WM = BM / 2, WN = BN / 2;
  constexpr int MF = WM / 16, NF = WN / 16;
  constexpr int AINST = BM / 64, BINST = BN / 64;
  constexpr int ABUF = BM * 32;                  // u16 per A tensor
  constexpr int BUFSZ = ABUF * PROD + BN * 32;
  constexpr int NT = KD_ / 32;
  constexpr int NWG = NBX * (8192 / BM);
  constexpr int CPX = NWG / 8;

  __shared__ __align__(16) u16 lds[2][BUFSZ];

  const int tid = threadIdx.x;
  const int lin = blockIdx.y * NBX + blockIdx.x;
  const int swb = (lin & 7) * CPX + (lin >> 3);
  const int m0 = (swb / NBX) * BM;
  const int n0 = (swb % NBX) * BN;

  const int wave = tid >> 6, lane = tid & 63;
  const int wm = wave >> 1, wn = wave & 1;
  const int lr = lane & 15, kg = lane >> 4;

  const int srow = tid >> 2;
  const int swz_s = (tid >> 3) & 3;
  const int sk = ((tid & 3) ^ swz_s) * 8;

  const u16* pAh = Ahg + (size_t)(m0 + srow) * KD_ + sk;
  const u16* pAl = (PROD == 2) ? (Alg + (size_t)(m0 + srow) * KD_ + sk) : nullptr;
  const u16* pBh = Bhg + (size_t)(n0 + srow) * KD_ + sk;

  f32x4 acc[MF][NF];
#pragma unroll
  for (int i = 0; i < MF; ++i)
#pragma unroll
    for (int j = 0; j < NF; ++j) acc[i][j] = (f32x4){0.f, 0.f, 0.f, 0.f};

  const int rsw = (lr >> 1) & 3;
  const int kq = (kg ^ rsw) * 8;
  const int abase = (wm * WM + lr) * 32 + kq;
  const int bbase = (wn * WN + lr) * 32 + kq;

#define STAGE_(buf, kt) do {                                              \
    const size_t go_ = (size_t)(kt) * 32;                                 \
    u16* L_ = &lds[buf][0];                                               \
    gld16(pAh + go_, L_ + tid * 8);                                       \
    if (AINST == 2) gld16(pAh + go_ + 64 * KD_, L_ + 2048 + tid * 8);     \
    if (PROD == 2) {                                                      \
      gld16(pAl + go_, L_ + ABUF + tid * 8);                              \
      if (AINST == 2) gld16(pAl + go_ + 64 * KD_, L_ + ABUF + 2048 + tid * 8); \
    }                                                                     \
    gld16(pBh + go_, L_ + ABUF * PROD + tid * 8);                         \
    if (BINST == 2) gld16(pBh + go_ + 64 * KD_, L_ + ABUF * PROD + 2048 + tid * 8); \
  } while (0)

  STAGE_(0, 0);
  __syncthreads();

  int cur = 0;
  for (int kt = 0; kt < NT; ++kt) {
    if (kt + 1 < NT) STAGE_(cur ^ 1, kt + 1);

    const u16* L_ = &lds[cur][0];
    f16x8 ah[MF], al[MF], bh[NF];
#pragma unroll
    for (int i = 0; i < MF; ++i) {
      ah[i] = *(const f16x8*)&L_[abase + i * 512];
      if (PROD == 2) al[i] = *(const f16x8*)&L_[ABUF + abase + i * 512];
    }
#pragma unroll
    for (int j = 0; j < NF; ++j)
      bh[j] = *(const f16x8*)&L_[ABUF * PROD + bbase + j * 512];
#pragma unroll
    for (int i = 0; i < MF; ++i)
#pragma unroll
      for (int j = 0; j < NF; ++j) {
        acc[i][j] = __builtin_amdgcn_mfma_f32_16x16x32_f16(ah[i], bh[j], acc[i][j], 0, 0, 0);
        if (PROD == 2)
          acc[i][j] = __builtin_amdgcn_mfma_f32_16x16x32_f16(al[i], bh[j], acc[i][j], 0, 0, 0);
      }

    __syncthreads();
    cur ^= 1;
  }
#undef STAGE_

  if (MODE == 0) {
    const int part = n0 / 768;
    const int h0 = (n0 - part * 768) >> 6;
    u16* base = (part == 0) ? oQ : ((part == 1) ? oK : oV);
#pragma unroll
    for (int i = 0; i < MF; ++i) {
      const int mbase = m0 + wm * WM + i * 16 + kg * 4;
#pragma unroll
      for (int j = 0; j < NF; ++j) {
        const int d = wn * WN + j * 16 + lr;
        const float bv = bias[n0 + d];
#pragma unroll
        for (int r = 0; r < 4; ++r) {
          const int row = mbase + r;
          const int b = row >> 12, s = row & (S_ - 1);
          base[(((size_t)(b * H_ + h0) * S_ + s) << 6) + d] = f2h_bits(acc[i][j][r] + bv);
        }
      }
    }
    // landmarks: wave's WM=64 rows = one full segment; block = one head
    if (part < 2) {
      const int rowseg = m0 + wm * WM;
      const int b = rowseg >> 12;
      const int seg = (rowseg & (S_ - 1)) >> 6;
      const int bhh = b * H_ + h0;
      float* dst = (part == 0) ? Ql : Kl;
#pragma unroll
      for (int j = 0; j < NF; ++j) {
        float sj = 0.f;
#pragma unroll
        for (int i = 0; i < MF; ++i)
#pragma unroll
          for (int r = 0; r < 4; ++r) sj += acc[i][j][r];
        sj += __shfl_xor(sj, 16);
        sj += __shfl_xor(sj, 32);
        if (kg == 0) {
          const int d = wn * WN + j * 16 + lr;
          const float lm = sj * (1.f / 64.f) + bias[n0 + d];
          dst[((size_t)bhh * M_ + seg) * 64 + d] = lm;
          if (part == 1) Klh[((size_t)bhh * M_ + seg) * 64 + d] = f2h_bits(lm);
        }
      }
    }
  } else {
#pragma unroll
    for (int i = 0; i < MF; ++i) {
      const int mbase = m0 + wm * WM + i * 16 + kg * 4;
#pragma unroll
      for (int j = 0; j < NF; ++j) {
        const int ncol = n0 + wn * WN + j * 16 + lr;
        const float bv = bias[ncol];
#pragma unroll
        for (int r = 0; r < 4; ++r) {
          const int row = mbase + r;
          oF[(size_t)row * HID_ + ncol] = acc[i][j][r] + bv;
        }
      }
    }
  }
}

// =============================================================
// kernel_2 softmax + per-(b,h) max col/row sums
// =============================================================
__global__ __launch_bounds__(256) void kernel2_softmax(
    const float* __restrict__ Ql, const float* __restrict__ Kl,
    float* __restrict__ K2, float* __restrict__ colmax, float* __restrict__ rowmax)
{
  __shared__ float Qs[64][68], Ks[64][68], S2[64][68];
  __shared__ float red1[64], red2[64];
  const int bh = blockIdx.x, tid = threadIdx.x;
  for (int idx = tid; idx < 4096; idx += 256) {
    const int r = idx >> 6, c = idx & 63;
    Qs[r][c] = Ql[(size_t)bh * 4096 + idx];
    Ks[r][c] = Kl[(size_t)bh * 4096 + idx];
  }
  __syncthreads();
  for (int idx = tid; idx < 4096; idx += 256) {
    const int r = idx >> 6, c = idx & 63;
    float dot = 0.f;
#pragma unroll
    for (int k = 0; k < 64; k += 4) {
      const float4 a = *(const float4*)&Qs[r][k];
      const float4 b = *(const float4*)&Ks[c][k];
      dot += a.x * b.x + a.y * b.y + a.z * b.z + a.w * b.w;
    }
    S2[r][c] = dot * 0.125f;
  }
  __syncthreads();
  if (tid < 64) {
    const int r = tid;
    float mx = -1e30f;
    for (int c = 0; c < 64; ++c) mx = fmaxf(mx, S2[r][c]);
    float sum = 0.f;
    for (int c = 0; c < 64; ++c) { const float e = expf(S2[r][c] - mx); S2[r][c] = e; sum += e; }
    const float inv = 1.f / sum;
    for (int c = 0; c < 64; ++c) S2[r][c] *= inv;
  }
  __syncthreads();
  for (int idx = tid; idx < 4096; idx += 256)
    K2[(size_t)bh * 4096 + idx] = S2[idx >> 6][idx & 63];
  if (tid < 64) {
    float cs = 0.f, rs = 0.f;
    for (int m = 0; m < 64; ++m) { cs += S2[m][tid]; rs += S2[tid][m]; }
    red1[tid] = cs; red2[tid] = rs;
  }
  __syncthreads();
  if (tid == 0) {
    float mc = 0.f, mr = 0.f;
    for (int i = 0; i < 64; ++i) { mc = fmaxf(mc, red1[i]); mr = fmaxf(mr, red2[i]); }
    colmax[bh] = mc; rowmax[bh] = mr;
  }
}

// 64x64x64 matmul in LDS, 512 threads (2x4 per thread)
__device__ inline void mm64w(float (*C)[68], float (*A)[68], float (*B)[68], int tid)
{
  const int r0 = (tid >> 4) * 2;
  const int c0 = (tid & 15) * 4;
  float acc[2][4];
#pragma unroll
  for (int i = 0; i < 2; ++i)
#pragma unroll
    for (int j = 0; j < 4; ++j) acc[i][j] = 0.f;
  for (int k = 0; k < 64; k += 4) {
    float4 a[2], b[4];
#pragma unroll
    for (int i = 0; i < 2; ++i) a[i] = *(const float4*)&A[r0 + i][k];
#pragma unroll
    for (int j = 0; j < 4; ++j) b[j] = *(const float4*)&B[k + j][c0];
    const float bb[4][4] = {{b[0].x, b[0].y, b[0].z, b[0].w},
                            {b[1].x, b[1].y, b[1].z, b[1].w},
                            {b[2].x, b[2].y, b[2].z, b[2].w},
                            {b[3].x, b[3].y, b[3].z, b[3].w}};
    const float aa[2][4] = {{a[0].x, a[0].y, a[0].z, a[0].w},
                            {a[1].x, a[1].y, a[1].z, a[1].w}};
#pragma unroll
    for (int i = 0; i < 2; ++i)
#pragma unroll
      for (int j = 0; j < 4; ++j)
#pragma unroll
        for (int kk = 0; kk < 4; ++kk) acc[i][j] += aa[i][kk] * bb[kk][j];
  }
#pragma unroll
  for (int i = 0; i < 2; ++i)
    *(float4*)&C[r0 + i][c0] = make_float4(acc[i][0], acc[i][1], acc[i][2], acc[i][3]);
}

// =============================================================
// FUSED: Newton-Schulz pinv + k3v combine + W2 = Vinv @ W1
// =============================================================
__global__ __launch_bounds__(512) void newton_combine(
    const float* __restrict__ K2, const float* __restrict__ colmax,
    const float* __restrict__ rowmax,
    const float* __restrict__ Opart, const float* __restrict__ mpart,
    const float* __restrict__ lpart, float* __restrict__ W2)
{
  __shared__ float A_[64][68], V_[64][68], KV_[64][68], T_[64][68], U_[64][68];
  __shared__ float scale_s;
  const int bh = blockIdx.x, tid = threadIdx.x;
  if (tid == 0) {
    float mc = 0.f, mr = 0.f;
    for (int i = 0; i < BH_; ++i) { mc = fmaxf(mc, colmax[i]); mr = fmaxf(mr, rowmax[i]); }
    scale_s = 1.f / (mc * mr);
  }
  for (int idx = tid; idx < 4096; idx += 512)
    A_[idx >> 6][idx & 63] = K2[(size_t)bh * 4096 + idx];
  __syncthreads();
  const float scale = scale_s;
  for (int idx = tid; idx < 4096; idx += 512) {
    const int r = idx >> 6, c = idx & 63;
    V_[r][c] = scale * A_[c][r];
  }
  __syncthreads();
  for (int it = 0; it < 6; ++it) {
    mm64w(KV_, A_, V_, tid); __syncthreads();
    for (int idx = tid; idx < 4096; idx += 512) {
      const int r = idx >> 6, c = idx & 63;
      T_[r][c] = (r == c ? 7.f : 0.f) - KV_[r][c];
    }
    __syncthreads();
    mm64w(U_, KV_, T_, tid); __syncthreads();
    for (int idx = tid; idx < 4096; idx += 512) {
      const int r = idx >> 6, c = idx & 63;
      T_[r][c] = (r == c ? 15.f : 0.f) - U_[r][c];
    }
    __syncthreads();
    mm64w(U_, KV_, T_, tid); __syncthreads();
    for (int idx = tid; idx < 4096; idx += 512) {
      const int r = idx >> 6, c = idx & 63;
      T_[r][c] = (r == c ? 13.f : 0.f) - U_[r][c];
    }
    __syncthreads();
    mm64w(U_, V_, T_, tid); __syncthreads();
    for (int idx = tid; idx < 4096; idx += 512) {
      const int r = idx >> 6, c = idx & 63;
      V_[r][c] = 0.25f * U_[r][c];
    }
    __syncthreads();
  }
  float (*W1s)[68] = A_;
  float (*C_)[68]  = KV_;
  float (*w_)[68]  = T_;
  if (tid < 64) {
    const int m = tid;
    float M = -1e30f;
    for (int j = 0; j < NCH_; ++j)
      M = fmaxf(M, mpart[((size_t)bh * NCH_ + j) * 64 + m]);
    float denom = 0.f;
    for (int j = 0; j < NCH_; ++j)
      denom += expf(mpart[((size_t)bh * NCH_ + j) * 64 + m] - M) *
               lpart[((size_t)bh * NCH_ + j) * 64 + m];
    const float inv = 1.f / denom;
    for (int j = 0; j < NCH_; ++j)
      w_[m][j] = expf(mpart[((size_t)bh * NCH_ + j) * 64 + m] - M) * inv;
  }
  __syncthreads();
  const int mgB = tid >> 4, dq = (tid & 15) * 4;
#pragma unroll
  for (int i = 0; i < 2; ++i) {
    const int m = mgB + 32 * i;
    float4 acc = make_float4(0.f, 0.f, 0.f, 0.f);
    for (int j = 0; j < NCH_; ++j) {
      const float ww = w_[m][j];
      const float4 o = *(const float4*)&Opart[(((size_t)bh * NCH_ + j) * 64 + m) * 64 + dq];
      acc.x += ww * o.x; acc.y += ww * o.y; acc.z += ww * o.z; acc.w += ww * o.w;
    }
    *(float4*)&W1s[m][dq] = acc;
  }
  __syncthreads();
  mm64w(C_, V_, W1s, tid);
  __syncthreads();
  for (int idx = tid; idx < 4096; idx += 512)
    W2[(size_t)bh * 4096 + idx] = C_[idx >> 6][idx & 63];
}

// =============================================================
// k3v pass 1 (unchanged from round 9)
// =============================================================
__global__ __launch_bounds__(256) void k3v_pass1(
    const float* __restrict__ Ql, const u16* __restrict__ Kh,
    const u16* __restrict__ Vh, float* __restrict__ Opart,
    float* __restrict__ mpart, float* __restrict__ lpart)
{
  __shared__ float P[64][129];
  __shared__ float red1[64][4], red2[64][4];

  const int ch = blockIdx.x;
  const int bh = blockIdx.y;
  const int tid = threadIdx.x;
  const int wave = tid >> 6, lane = tid & 63;
  const int lr = lane & 15, kg = lane >> 4;

  const float* Qlb = Ql + (size_t)bh * 4096;
  const u16*   Kb  = Kh + (size_t)bh * S_ * 64;
  const u16*   Vb  = Vh + (size_t)bh * S_ * 64;

  f16x8 ah[4][2], al[4][2];
#pragma unroll
  for (int mt = 0; mt < 4; ++mt)
#pragma unroll
    for (int kk = 0; kk < 2; ++kk) {
      const float* qr = Qlb + (size_t)(mt * 16 + lr) * 64 + kk * 32 + kg * 8;
      cvt8_hl(*(const float4*)qr, *(const float4*)(qr + 4), &ah[mt][kk], &al[mt][kk]);
    }

#pragma unroll
  for (int t = 0; t < 2; ++t) {
    const int s0 = (wave * 2 + t) * 16;
    const int srow = ch * SC_ + s0 + lr;
    f32x4 acc[4];
#pragma unroll
    for (int mt = 0; mt < 4; ++mt) acc[mt] = (f32x4){0.f, 0.f, 0.f, 0.f};
#pragma unroll
    for (int kk = 0; kk < 2; ++kk) {
      const f16x8 bhf = *(const f16x8*)&Kb[(size_t)srow * 64 + kk * 32 + kg * 8];
#pragma unroll
      for (int mt = 0; mt < 4; ++mt) {
        acc[mt] = __builtin_amdgcn_mfma_f32_16x16x32_f16(ah[mt][kk], bhf, acc[mt], 0, 0, 0);
        acc[mt] = __builtin_amdgcn_mfma_f32_16x16x32_f16(al[mt][kk], bhf, acc[mt], 0, 0, 0);
      }
    }
#pragma unroll
    for (int mt = 0; mt < 4; ++mt)
#pragma unroll
      for (int r = 0; r < 4; ++r)
        P[mt * 16 + kg * 4 + r][s0 + lr] = acc[mt][r] * 0.125f;
  }
  __syncthreads();

  const int r = tid >> 2, q = tid & 3;
  {
    float mx = -1e30f;
#pragma unroll
    for (int s = 0; s < 32; ++s) mx = fmaxf(mx, P[r][q * 32 + s]);
    red1[r][q] = mx;
  }
  __syncthreads();
  const float rowmax = fmaxf(fmaxf(red1[r][0], red1[r][1]),
                             fmaxf(red1[r][2], red1[r][3]));
  {
    float sum = 0.f;
#pragma unroll
    for (int s = 0; s < 32; ++s) {
      const float e = expf(P[r][q * 32 + s] - rowmax);
      P[r][q * 32 + s] = e;
      sum += e;
    }
    red2[r][q] = sum;
  }
  __syncthreads();
  if (q == 0) {
    const float rowsum = red2[r][0] + red2[r][1] + red2[r][2] + red2[r][3];
    mpart[((size_t)bh * NCH_ + ch) * 64 + r] = rowmax;
    lpart[((size_t)bh * NCH_ + ch) * 64 + r] = rowsum;
  }

  const int mg = tid >> 4, dq = (tid & 15) * 4;
  float4 oacc[4];
#pragma unroll
  for (int i = 0; i < 4; ++i) oacc[i] = make_float4(0.f, 0.f, 0.f, 0.f);
  for (int s = 0; s < SC_; ++s) {
    const ushort4 vv = *(const ushort4*)&Vb[(size_t)(ch * SC_ + s) * 64 + dq];
    const float4 v = make_float4(h2f(vv.x), h2f(vv.y), h2f(vv.z), h2f(vv.w));
#pragma unroll
    for (int i = 0; i < 4; ++i) {
      const float p = P[mg * 4 + i][s];
      oacc[i].x += p * v.x; oacc[i].y += p * v.y;
      oacc[i].z += p * v.z; oacc[i].w += p * v.w;
    }
  }
#pragma unroll
  for (int i = 0; i < 4; ++i) {
    const size_t o = (((size_t)bh * NCH_ + ch) * 64 + mg * 4 + i) * 64 + dq;
    *(float4*)&Opart[o] = oacc[i];
  }
}

// =============================================================
// FUSED attention + conv v3: compact code (runtime loops).
// scores MFMA -> P[128][70]; softmax (rinv folded into PV);
// PV = runtime m-pair loop (float2 P, float4 W2s);
// conv = register window, runtime chunk loop; split-fp16 out.
// =============================================================
__global__ __launch_bounds__(256) void attn_conv_fused(
    const u16* __restrict__ Qh, const u16* __restrict__ Klh,
    const float* __restrict__ W2, const u16* __restrict__ Vh,
    const float* __restrict__ cw,
    u16* __restrict__ Xch, u16* __restrict__ Xcl)
{
  __shared__ float P[128][70];
  __shared__ float W2s[64][68];
  __shared__ float rinv[128];
  __shared__ float cws[33];

  const int ch = blockIdx.x;     // 0..31
  const int bh = blockIdx.y;     // 0..23
  const int tid = threadIdx.x;
  const int wave = tid >> 6, lane = tid & 63;
  const int lr = lane & 15, kg = lane >> 4;
  const int b = bh / H_, h = bh % H_;
  const int s0 = ch * 128;

  if (tid < 33) cws[tid] = cw[h * 33 + tid];
  for (int idx = tid; idx < 4096; idx += 256)
    W2s[idx >> 6][idx & 63] = W2[(size_t)bh * 4096 + idx];

  // ---- scores: Q(fp16) @ Kl(fp16)^T via MFMA ----
  const u16* Klb = Klh + (size_t)bh * 4096;
  const u16* Qb  = Qh + (size_t)bh * S_ * 64;
  f16x8 bf[4][2];
#pragma unroll
  for (int nt = 0; nt < 4; ++nt)
#pragma unroll
    for (int kk = 0; kk < 2; ++kk)
      bf[nt][kk] = *(const f16x8*)&Klb[(size_t)(nt * 16 + lr) * 64 + kk * 32 + kg * 8];

#pragma unroll
  for (int t = 0; t < 2; ++t) {
    const int rloc = wave * 32 + t * 16;
    f16x8 af[2];
#pragma unroll
    for (int kk = 0; kk < 2; ++kk)
      af[kk] = *(const f16x8*)&Qb[(size_t)(s0 + rloc + lr) * 64 + kk * 32 + kg * 8];
    f32x4 acc[4];
#pragma unroll
    for (int nt = 0; nt < 4; ++nt) acc[nt] = (f32x4){0.f, 0.f, 0.f, 0.f};
#pragma unroll
    for (int kk = 0; kk < 2; ++kk)
#pragma unroll
      for (int nt = 0; nt < 4; ++nt)
        acc[nt] = __builtin_amdgcn_mfma_f32_16x16x32_f16(af[kk], bf[nt][kk], acc[nt], 0, 0, 0);
#pragma unroll
    for (int nt = 0; nt < 4; ++nt)
#pragma unroll
      for (int r = 0; r < 4; ++r)
        P[rloc + kg * 4 + r][nt * 16 + lr] = acc[nt][r] * 0.125f;
  }
  __syncthreads();

  // ---- softmax: 2 threads/row; P <- exp(P - mx), rinv = 1/sum ----
  {
    const int r = tid >> 1, q = (tid & 1) * 32;
    float mx = -1e30f;
    for (int s = 0; s < 32; ++s) mx = fmaxf(mx, P[r][q + s]);
    mx = fmaxf(mx, __shfl_xor(mx, 1));
    float sum = 0.f;
    for (int s = 0; s < 32; ++s) {
      const float e = expf(P[r][q + s] - mx);
      P[r][q + s] = e;
      sum += e;
    }
    sum += __shfl_xor(sum, 1);
    if ((tid & 1) == 0) rinv[r] = 1.f / sum;
  }
  __syncthreads();

  // ---- PV: thread (rq,dq) owns 8 rows x 4 cols; runtime m-pair loop ----
  const int rq = tid >> 4, dq = (tid & 15) * 4;
  float4 o[8];
#pragma unroll
  for (int i = 0; i < 8; ++i) o[i] = make_float4(0.f, 0.f, 0.f, 0.f);
#pragma clang loop unroll_count(2)
  for (int m2 = 0; m2 < 32; ++m2) {
    const int m = m2 * 2;
    const float4 w0 = *(const float4*)&W2s[m][dq];
    const float4 w1 = *(const float4*)&W2s[m + 1][dq];
#pragma unroll
    for (int i = 0; i < 8; ++i) {
      const float2 p = *(const float2*)&P[rq * 8 + i][m];
      o[i].x += p.x * w0.x + p.y * w1.x;
      o[i].y += p.x * w0.y + p.y * w1.y;
      o[i].z += p.x * w0.z + p.y * w1.z;
      o[i].w += p.x * w0.w + p.y * w1.w;
    }
  }
  __syncthreads();
#pragma unroll
  for (int i = 0; i < 8; ++i) {
    const float ri = rinv[rq * 8 + i];
    *(float2*)&P[rq * 8 + i][dq]     = make_float2(o[i].x * ri, o[i].y * ri);
    *(float2*)&P[rq * 8 + i][dq + 2] = make_float2(o[i].z * ri, o[i].w * ri);
  }
  __syncthreads();

  // ---- conv: register sliding window, runtime chunk loop ----
  const int d = tid & 63, rg = tid >> 6;        // 4 waves x 32 rows
  const int rbase = s0 + rg * 32;
  const u16* Vd = Vh + (size_t)bh * S_ * 64 + d;

  float v[40];
#pragma unroll
  for (int j = 0; j < 40; ++j) {
    const int sv = rbase - 16 + j;
    v[j] = (sv >= 0 && sv < S_) ? h2f(Vd[(size_t)sv * 64]) : 0.f;
  }

#pragma clang loop unroll(disable)
  for (int c = 0; c < 4; ++c) {                 // 4 chunks of 8 rows
#pragma unroll
    for (int rr = 0; rr < 8; ++rr) {
      float acc = 0.f;
#pragma unroll
      for (int t = 0; t < 33; ++t) acc += v[rr + t] * cws[t];
      const int row = rg * 32 + c * 8 + rr;     // 0..127
      const float oo = P[row][d] + acc;
      const size_t idx = ((size_t)(b * S_ + s0 + row)) * HID_ + h * 64 + d;
      const u16 hh = f2h_bits(oo);
      Xch[idx] = hh;
      Xcl[idx] = f2h_bits(oo - h2f(hh));
    }
    if (c < 3) {
#pragma unroll
      for (int j = 0; j < 32; ++j) v[j] = v[j + 8];
#pragma unroll
      for (int j = 0; j < 8; ++j) {
        const int sv = rbase + 24 + c * 8 + j;
        v[32 + j] = (sv >= 0 && sv < S_) ? h2f(Vd[(size_t)sv * 64]) : 0.f;
      }
    }
  }
}

// =============================================================
extern "C" void kernel_launch(void* const* d_in, const int* in_sizes, int n_in,
                              void* d_out, int out_size, void* d_ws, size_t ws_size,
                              hipStream_t stream)
{
  (void)in_sizes; (void)n_in; (void)out_size; (void)ws_size;
  const float* x      = (const float*)d_in[0];
  const float* qkv_w  = (const float*)d_in[1];
  const float* qkv_b  = (const float*)d_in[2];
  const float* conv_w = (const float*)d_in[3];
  const float* out_w  = (const float*)d_in[4];
  const float* out_b  = (const float*)d_in[5];
  float* out = (float*)d_out;

  float* ws = (float*)d_ws;
  u16* Qh = (u16*)ws;
  u16* Kh = Qh + 6291456;
  u16* Vh = Kh + 6291456;
  float* Ql = ws + 9437184;
  float* Kl = Ql + 98304;
  float* K2 = Kl + 98304;
  float* W2 = K2 + 98304;
  float* colmax = W2 + 98304;
  float* rowmax = colmax + 32;
  u16* Klh = (u16*)(rowmax + 32);
  float* nxt = rowmax + 32 + 49152;
  u16* Xh  = (u16*)nxt;
  u16* Xl  = Xh + 6291456;
  u16* Wqh = Xl + 6291456;
  u16* Woh = Wqh + 1769472;
  u16* Xch = Xh;
  u16* Xcl = Xl;
  float* Opart = (float*)Xh;
  float* mpart = (float*)Xl;
  float* lpart = mpart + BH_ * NCH_ * 64;

  split3<<<(N8X + N8WQ + N8WO + 255) / 256, 256, 0, stream>>>(
      x, qkv_w, out_w, Xh, Wqh, Woh);

  gemm_mfma<0, 1><<<dim3(36, 64), 256, 0, stream>>>(
      Xh, nullptr, Wqh, qkv_b, nullptr, Qh, Kh, Vh, Ql, Kl, Klh);

  kernel2_softmax<<<BH_, 256, 0, stream>>>(Ql, Kl, K2, colmax, rowmax);

  k3v_pass1<<<dim3(NCH_, BH_), 256, 0, stream>>>(Ql, Kh, Vh, Opart, mpart, lpart);

  newton_combine<<<BH_, 512, 0, stream>>>(K2, colmax, rowmax,
                                          Opart, mpart, lpart, W2);

  attn_conv_fused<<<dim3(NCH_, BH_), 256, 0, stream>>>(
      Qh, Klh, W2, Vh, conv_w, Xch, Xcl);

  gemm_mfma<1, 2><<<dim3(6, 128), 256, 0, stream>>>(
      Xch, Xcl, Woh, out_b, out, nullptr, nullptr, nullptr,
      nullptr, nullptr, nullptr);
}

// Round 11
// 240.292 us; speedup vs baseline: 1.1620x; 1.1073x over previous
//
#include <hip/hip_runtime.h>
#include <math.h>

#define B_   2
#define S_   4096
#define HID_ 768
#define H_   12
#define D_   64
#define M_   64
#define CK_  33
#define BH_  (B_*H_)   // 24
#define KD_  768
#define NCH_ 32        // S-chunks (128 rows each)
#define SC_  128       // keys per chunk

typedef float  f32x4  __attribute__((ext_vector_type(4)));
typedef _Float16 f16x8 __attribute__((ext_vector_type(8)));
typedef unsigned short u16;

__device__ __forceinline__ u16 f2h_bits(float f) {
  union { _Float16 h; u16 u; } c; c.h = (_Float16)f; return c.u;
}
__device__ __forceinline__ float h2f(u16 b) {
  union { _Float16 h; u16 u; } c; c.u = b; return (float)c.h;
}
__device__ __forceinline__ void cvt8_hl(const float4 a, const float4 b,
                                        f16x8* hi, f16x8* lo) {
  const float v[8] = {a.x, a.y, a.z, a.w, b.x, b.y, b.z, b.w};
  f16x8 H, L;
#pragma unroll
  for (int e = 0; e < 8; ++e) {
    const _Float16 hh = (_Float16)v[e];
    H[e] = hh;
    L[e] = (_Float16)(v[e] - (float)hh);
  }
  *hi = H; *lo = L;
}

__device__ __forceinline__ void gld16(const void* g, void* l) {
  __builtin_amdgcn_global_load_lds(
      (const __attribute__((address_space(1))) void*)g,
      (__attribute__((address_space(3))) void*)l, 16, 0, 0);
}

// =============================================================
// Downcast: x -> Xh, qkv_w -> Wqh, out_w -> Woh (fp16 hi only)
// =============================================================
#define N8X  786432
#define N8WQ 221184
#define N8WO 73728
__global__ __launch_bounds__(256) void split3(
    const float* __restrict__ x, const float* __restrict__ qkv_w,
    const float* __restrict__ out_w,
    u16* __restrict__ Xh, u16* __restrict__ Wqh, u16* __restrict__ Woh)
{
  const int i = blockIdx.x * 256 + threadIdx.x;
  const float* src; u16* dst; int j;
  if (i < N8X)                 { src = x;     dst = Xh;  j = i; }
  else if (i < N8X + N8WQ)     { src = qkv_w; dst = Wqh; j = i - N8X; }
  else if (i < N8X + N8WQ + N8WO) { src = out_w; dst = Woh; j = i - N8X - N8WQ; }
  else return;
  const float4 a = ((const float4*)src)[2 * j], b = ((const float4*)src)[2 * j + 1];
  const float v[8] = {a.x, a.y, a.z, a.w, b.x, b.y, b.z, b.w};
  union { u16 u[8]; uint4 q; } hv;
#pragma unroll
  for (int e = 0; e < 8; ++e) hv.u[e] = f2h_bits(v[e]);
  ((uint4*)dst)[j] = hv.q;
}

// =============================================================
// fp16 MFMA GEMM: C = A @ W^T (+bias)
// MODE 0: tile 128x64, PROD=1, scatter Q/K/V fp16, fused landmarks.
// MODE 1: tile 64x128, PROD=2, row-major f32 out.
// =============================================================
template<int MODE, int PROD>
__global__ __launch_bounds__(256) void gemm_mfma(
    const u16* __restrict__ Ahg, const u16* __restrict__ Alg,
    const u16* __restrict__ Bhg,
    const float* __restrict__ bias,
    float* __restrict__ oF, u16* __restrict__ oQ, u16* __restrict__ oK,
    u16* __restrict__ oV,
    float* __restrict__ Ql, float* __restrict__ Kl, u16* __restrict__ Klh)
{
  constexpr int BM = (MODE == 0) ? 128 : 64;
  constexpr int BN = (MODE == 0) ? 64 : 128;
  constexpr int NBX = (MODE == 0) ? 36 : 6;
  constexpr int WM = BM / 2, WN = BN / 2;
  constexpr int MF = WM / 16, NF = WN / 16;
  constexpr int AINST = BM / 64, BINST = BN / 64;
  constexpr int ABUF = BM * 32;
  constexpr int BUFSZ = ABUF * PROD + BN * 32;
  constexpr int NT = KD_ / 32;
  constexpr int NWG = NBX * (8192 / BM);
  constexpr int CPX = NWG / 8;

  __shared__ __align__(16) u16 lds[2][BUFSZ];

  const int tid = threadIdx.x;
  const int lin = blockIdx.y * NBX + blockIdx.x;
  const int swb = (lin & 7) * CPX + (lin >> 3);
  const int m0 = (swb / NBX) * BM;
  const int n0 = (swb % NBX) * BN;

  const int wave = tid >> 6, lane = tid & 63;
  const int wm = wave >> 1, wn = wave & 1;
  const int lr = lane & 15, kg = lane >> 4;

  const int srow = tid >> 2;
  const int swz_s = (tid >> 3) & 3;
  const int sk = ((tid & 3) ^ swz_s) * 8;

  const u16* pAh = Ahg + (size_t)(m0 + srow) * KD_ + sk;
  const u16* pAl = (PROD == 2) ? (Alg + (size_t)(m0 + srow) * KD_ + sk) : nullptr;
  const u16* pBh = Bhg + (size_t)(n0 + srow) * KD_ + sk;

  f32x4 acc[MF][NF];
#pragma unroll
  for (int i = 0; i < MF; ++i)
#pragma unroll
    for (int j = 0; j < NF; ++j) acc[i][j] = (f32x4){0.f, 0.f, 0.f, 0.f};

  const int rsw = (lr >> 1) & 3;
  const int kq = (kg ^ rsw) * 8;
  const int abase = (wm * WM + lr) * 32 + kq;
  const int bbase = (wn * WN + lr) * 32 + kq;

#define STAGE_(buf, kt) do {                                              \
    const size_t go_ = (size_t)(kt) * 32;                                 \
    u16* L_ = &lds[buf][0];                                               \
    gld16(pAh + go_, L_ + tid * 8);                                       \
    if (AINST == 2) gld16(pAh + go_ + 64 * KD_, L_ + 2048 + tid * 8);     \
    if (PROD == 2) {                                                      \
      gld16(pAl + go_, L_ + ABUF + tid * 8);                              \
      if (AINST == 2) gld16(pAl + go_ + 64 * KD_, L_ + ABUF + 2048 + tid * 8); \
    }                                                                     \
    gld16(pBh + go_, L_ + ABUF * PROD + tid * 8);                         \
    if (BINST == 2) gld16(pBh + go_ + 64 * KD_, L_ + ABUF * PROD + 2048 + tid * 8); \
  } while (0)

  STAGE_(0, 0);
  __syncthreads();

  int cur = 0;
  for (int kt = 0; kt < NT; ++kt) {
    if (kt + 1 < NT) STAGE_(cur ^ 1, kt + 1);

    const u16* L_ = &lds[cur][0];
    f16x8 ah[MF], al[MF], bh[NF];
#pragma unroll
    for (int i = 0; i < MF; ++i) {
      ah[i] = *(const f16x8*)&L_[abase + i * 512];
      if (PROD == 2) al[i] = *(const f16x8*)&L_[ABUF + abase + i * 512];
    }
#pragma unroll
    for (int j = 0; j < NF; ++j)
      bh[j] = *(const f16x8*)&L_[ABUF * PROD + bbase + j * 512];
#pragma unroll
    for (int i = 0; i < MF; ++i)
#pragma unroll
      for (int j = 0; j < NF; ++j) {
        acc[i][j] = __builtin_amdgcn_mfma_f32_16x16x32_f16(ah[i], bh[j], acc[i][j], 0, 0, 0);
        if (PROD == 2)
          acc[i][j] = __builtin_amdgcn_mfma_f32_16x16x32_f16(al[i], bh[j], acc[i][j], 0, 0, 0);
      }

    __syncthreads();
    cur ^= 1;
  }
#undef STAGE_

  if (MODE == 0) {
    const int part = n0 / 768;
    const int h0 = (n0 - part * 768) >> 6;
    u16* base = (part == 0) ? oQ : ((part == 1) ? oK : oV);
#pragma unroll
    for (int i = 0; i < MF; ++i) {
      const int mbase = m0 + wm * WM + i * 16 + kg * 4;
#pragma unroll
      for (int j = 0; j < NF; ++j) {
        const int d = wn * WN + j * 16 + lr;
        const float bv = bias[n0 + d];
#pragma unroll
        for (int r = 0; r < 4; ++r) {
          const int row = mbase + r;
          const int b = row >> 12, s = row & (S_ - 1);
          base[(((size_t)(b * H_ + h0) * S_ + s) << 6) + d] = f2h_bits(acc[i][j][r] + bv);
        }
      }
    }
    if (part < 2) {
      const int rowseg = m0 + wm * WM;
      const int b = rowseg >> 12;
      const int seg = (rowseg & (S_ - 1)) >> 6;
      const int bhh = b * H_ + h0;
      float* dst = (part == 0) ? Ql : Kl;
#pragma unroll
      for (int j = 0; j < NF; ++j) {
        float sj = 0.f;
#pragma unroll
        for (int i = 0; i < MF; ++i)
#pragma unroll
          for (int r = 0; r < 4; ++r) sj += acc[i][j][r];
        sj += __shfl_xor(sj, 16);
        sj += __shfl_xor(sj, 32);
        if (kg == 0) {
          const int d = wn * WN + j * 16 + lr;
          const float lm = sj * (1.f / 64.f) + bias[n0 + d];
          dst[((size_t)bhh * M_ + seg) * 64 + d] = lm;
          if (part == 1) Klh[((size_t)bhh * M_ + seg) * 64 + d] = f2h_bits(lm);
        }
      }
    }
  } else {
#pragma unroll
    for (int i = 0; i < MF; ++i) {
      const int mbase = m0 + wm * WM + i * 16 + kg * 4;
#pragma unroll
      for (int j = 0; j < NF; ++j) {
        const int ncol = n0 + wn * WN + j * 16 + lr;
        const float bv = bias[ncol];
#pragma unroll
        for (int r = 0; r < 4; ++r) {
          const int row = mbase + r;
          oF[(size_t)row * HID_ + ncol] = acc[i][j][r] + bv;
        }
      }
    }
  }
}

// =============================================================
// kernel_2 softmax + per-(b,h) max col/row sums
// =============================================================
__global__ __launch_bounds__(256) void kernel2_softmax(
    const float* __restrict__ Ql, const float* __restrict__ Kl,
    float* __restrict__ K2, float* __restrict__ colmax, float* __restrict__ rowmax)
{
  __shared__ float Qs[64][68], Ks[64][68], S2[64][68];
  __shared__ float red1[64], red2[64];
  const int bh = blockIdx.x, tid = threadIdx.x;
  for (int idx = tid; idx < 4096; idx += 256) {
    const int r = idx >> 6, c = idx & 63;
    Qs[r][c] = Ql[(size_t)bh * 4096 + idx];
    Ks[r][c] = Kl[(size_t)bh * 4096 + idx];
  }
  __syncthreads();
  for (int idx = tid; idx < 4096; idx += 256) {
    const int r = idx >> 6, c = idx & 63;
    float dot = 0.f;
#pragma unroll
    for (int k = 0; k < 64; k += 4) {
      const float4 a = *(const float4*)&Qs[r][k];
      const float4 b = *(const float4*)&Ks[c][k];
      dot += a.x * b.x + a.y * b.y + a.z * b.z + a.w * b.w;
    }
    S2[r][c] = dot * 0.125f;
  }
  __syncthreads();
  if (tid < 64) {
    const int r = tid;
    float mx = -1e30f;
    for (int c = 0; c < 64; ++c) mx = fmaxf(mx, S2[r][c]);
    float sum = 0.f;
    for (int c = 0; c < 64; ++c) { const float e = expf(S2[r][c] - mx); S2[r][c] = e; sum += e; }
    const float inv = 1.f / sum;
    for (int c = 0; c < 64; ++c) S2[r][c] *= inv;
  }
  __syncthreads();
  for (int idx = tid; idx < 4096; idx += 256)
    K2[(size_t)bh * 4096 + idx] = S2[idx >> 6][idx & 63];
  if (tid < 64) {
    float cs = 0.f, rs = 0.f;
    for (int m = 0; m < 64; ++m) { cs += S2[m][tid]; rs += S2[tid][m]; }
    red1[tid] = cs; red2[tid] = rs;
  }
  __syncthreads();
  if (tid == 0) {
    float mc = 0.f, mr = 0.f;
    for (int i = 0; i < 64; ++i) { mc = fmaxf(mc, red1[i]); mr = fmaxf(mr, red2[i]); }
    colmax[bh] = mc; rowmax[bh] = mr;
  }
}

// 64x64x64 matmul in LDS, 512 threads (2x4 per thread)
__device__ inline void mm64w(float (*C)[68], float (*A)[68], float (*B)[68], int tid)
{
  const int r0 = (tid >> 4) * 2;
  const int c0 = (tid & 15) * 4;
  float acc[2][4];
#pragma unroll
  for (int i = 0; i < 2; ++i)
#pragma unroll
    for (int j = 0; j < 4; ++j) acc[i][j] = 0.f;
  for (int k = 0; k < 64; k += 4) {
    float4 a[2], b[4];
#pragma unroll
    for (int i = 0; i < 2; ++i) a[i] = *(const float4*)&A[r0 + i][k];
#pragma unroll
    for (int j = 0; j < 4; ++j) b[j] = *(const float4*)&B[k + j][c0];
    const float bb[4][4] = {{b[0].x, b[0].y, b[0].z, b[0].w},
                            {b[1].x, b[1].y, b[1].z, b[1].w},
                            {b[2].x, b[2].y, b[2].z, b[2].w},
                            {b[3].x, b[3].y, b[3].z, b[3].w}};
    const float aa[2][4] = {{a[0].x, a[0].y, a[0].z, a[0].w},
                            {a[1].x, a[1].y, a[1].z, a[1].w}};
#pragma unroll
    for (int i = 0; i < 2; ++i)
#pragma unroll
      for (int j = 0; j < 4; ++j)
#pragma unroll
        for (int kk = 0; kk < 4; ++kk) acc[i][j] += aa[i][kk] * bb[kk][j];
  }
#pragma unroll
  for (int i = 0; i < 2; ++i)
    *(float4*)&C[r0 + i][c0] = make_float4(acc[i][0], acc[i][1], acc[i][2], acc[i][3]);
}

// =============================================================
// FUSED: Newton-Schulz pinv + k3v combine + W2 = Vinv @ W1
// =============================================================
__global__ __launch_bounds__(512) void newton_combine(
    const float* __restrict__ K2, const float* __restrict__ colmax,
    const float* __restrict__ rowmax,
    const float* __restrict__ Opart, const float* __restrict__ mpart,
    const float* __restrict__ lpart, float* __restrict__ W2)
{
  __shared__ float A_[64][68], V_[64][68], KV_[64][68], T_[64][68], U_[64][68];
  __shared__ float scale_s;
  const int bh = blockIdx.x, tid = threadIdx.x;
  if (tid == 0) {
    float mc = 0.f, mr = 0.f;
    for (int i = 0; i < BH_; ++i) { mc = fmaxf(mc, colmax[i]); mr = fmaxf(mr, rowmax[i]); }
    scale_s = 1.f / (mc * mr);
  }
  for (int idx = tid; idx < 4096; idx += 512)
    A_[idx >> 6][idx & 63] = K2[(size_t)bh * 4096 + idx];
  __syncthreads();
  const float scale = scale_s;
  for (int idx = tid; idx < 4096; idx += 512) {
    const int r = idx >> 6, c = idx & 63;
    V_[r][c] = scale * A_[c][r];
  }
  __syncthreads();
  for (int it = 0; it < 6; ++it) {
    mm64w(KV_, A_, V_, tid); __syncthreads();
    for (int idx = tid; idx < 4096; idx += 512) {
      const int r = idx >> 6, c = idx & 63;
      T_[r][c] = (r == c ? 7.f : 0.f) - KV_[r][c];
    }
    __syncthreads();
    mm64w(U_, KV_, T_, tid); __syncthreads();
    for (int idx = tid; idx < 4096; idx += 512) {
      const int r = idx >> 6, c = idx & 63;
      T_[r][c] = (r == c ? 15.f : 0.f) - U_[r][c];
    }
    __syncthreads();
    mm64w(U_, KV_, T_, tid); __syncthreads();
    for (int idx = tid; idx < 4096; idx += 512) {
      const int r = idx >> 6, c = idx & 63;
      T_[r][c] = (r == c ? 13.f : 0.f) - U_[r][c];
    }
    __syncthreads();
    mm64w(U_, V_, T_, tid); __syncthreads();
    for (int idx = tid; idx < 4096; idx += 512) {
      const int r = idx >> 6, c = idx & 63;
      V_[r][c] = 0.25f * U_[r][c];
    }
    __syncthreads();
  }
  float (*W1s)[68] = A_;
  float (*C_)[68]  = KV_;
  float (*w_)[68]  = T_;
  if (tid < 64) {
    const int m = tid;
    float M = -1e30f;
    for (int j = 0; j < NCH_; ++j)
      M = fmaxf(M, mpart[((size_t)bh * NCH_ + j) * 64 + m]);
    float denom = 0.f;
    for (int j = 0; j < NCH_; ++j)
      denom += expf(mpart[((size_t)bh * NCH_ + j) * 64 + m] - M) *
               lpart[((size_t)bh * NCH_ + j) * 64 + m];
    const float inv = 1.f / denom;
    for (int j = 0; j < NCH_; ++j)
      w_[m][j] = expf(mpart[((size_t)bh * NCH_ + j) * 64 + m] - M) * inv;
  }
  __syncthreads();
  const int mgB = tid >> 4, dq = (tid & 15) * 4;
#pragma unroll
  for (int i = 0; i < 2; ++i) {
    const int m = mgB + 32 * i;
    float4 acc = make_float4(0.f, 0.f, 0.f, 0.f);
    for (int j = 0; j < NCH_; ++j) {
      const float ww = w_[m][j];
      const float4 o = *(const float4*)&Opart[(((size_t)bh * NCH_ + j) * 64 + m) * 64 + dq];
      acc.x += ww * o.x; acc.y += ww * o.y; acc.z += ww * o.z; acc.w += ww * o.w;
    }
    *(float4*)&W1s[m][dq] = acc;
  }
  __syncthreads();
  mm64w(C_, V_, W1s, tid);
  __syncthreads();
  for (int idx = tid; idx < 4096; idx += 512)
    W2[(size_t)bh * 4096 + idx] = C_[idx >> 6][idx & 63];
}

// =============================================================
// k3v pass 1 (unchanged)
// =============================================================
__global__ __launch_bounds__(256) void k3v_pass1(
    const float* __restrict__ Ql, const u16* __restrict__ Kh,
    const u16* __restrict__ Vh, float* __restrict__ Opart,
    float* __restrict__ mpart, float* __restrict__ lpart)
{
  __shared__ float P[64][129];
  __shared__ float red1[64][4], red2[64][4];

  const int ch = blockIdx.x;
  const int bh = blockIdx.y;
  const int tid = threadIdx.x;
  const int wave = tid >> 6, lane = tid & 63;
  const int lr = lane & 15, kg = lane >> 4;

  const float* Qlb = Ql + (size_t)bh * 4096;
  const u16*   Kb  = Kh + (size_t)bh * S_ * 64;
  const u16*   Vb  = Vh + (size_t)bh * S_ * 64;

  f16x8 ah[4][2], al[4][2];
#pragma unroll
  for (int mt = 0; mt < 4; ++mt)
#pragma unroll
    for (int kk = 0; kk < 2; ++kk) {
      const float* qr = Qlb + (size_t)(mt * 16 + lr) * 64 + kk * 32 + kg * 8;
      cvt8_hl(*(const float4*)qr, *(const float4*)(qr + 4), &ah[mt][kk], &al[mt][kk]);
    }

#pragma unroll
  for (int t = 0; t < 2; ++t) {
    const int s0 = (wave * 2 + t) * 16;
    const int srow = ch * SC_ + s0 + lr;
    f32x4 acc[4];
#pragma unroll
    for (int mt = 0; mt < 4; ++mt) acc[mt] = (f32x4){0.f, 0.f, 0.f, 0.f};
#pragma unroll
    for (int kk = 0; kk < 2; ++kk) {
      const f16x8 bhf = *(const f16x8*)&Kb[(size_t)srow * 64 + kk * 32 + kg * 8];
#pragma unroll
      for (int mt = 0; mt < 4; ++mt) {
        acc[mt] = __builtin_amdgcn_mfma_f32_16x16x32_f16(ah[mt][kk], bhf, acc[mt], 0, 0, 0);
        acc[mt] = __builtin_amdgcn_mfma_f32_16x16x32_f16(al[mt][kk], bhf, acc[mt], 0, 0, 0);
      }
    }
#pragma unroll
    for (int mt = 0; mt < 4; ++mt)
#pragma unroll
      for (int r = 0; r < 4; ++r)
        P[mt * 16 + kg * 4 + r][s0 + lr] = acc[mt][r] * 0.125f;
  }
  __syncthreads();

  const int r = tid >> 2, q = tid & 3;
  {
    float mx = -1e30f;
#pragma unroll
    for (int s = 0; s < 32; ++s) mx = fmaxf(mx, P[r][q * 32 + s]);
    red1[r][q] = mx;
  }
  __syncthreads();
  const float rowmax = fmaxf(fmaxf(red1[r][0], red1[r][1]),
                             fmaxf(red1[r][2], red1[r][3]));
  {
    float sum = 0.f;
#pragma unroll
    for (int s = 0; s < 32; ++s) {
      const float e = expf(P[r][q * 32 + s] - rowmax);
      P[r][q * 32 + s] = e;
      sum += e;
    }
    red2[r][q] = sum;
  }
  __syncthreads();
  if (q == 0) {
    const float rowsum = red2[r][0] + red2[r][1] + red2[r][2] + red2[r][3];
    mpart[((size_t)bh * NCH_ + ch) * 64 + r] = rowmax;
    lpart[((size_t)bh * NCH_ + ch) * 64 + r] = rowsum;
  }

  const int mg = tid >> 4, dq = (tid & 15) * 4;
  float4 oacc[4];
#pragma unroll
  for (int i = 0; i < 4; ++i) oacc[i] = make_float4(0.f, 0.f, 0.f, 0.f);
  for (int s = 0; s < SC_; ++s) {
    const ushort4 vv = *(const ushort4*)&Vb[(size_t)(ch * SC_ + s) * 64 + dq];
    const float4 v = make_float4(h2f(vv.x), h2f(vv.y), h2f(vv.z), h2f(vv.w));
#pragma unroll
    for (int i = 0; i < 4; ++i) {
      const float p = P[mg * 4 + i][s];
      oacc[i].x += p * v.x; oacc[i].y += p * v.y;
      oacc[i].z += p * v.z; oacc[i].w += p * v.w;
    }
  }
#pragma unroll
  for (int i = 0; i < 4; ++i) {
    const size_t o = (((size_t)bh * NCH_ + ch) * 64 + mg * 4 + i) * 64 + dq;
    *(float4*)&Opart[o] = oacc[i];
  }
}

// =============================================================
// FUSED attention + conv v4:
//   scores MFMA -> in-register softmax (shfl 16-lane groups)
//   P*(1/sum) -> fp16 LDS [128][76]; W2 hi/lo fp16 transposed [64][76]
//   PV via MFMA (2-product on W2 hi/lo) -> O fp32 LDS overlay
//   conv: register sliding window over fp16 V; split-fp16 out
// =============================================================
__global__ __launch_bounds__(256) void attn_conv_fused(
    const u16* __restrict__ Qh, const u16* __restrict__ Klh,
    const float* __restrict__ W2, const u16* __restrict__ Vh,
    const float* __restrict__ cw,
    u16* __restrict__ Xch, u16* __restrict__ Xcl)
{
  __shared__ __align__(16) u16 smem[19456];   // Ph[0,9728) W2Th[9728,14592) W2Tl[14592,19456)
  __shared__ float cws[33];

  const int ch = blockIdx.x;     // 0..31
  const int bh = blockIdx.y;     // 0..23
  const int tid = threadIdx.x;
  const int wave = tid >> 6, lane = tid & 63;
  const int lr = lane & 15, kg = lane >> 4;
  const int b = bh / H_, h = bh % H_;
  const int s0 = ch * 128;

  u16* Ph   = smem;
  u16* W2Th = smem + 9728;
  u16* W2Tl = smem + 14592;

  if (tid < 33) cws[tid] = cw[h * 33 + tid];
  // W2 -> hi/lo fp16, transposed [d][m], stride 76
  for (int idx = tid; idx < 4096; idx += 256) {
    const int m = idx >> 6, d = idx & 63;
    const float w = W2[(size_t)bh * 4096 + idx];
    const _Float16 hh = (_Float16)w;
    W2Th[d * 76 + m] = f2h_bits(w);
    W2Tl[d * 76 + m] = f2h_bits(w - (float)hh);
  }

  // ---- scores: Q(fp16) @ Kl(fp16)^T via MFMA ----
  const u16* Klb = Klh + (size_t)bh * 4096;
  const u16* Qb  = Qh + (size_t)bh * S_ * 64;
  f16x8 bf[4][2];
#pragma unroll
  for (int nt = 0; nt < 4; ++nt)
#pragma unroll
    for (int kk = 0; kk < 2; ++kk)
      bf[nt][kk] = *(const f16x8*)&Klb[(size_t)(nt * 16 + lr) * 64 + kk * 32 + kg * 8];

  f32x4 sacc[2][4];
#pragma unroll
  for (int t = 0; t < 2; ++t) {
#pragma unroll
    for (int nt = 0; nt < 4; ++nt) sacc[t][nt] = (f32x4){0.f, 0.f, 0.f, 0.f};
    const int rloc = wave * 32 + t * 16;
    f16x8 af[2];
#pragma unroll
    for (int kk = 0; kk < 2; ++kk)
      af[kk] = *(const f16x8*)&Qb[(size_t)(s0 + rloc + lr) * 64 + kk * 32 + kg * 8];
#pragma unroll
    for (int kk = 0; kk < 2; ++kk)
#pragma unroll
      for (int nt = 0; nt < 4; ++nt)
        sacc[t][nt] = __builtin_amdgcn_mfma_f32_16x16x32_f16(af[kk], bf[nt][kk], sacc[t][nt], 0, 0, 0);
  }

  // ---- in-register softmax (rows live in 16-lane groups) ----
#pragma unroll
  for (int t = 0; t < 2; ++t)
#pragma unroll
    for (int nt = 0; nt < 4; ++nt)
      sacc[t][nt] *= 0.125f;

  float rinv[2][4];
#pragma unroll
  for (int t = 0; t < 2; ++t) {
#pragma unroll
    for (int r = 0; r < 4; ++r) {
      float mx = fmaxf(fmaxf(sacc[t][0][r], sacc[t][1][r]),
                       fmaxf(sacc[t][2][r], sacc[t][3][r]));
      mx = fmaxf(mx, __shfl_xor(mx, 1));
      mx = fmaxf(mx, __shfl_xor(mx, 2));
      mx = fmaxf(mx, __shfl_xor(mx, 4));
      mx = fmaxf(mx, __shfl_xor(mx, 8));
      float sum = 0.f;
#pragma unroll
      for (int nt = 0; nt < 4; ++nt) {
        const float e = expf(sacc[t][nt][r] - mx);
        sacc[t][nt][r] = e;
        sum += e;
      }
      sum += __shfl_xor(sum, 1);
      sum += __shfl_xor(sum, 2);
      sum += __shfl_xor(sum, 4);
      sum += __shfl_xor(sum, 8);
      rinv[t][r] = 1.f / sum;
    }
  }

  // ---- write normalized P as fp16, row-major stride 76 ----
#pragma unroll
  for (int t = 0; t < 2; ++t)
#pragma unroll
    for (int nt = 0; nt < 4; ++nt)
#pragma unroll
      for (int r = 0; r < 4; ++r) {
        const int row = wave * 32 + t * 16 + kg * 4 + r;
        Ph[row * 76 + nt * 16 + lr] = f2h_bits(sacc[t][nt][r] * rinv[t][r]);
      }
  __syncthreads();

  // ---- PV via MFMA: O = P @ (W2h + W2l) ----
  f32x4 oacc[2][4];
#pragma unroll
  for (int t = 0; t < 2; ++t)
#pragma unroll
    for (int dt = 0; dt < 4; ++dt) oacc[t][dt] = (f32x4){0.f, 0.f, 0.f, 0.f};
#pragma unroll
  for (int kk = 0; kk < 2; ++kk) {
    f16x8 pa[2];
#pragma unroll
    for (int t = 0; t < 2; ++t)
      pa[t] = *(const f16x8*)&Ph[(wave * 32 + t * 16 + lr) * 76 + kk * 32 + kg * 8];
#pragma unroll
    for (int dt = 0; dt < 4; ++dt) {
      const f16x8 wh = *(const f16x8*)&W2Th[(dt * 16 + lr) * 76 + kk * 32 + kg * 8];
      const f16x8 wl = *(const f16x8*)&W2Tl[(dt * 16 + lr) * 76 + kk * 32 + kg * 8];
#pragma unroll
      for (int t = 0; t < 2; ++t) {
        oacc[t][dt] = __builtin_amdgcn_mfma_f32_16x16x32_f16(pa[t], wh, oacc[t][dt], 0, 0, 0);
        oacc[t][dt] = __builtin_amdgcn_mfma_f32_16x16x32_f16(pa[t], wl, oacc[t][dt], 0, 0, 0);
      }
    }
  }
  __syncthreads();             // all Ph/W2T reads done -> safe to overlay

  // ---- write O fp32 to LDS overlay [128][68] ----
  float* O = (float*)smem;
#pragma unroll
  for (int t = 0; t < 2; ++t)
#pragma unroll
    for (int dt = 0; dt < 4; ++dt)
#pragma unroll
      for (int r = 0; r < 4; ++r) {
        const int row = wave * 32 + t * 16 + kg * 4 + r;
        O[row * 68 + dt * 16 + lr] = oacc[t][dt][r];
      }
  __syncthreads();

  // ---- conv: register sliding window, runtime chunk loop ----
  const int d = tid & 63, rg = tid >> 6;        // 4 waves x 32 rows
  const int rbase = s0 + rg * 32;
  const u16* Vd = Vh + (size_t)bh * S_ * 64 + d;

  float v[40];
#pragma unroll
  for (int j = 0; j < 40; ++j) {
    const int sv = rbase - 16 + j;
    v[j] = (sv >= 0 && sv < S_) ? h2f(Vd[(size_t)sv * 64]) : 0.f;
  }

#pragma clang loop unroll(disable)
  for (int c = 0; c < 4; ++c) {                 // 4 chunks of 8 rows
#pragma unroll
    for (int rr = 0; rr < 8; ++rr) {
      float acc = 0.f;
#pragma unroll
      for (int t = 0; t < 33; ++t) acc += v[rr + t] * cws[t];
      const int row = rg * 32 + c * 8 + rr;     // 0..127
      const float oo = O[row * 68 + d] + acc;
      const size_t idx = ((size_t)(b * S_ + s0 + row)) * HID_ + h * 64 + d;
      const u16 hh = f2h_bits(oo);
      Xch[idx] = hh;
      Xcl[idx] = f2h_bits(oo - h2f(hh));
    }
    if (c < 3) {
#pragma unroll
      for (int j = 0; j < 32; ++j) v[j] = v[j + 8];
#pragma unroll
      for (int j = 0; j < 8; ++j) {
        const int sv = rbase + 24 + c * 8 + j;
        v[32 + j] = (sv >= 0 && sv < S_) ? h2f(Vd[(size_t)sv * 64]) : 0.f;
      }
    }
  }
}

// =============================================================
extern "C" void kernel_launch(void* const* d_in, const int* in_sizes, int n_in,
                              void* d_out, int out_size, void* d_ws, size_t ws_size,
                              hipStream_t stream)
{
  (void)in_sizes; (void)n_in; (void)out_size; (void)ws_size;
  const float* x      = (const float*)d_in[0];
  const float* qkv_w  = (const float*)d_in[1];
  const float* qkv_b  = (const float*)d_in[2];
  const float* conv_w = (const float*)d_in[3];
  const float* out_w  = (const float*)d_in[4];
  const float* out_b  = (const float*)d_in[5];
  float* out = (float*)d_out;

  float* ws = (float*)d_ws;
  u16* Qh = (u16*)ws;
  u16* Kh = Qh + 6291456;
  u16* Vh = Kh + 6291456;
  float* Ql = ws + 9437184;
  float* Kl = Ql + 98304;
  float* K2 = Kl + 98304;
  float* W2 = K2 + 98304;
  float* colmax = W2 + 98304;
  float* rowmax = colmax + 32;
  u16* Klh = (u16*)(rowmax + 32);
  float* nxt = rowmax + 32 + 49152;
  u16* Xh  = (u16*)nxt;
  u16* Xl  = Xh + 6291456;
  u16* Wqh = Xl + 6291456;
  u16* Woh = Wqh + 1769472;
  u16* Xch = Xh;
  u16* Xcl = Xl;
  float* Opart = (float*)Xh;
  float* mpart = (float*)Xl;
  float* lpart = mpart + BH_ * NCH_ * 64;

  split3<<<(N8X + N8WQ + N8WO + 255) / 256, 256, 0, stream>>>(
      x, qkv_w, out_w, Xh, Wqh, Woh);

  gemm_mfma<0, 1><<<dim3(36, 64), 256, 0, stream>>>(
      Xh, nullptr, Wqh, qkv_b, nullptr, Qh, Kh, Vh, Ql, Kl, Klh);

  kernel2_softmax<<<BH_, 256, 0, stream>>>(Ql, Kl, K2, colmax, rowmax);

  k3v_pass1<<<dim3(NCH_, BH_), 256, 0, stream>>>(Ql, Kh, Vh, Opart, mpart, lpart);

  newton_combine<<<BH_, 512, 0, stream>>>(K2, colmax, rowmax,
                                          Opart, mpart, lpart, W2);

  attn_conv_fused<<<dim3(NCH_, BH_), 256, 0, stream>>>(
      Qh, Klh, W2, Vh, conv_w, Xch, Xcl);

  gemm_mfma<1, 2><<<dim3(6, 128), 256, 0, stream>>>(
      Xch, Xcl, Woh, out_b, out, nullptr, nullptr, nullptr,
      nullptr, nullptr, nullptr);
}

// Round 12
// 238.902 us; speedup vs baseline: 1.1687x; 1.0058x over previous
//
#include <hip/hip_runtime.h>
#include <math.h>

#define B_   2
#define S_   4096
#define HID_ 768
#define H_   12
#define D_   64
#define M_   64
#define CK_  33
#define BH_  (B_*H_)   // 24
#define KD_  768
#define NCH_ 32        // S-chunks (128 rows each)
#define SC_  128       // keys per chunk

typedef float  f32x4  __attribute__((ext_vector_type(4)));
typedef _Float16 f16x8 __attribute__((ext_vector_type(8)));
typedef unsigned short u16;

__device__ __forceinline__ u16 f2h_bits(float f) {
  union { _Float16 h; u16 u; } c; c.h = (_Float16)f; return c.u;
}
__device__ __forceinline__ float h2f(u16 b) {
  union { _Float16 h; u16 u; } c; c.u = b; return (float)c.h;
}
__device__ __forceinline__ void cvt8_hl(const float4 a, const float4 b,
                                        f16x8* hi, f16x8* lo) {
  const float v[8] = {a.x, a.y, a.z, a.w, b.x, b.y, b.z, b.w};
  f16x8 H, L;
#pragma unroll
  for (int e = 0; e < 8; ++e) {
    const _Float16 hh = (_Float16)v[e];
    H[e] = hh;
    L[e] = (_Float16)(v[e] - (float)hh);
  }
  *hi = H; *lo = L;
}

__device__ __forceinline__ void gld16(const void* g, void* l) {
  __builtin_amdgcn_global_load_lds(
      (const __attribute__((address_space(1))) void*)g,
      (__attribute__((address_space(3))) void*)l, 16, 0, 0);
}

// =============================================================
// Downcast: x -> Xh, qkv_w -> Wqh, out_w -> Woh (fp16 hi only)
// =============================================================
#define N8X  786432
#define N8WQ 221184
#define N8WO 73728
__global__ __launch_bounds__(256) void split3(
    const float* __restrict__ x, const float* __restrict__ qkv_w,
    const float* __restrict__ out_w,
    u16* __restrict__ Xh, u16* __restrict__ Wqh, u16* __restrict__ Woh)
{
  const int i = blockIdx.x * 256 + threadIdx.x;
  const float* src; u16* dst; int j;
  if (i < N8X)                 { src = x;     dst = Xh;  j = i; }
  else if (i < N8X + N8WQ)     { src = qkv_w; dst = Wqh; j = i - N8X; }
  else if (i < N8X + N8WQ + N8WO) { src = out_w; dst = Woh; j = i - N8X - N8WQ; }
  else return;
  const float4 a = ((const float4*)src)[2 * j], b = ((const float4*)src)[2 * j + 1];
  const float v[8] = {a.x, a.y, a.z, a.w, b.x, b.y, b.z, b.w};
  union { u16 u[8]; uint4 q; } hv;
#pragma unroll
  for (int e = 0; e < 8; ++e) hv.u[e] = f2h_bits(v[e]);
  ((uint4*)dst)[j] = hv.q;
}

// =============================================================
// fp16 MFMA GEMM: C = A @ W^T (+bias)
// MODE 0: tile 128x64, PROD=1, scatter Q/K/V fp16, fused landmarks.
// MODE 1: tile 64x128, PROD=2, row-major f32 out.
// T4 pipeline: counted s_waitcnt vmcnt(NLOADS) + raw s_barrier —
// prefetch stays in flight across compute (never drain to 0 mid-loop).
// =============================================================
template<int MODE, int PROD>
__global__ __launch_bounds__(256) void gemm_mfma(
    const u16* __restrict__ Ahg, const u16* __restrict__ Alg,
    const u16* __restrict__ Bhg,
    const float* __restrict__ bias,
    float* __restrict__ oF, u16* __restrict__ oQ, u16* __restrict__ oK,
    u16* __restrict__ oV,
    float* __restrict__ Ql, float* __restrict__ Kl, u16* __restrict__ Klh)
{
  constexpr int BM = (MODE == 0) ? 128 : 64;
  constexpr int BN = (MODE == 0) ? 64 : 128;
  constexpr int NBX = (MODE == 0) ? 36 : 6;
  constexpr int WM = BM / 2, WN = BN / 2;
  constexpr int MF = WM / 16, NF = WN / 16;
  constexpr int AINST = BM / 64, BINST = BN / 64;
  constexpr int ABUF = BM * 32;
  constexpr int BUFSZ = ABUF * PROD + BN * 32;
  constexpr int NT = KD_ / 32;
  constexpr int NWG = NBX * (8192 / BM);
  constexpr int CPX = NWG / 8;
  constexpr int NLOADS = AINST * PROD + BINST;   // 3 (MODE0) / 4 (MODE1)

  __shared__ __align__(16) u16 lds[2][BUFSZ];

  const int tid = threadIdx.x;
  const int lin = blockIdx.y * NBX + blockIdx.x;
  const int swb = (lin & 7) * CPX + (lin >> 3);
  const int m0 = (swb / NBX) * BM;
  const int n0 = (swb % NBX) * BN;

  const int wave = tid >> 6, lane = tid & 63;
  const int wm = wave >> 1, wn = wave & 1;
  const int lr = lane & 15, kg = lane >> 4;

  const int srow = tid >> 2;
  const int swz_s = (tid >> 3) & 3;
  const int sk = ((tid & 3) ^ swz_s) * 8;

  const u16* pAh = Ahg + (size_t)(m0 + srow) * KD_ + sk;
  const u16* pAl = (PROD == 2) ? (Alg + (size_t)(m0 + srow) * KD_ + sk) : nullptr;
  const u16* pBh = Bhg + (size_t)(n0 + srow) * KD_ + sk;

  f32x4 acc[MF][NF];
#pragma unroll
  for (int i = 0; i < MF; ++i)
#pragma unroll
    for (int j = 0; j < NF; ++j) acc[i][j] = (f32x4){0.f, 0.f, 0.f, 0.f};

  const int rsw = (lr >> 1) & 3;
  const int kq = (kg ^ rsw) * 8;
  const int abase = (wm * WM + lr) * 32 + kq;
  const int bbase = (wn * WN + lr) * 32 + kq;

#define STAGE_(buf, kt) do {                                              \
    const size_t go_ = (size_t)(kt) * 32;                                 \
    u16* L_ = &lds[buf][0];                                               \
    gld16(pAh + go_, L_ + tid * 8);                                       \
    if (AINST == 2) gld16(pAh + go_ + 64 * KD_, L_ + 2048 + tid * 8);     \
    if (PROD == 2) {                                                      \
      gld16(pAl + go_, L_ + ABUF + tid * 8);                              \
      if (AINST == 2) gld16(pAl + go_ + 64 * KD_, L_ + ABUF + 2048 + tid * 8); \
    }                                                                     \
    gld16(pBh + go_, L_ + ABUF * PROD + tid * 8);                         \
    if (BINST == 2) gld16(pBh + go_ + 64 * KD_, L_ + ABUF * PROD + 2048 + tid * 8); \
  } while (0)

  STAGE_(0, 0);

  int cur = 0;
  for (int kt = 0; kt < NT; ++kt) {
    if (kt + 1 < NT) {
      STAGE_(cur ^ 1, kt + 1);
      // wait only for the PREVIOUS stage (oldest NLOADS); new ones stay in flight
      if constexpr (NLOADS == 3)
        asm volatile("s_waitcnt vmcnt(3)" ::: "memory");
      else
        asm volatile("s_waitcnt vmcnt(4)" ::: "memory");
    } else {
      asm volatile("s_waitcnt vmcnt(0)" ::: "memory");
    }
    __builtin_amdgcn_s_barrier();          // stage(cur) visible to all waves
    __builtin_amdgcn_sched_barrier(0);

    const u16* L_ = &lds[cur][0];
    f16x8 ah[MF], al[MF], bh[NF];
#pragma unroll
    for (int i = 0; i < MF; ++i) {
      ah[i] = *(const f16x8*)&L_[abase + i * 512];
      if (PROD == 2) al[i] = *(const f16x8*)&L_[ABUF + abase + i * 512];
    }
#pragma unroll
    for (int j = 0; j < NF; ++j)
      bh[j] = *(const f16x8*)&L_[ABUF * PROD + bbase + j * 512];
#pragma unroll
    for (int i = 0; i < MF; ++i)
#pragma unroll
      for (int j = 0; j < NF; ++j) {
        acc[i][j] = __builtin_amdgcn_mfma_f32_16x16x32_f16(ah[i], bh[j], acc[i][j], 0, 0, 0);
        if (PROD == 2)
          acc[i][j] = __builtin_amdgcn_mfma_f32_16x16x32_f16(al[i], bh[j], acc[i][j], 0, 0, 0);
      }

    __builtin_amdgcn_sched_barrier(0);
    __builtin_amdgcn_s_barrier();          // reads done before buf overwritten
    cur ^= 1;
  }
#undef STAGE_

  if (MODE == 0) {
    const int part = n0 / 768;
    const int h0 = (n0 - part * 768) >> 6;
    u16* base = (part == 0) ? oQ : ((part == 1) ? oK : oV);
#pragma unroll
    for (int i = 0; i < MF; ++i) {
      const int mbase = m0 + wm * WM + i * 16 + kg * 4;
#pragma unroll
      for (int j = 0; j < NF; ++j) {
        const int d = wn * WN + j * 16 + lr;
        const float bv = bias[n0 + d];
#pragma unroll
        for (int r = 0; r < 4; ++r) {
          const int row = mbase + r;
          const int b = row >> 12, s = row & (S_ - 1);
          base[(((size_t)(b * H_ + h0) * S_ + s) << 6) + d] = f2h_bits(acc[i][j][r] + bv);
        }
      }
    }
    if (part < 2) {
      const int rowseg = m0 + wm * WM;
      const int b = rowseg >> 12;
      const int seg = (rowseg & (S_ - 1)) >> 6;
      const int bhh = b * H_ + h0;
      float* dst = (part == 0) ? Ql : Kl;
#pragma unroll
      for (int j = 0; j < NF; ++j) {
        float sj = 0.f;
#pragma unroll
        for (int i = 0; i < MF; ++i)
#pragma unroll
          for (int r = 0; r < 4; ++r) sj += acc[i][j][r];
        sj += __shfl_xor(sj, 16);
        sj += __shfl_xor(sj, 32);
        if (kg == 0) {
          const int d = wn * WN + j * 16 + lr;
          const float lm = sj * (1.f / 64.f) + bias[n0 + d];
          dst[((size_t)bhh * M_ + seg) * 64 + d] = lm;
          if (part == 1) Klh[((size_t)bhh * M_ + seg) * 64 + d] = f2h_bits(lm);
        }
      }
    }
  } else {
#pragma unroll
    for (int i = 0; i < MF; ++i) {
      const int mbase = m0 + wm * WM + i * 16 + kg * 4;
#pragma unroll
      for (int j = 0; j < NF; ++j) {
        const int ncol = n0 + wn * WN + j * 16 + lr;
        const float bv = bias[ncol];
#pragma unroll
        for (int r = 0; r < 4; ++r) {
          const int row = mbase + r;
          oF[(size_t)row * HID_ + ncol] = acc[i][j][r] + bv;
        }
      }
    }
  }
}

// =============================================================
// kernel_2 softmax + per-(b,h) max col/row sums
// =============================================================
__global__ __launch_bounds__(256) void kernel2_softmax(
    const float* __restrict__ Ql, const float* __restrict__ Kl,
    float* __restrict__ K2, float* __restrict__ colmax, float* __restrict__ rowmax)
{
  __shared__ float Qs[64][68], Ks[64][68], S2[64][68];
  __shared__ float red1[64], red2[64];
  const int bh = blockIdx.x, tid = threadIdx.x;
  for (int idx = tid; idx < 4096; idx += 256) {
    const int r = idx >> 6, c = idx & 63;
    Qs[r][c] = Ql[(size_t)bh * 4096 + idx];
    Ks[r][c] = Kl[(size_t)bh * 4096 + idx];
  }
  __syncthreads();
  for (int idx = tid; idx < 4096; idx += 256) {
    const int r = idx >> 6, c = idx & 63;
    float dot = 0.f;
#pragma unroll
    for (int k = 0; k < 64; k += 4) {
      const float4 a = *(const float4*)&Qs[r][k];
      const float4 b = *(const float4*)&Ks[c][k];
      dot += a.x * b.x + a.y * b.y + a.z * b.z + a.w * b.w;
    }
    S2[r][c] = dot * 0.125f;
  }
  __syncthreads();
  if (tid < 64) {
    const int r = tid;
    float mx = -1e30f;
    for (int c = 0; c < 64; ++c) mx = fmaxf(mx, S2[r][c]);
    float sum = 0.f;
    for (int c = 0; c < 64; ++c) { const float e = expf(S2[r][c] - mx); S2[r][c] = e; sum += e; }
    const float inv = 1.f / sum;
    for (int c = 0; c < 64; ++c) S2[r][c] *= inv;
  }
  __syncthreads();
  for (int idx = tid; idx < 4096; idx += 256)
    K2[(size_t)bh * 4096 + idx] = S2[idx >> 6][idx & 63];
  if (tid < 64) {
    float cs = 0.f, rs = 0.f;
    for (int m = 0; m < 64; ++m) { cs += S2[m][tid]; rs += S2[tid][m]; }
    red1[tid] = cs; red2[tid] = rs;
  }
  __syncthreads();
  if (tid == 0) {
    float mc = 0.f, mr = 0.f;
    for (int i = 0; i < 64; ++i) { mc = fmaxf(mc, red1[i]); mr = fmaxf(mr, red2[i]); }
    colmax[bh] = mc; rowmax[bh] = mr;
  }
}

// 64x64x64 matmul in LDS, 512 threads (2x4 per thread)
__device__ inline void mm64w(float (*C)[68], float (*A)[68], float (*B)[68], int tid)
{
  const int r0 = (tid >> 4) * 2;
  const int c0 = (tid & 15) * 4;
  float acc[2][4];
#pragma unroll
  for (int i = 0; i < 2; ++i)
#pragma unroll
    for (int j = 0; j < 4; ++j) acc[i][j] = 0.f;
  for (int k = 0; k < 64; k += 4) {
    float4 a[2], b[4];
#pragma unroll
    for (int i = 0; i < 2; ++i) a[i] = *(const float4*)&A[r0 + i][k];
#pragma unroll
    for (int j = 0; j < 4; ++j) b[j] = *(const float4*)&B[k + j][c0];
    const float bb[4][4] = {{b[0].x, b[0].y, b[0].z, b[0].w},
                            {b[1].x, b[1].y, b[1].z, b[1].w},
                            {b[2].x, b[2].y, b[2].z, b[2].w},
                            {b[3].x, b[3].y, b[3].z, b[3].w}};
    const float aa[2][4] = {{a[0].x, a[0].y, a[0].z, a[0].w},
                            {a[1].x, a[1].y, a[1].z, a[1].w}};
#pragma unroll
    for (int i = 0; i < 2; ++i)
#pragma unroll
      for (int j = 0; j < 4; ++j)
#pragma unroll
        for (int kk = 0; kk < 4; ++kk) acc[i][j] += aa[i][kk] * bb[kk][j];
  }
#pragma unroll
  for (int i = 0; i < 2; ++i)
    *(float4*)&C[r0 + i][c0] = make_float4(acc[i][0], acc[i][1], acc[i][2], acc[i][3]);
}

// =============================================================
// FUSED: Newton-Schulz pinv + k3v combine + W2 = Vinv @ W1
// =============================================================
__global__ __launch_bounds__(512) void newton_combine(
    const float* __restrict__ K2, const float* __restrict__ colmax,
    const float* __restrict__ rowmax,
    const float* __restrict__ Opart, const float* __restrict__ mpart,
    const float* __restrict__ lpart, float* __restrict__ W2)
{
  __shared__ float A_[64][68], V_[64][68], KV_[64][68], T_[64][68], U_[64][68];
  __shared__ float scale_s;
  const int bh = blockIdx.x, tid = threadIdx.x;
  if (tid == 0) {
    float mc = 0.f, mr = 0.f;
    for (int i = 0; i < BH_; ++i) { mc = fmaxf(mc, colmax[i]); mr = fmaxf(mr, rowmax[i]); }
    scale_s = 1.f / (mc * mr);
  }
  for (int idx = tid; idx < 4096; idx += 512)
    A_[idx >> 6][idx & 63] = K2[(size_t)bh * 4096 + idx];
  __syncthreads();
  const float scale = scale_s;
  for (int idx = tid; idx < 4096; idx += 512) {
    const int r = idx >> 6, c = idx & 63;
    V_[r][c] = scale * A_[c][r];
  }
  __syncthreads();
  for (int it = 0; it < 6; ++it) {
    mm64w(KV_, A_, V_, tid); __syncthreads();
    for (int idx = tid; idx < 4096; idx += 512) {
      const int r = idx >> 6, c = idx & 63;
      T_[r][c] = (r == c ? 7.f : 0.f) - KV_[r][c];
    }
    __syncthreads();
    mm64w(U_, KV_, T_, tid); __syncthreads();
    for (int idx = tid; idx < 4096; idx += 512) {
      const int r = idx >> 6, c = idx & 63;
      T_[r][c] = (r == c ? 15.f : 0.f) - U_[r][c];
    }
    __syncthreads();
    mm64w(U_, KV_, T_, tid); __syncthreads();
    for (int idx = tid; idx < 4096; idx += 512) {
      const int r = idx >> 6, c = idx & 63;
      T_[r][c] = (r == c ? 13.f : 0.f) - U_[r][c];
    }
    __syncthreads();
    mm64w(U_, V_, T_, tid); __syncthreads();
    for (int idx = tid; idx < 4096; idx += 512) {
      const int r = idx >> 6, c = idx & 63;
      V_[r][c] = 0.25f * U_[r][c];
    }
    __syncthreads();
  }
  float (*W1s)[68] = A_;
  float (*C_)[68]  = KV_;
  float (*w_)[68]  = T_;
  if (tid < 64) {
    const int m = tid;
    float M = -1e30f;
    for (int j = 0; j < NCH_; ++j)
      M = fmaxf(M, mpart[((size_t)bh * NCH_ + j) * 64 + m]);
    float denom = 0.f;
    for (int j = 0; j < NCH_; ++j)
      denom += expf(mpart[((size_t)bh * NCH_ + j) * 64 + m] - M) *
               lpart[((size_t)bh * NCH_ + j) * 64 + m];
    const float inv = 1.f / denom;
    for (int j = 0; j < NCH_; ++j)
      w_[m][j] = expf(mpart[((size_t)bh * NCH_ + j) * 64 + m] - M) * inv;
  }
  __syncthreads();
  const int mgB = tid >> 4, dq = (tid & 15) * 4;
#pragma unroll
  for (int i = 0; i < 2; ++i) {
    const int m = mgB + 32 * i;
    float4 acc = make_float4(0.f, 0.f, 0.f, 0.f);
    for (int j = 0; j < NCH_; ++j) {
      const float ww = w_[m][j];
      const float4 o = *(const float4*)&Opart[(((size_t)bh * NCH_ + j) * 64 + m) * 64 + dq];
      acc.x += ww * o.x; acc.y += ww * o.y; acc.z += ww * o.z; acc.w += ww * o.w;
    }
    *(float4*)&W1s[m][dq] = acc;
  }
  __syncthreads();
  mm64w(C_, V_, W1s, tid);
  __syncthreads();
  for (int idx = tid; idx < 4096; idx += 512)
    W2[(size_t)bh * 4096 + idx] = C_[idx >> 6][idx & 63];
}

// =============================================================
// k3v pass 1 (unchanged)
// =============================================================
__global__ __launch_bounds__(256) void k3v_pass1(
    const float* __restrict__ Ql, const u16* __restrict__ Kh,
    const u16* __restrict__ Vh, float* __restrict__ Opart,
    float* __restrict__ mpart, float* __restrict__ lpart)
{
  __shared__ float P[64][129];
  __shared__ float red1[64][4], red2[64][4];

  const int ch = blockIdx.x;
  const int bh = blockIdx.y;
  const int tid = threadIdx.x;
  const int wave = tid >> 6, lane = tid & 63;
  const int lr = lane & 15, kg = lane >> 4;

  const float* Qlb = Ql + (size_t)bh * 4096;
  const u16*   Kb  = Kh + (size_t)bh * S_ * 64;
  const u16*   Vb  = Vh + (size_t)bh * S_ * 64;

  f16x8 ah[4][2], al[4][2];
#pragma unroll
  for (int mt = 0; mt < 4; ++mt)
#pragma unroll
    for (int kk = 0; kk < 2; ++kk) {
      const float* qr = Qlb + (size_t)(mt * 16 + lr) * 64 + kk * 32 + kg * 8;
      cvt8_hl(*(const float4*)qr, *(const float4*)(qr + 4), &ah[mt][kk], &al[mt][kk]);
    }

#pragma unroll
  for (int t = 0; t < 2; ++t) {
    const int s0 = (wave * 2 + t) * 16;
    const int srow = ch * SC_ + s0 + lr;
    f32x4 acc[4];
#pragma unroll
    for (int mt = 0; mt < 4; ++mt) acc[mt] = (f32x4){0.f, 0.f, 0.f, 0.f};
#pragma unroll
    for (int kk = 0; kk < 2; ++kk) {
      const f16x8 bhf = *(const f16x8*)&Kb[(size_t)srow * 64 + kk * 32 + kg * 8];
#pragma unroll
      for (int mt = 0; mt < 4; ++mt) {
        acc[mt] = __builtin_amdgcn_mfma_f32_16x16x32_f16(ah[mt][kk], bhf, acc[mt], 0, 0, 0);
        acc[mt] = __builtin_amdgcn_mfma_f32_16x16x32_f16(al[mt][kk], bhf, acc[mt], 0, 0, 0);
      }
    }
#pragma unroll
    for (int mt = 0; mt < 4; ++mt)
#pragma unroll
      for (int r = 0; r < 4; ++r)
        P[mt * 16 + kg * 4 + r][s0 + lr] = acc[mt][r] * 0.125f;
  }
  __syncthreads();

  const int r = tid >> 2, q = tid & 3;
  {
    float mx = -1e30f;
#pragma unroll
    for (int s = 0; s < 32; ++s) mx = fmaxf(mx, P[r][q * 32 + s]);
    red1[r][q] = mx;
  }
  __syncthreads();
  const float rowmax = fmaxf(fmaxf(red1[r][0], red1[r][1]),
                             fmaxf(red1[r][2], red1[r][3]));
  {
    float sum = 0.f;
#pragma unroll
    for (int s = 0; s < 32; ++s) {
      const float e = expf(P[r][q * 32 + s] - rowmax);
      P[r][q * 32 + s] = e;
      sum += e;
    }
    red2[r][q] = sum;
  }
  __syncthreads();
  if (q == 0) {
    const float rowsum = red2[r][0] + red2[r][1] + red2[r][2] + red2[r][3];
    mpart[((size_t)bh * NCH_ + ch) * 64 + r] = rowmax;
    lpart[((size_t)bh * NCH_ + ch) * 64 + r] = rowsum;
  }

  const int mg = tid >> 4, dq = (tid & 15) * 4;
  float4 oacc[4];
#pragma unroll
  for (int i = 0; i < 4; ++i) oacc[i] = make_float4(0.f, 0.f, 0.f, 0.f);
  for (int s = 0; s < SC_; ++s) {
    const ushort4 vv = *(const ushort4*)&Vb[(size_t)(ch * SC_ + s) * 64 + dq];
    const float4 v = make_float4(h2f(vv.x), h2f(vv.y), h2f(vv.z), h2f(vv.w));
#pragma unroll
    for (int i = 0; i < 4; ++i) {
      const float p = P[mg * 4 + i][s];
      oacc[i].x += p * v.x; oacc[i].y += p * v.y;
      oacc[i].z += p * v.z; oacc[i].w += p * v.w;
    }
  }
#pragma unroll
  for (int i = 0; i < 4; ++i) {
    const size_t o = (((size_t)bh * NCH_ + ch) * 64 + mg * 4 + i) * 64 + dq;
    *(float4*)&Opart[o] = oacc[i];
  }
}

// =============================================================
// FUSED attention + conv v4 (unchanged from round 11)
// =============================================================
__global__ __launch_bounds__(256) void attn_conv_fused(
    const u16* __restrict__ Qh, const u16* __restrict__ Klh,
    const float* __restrict__ W2, const u16* __restrict__ Vh,
    const float* __restrict__ cw,
    u16* __restrict__ Xch, u16* __restrict__ Xcl)
{
  __shared__ __align__(16) u16 smem[19456];   // Ph[0,9728) W2Th[9728,14592) W2Tl[14592,19456)
  __shared__ float cws[33];

  const int ch = blockIdx.x;
  const int bh = blockIdx.y;
  const int tid = threadIdx.x;
  const int wave = tid >> 6, lane = tid & 63;
  const int lr = lane & 15, kg = lane >> 4;
  const int b = bh / H_, h = bh % H_;
  const int s0 = ch * 128;

  u16* Ph   = smem;
  u16* W2Th = smem + 9728;
  u16* W2Tl = smem + 14592;

  if (tid < 33) cws[tid] = cw[h * 33 + tid];
  for (int idx = tid; idx < 4096; idx += 256) {
    const int m = idx >> 6, d = idx & 63;
    const float w = W2[(size_t)bh * 4096 + idx];
    const _Float16 hh = (_Float16)w;
    W2Th[d * 76 + m] = f2h_bits(w);
    W2Tl[d * 76 + m] = f2h_bits(w - (float)hh);
  }

  const u16* Klb = Klh + (size_t)bh * 4096;
  const u16* Qb  = Qh + (size_t)bh * S_ * 64;
  f16x8 bf[4][2];
#pragma unroll
  for (int nt = 0; nt < 4; ++nt)
#pragma unroll
    for (int kk = 0; kk < 2; ++kk)
      bf[nt][kk] = *(const f16x8*)&Klb[(size_t)(nt * 16 + lr) * 64 + kk * 32 + kg * 8];

  f32x4 sacc[2][4];
#pragma unroll
  for (int t = 0; t < 2; ++t) {
#pragma unroll
    for (int nt = 0; nt < 4; ++nt) sacc[t][nt] = (f32x4){0.f, 0.f, 0.f, 0.f};
    const int rloc = wave * 32 + t * 16;
    f16x8 af[2];
#pragma unroll
    for (int kk = 0; kk < 2; ++kk)
      af[kk] = *(const f16x8*)&Qb[(size_t)(s0 + rloc + lr) * 64 + kk * 32 + kg * 8];
#pragma unroll
    for (int kk = 0; kk < 2; ++kk)
#pragma unroll
      for (int nt = 0; nt < 4; ++nt)
        sacc[t][nt] = __builtin_amdgcn_mfma_f32_16x16x32_f16(af[kk], bf[nt][kk], sacc[t][nt], 0, 0, 0);
  }

#pragma unroll
  for (int t = 0; t < 2; ++t)
#pragma unroll
    for (int nt = 0; nt < 4; ++nt)
      sacc[t][nt] *= 0.125f;

  float rinv[2][4];
#pragma unroll
  for (int t = 0; t < 2; ++t) {
#pragma unroll
    for (int r = 0; r < 4; ++r) {
      float mx = fmaxf(fmaxf(sacc[t][0][r], sacc[t][1][r]),
                       fmaxf(sacc[t][2][r], sacc[t][3][r]));
      mx = fmaxf(mx, __shfl_xor(mx, 1));
      mx = fmaxf(mx, __shfl_xor(mx, 2));
      mx = fmaxf(mx, __shfl_xor(mx, 4));
      mx = fmaxf(mx, __shfl_xor(mx, 8));
      float sum = 0.f;
#pragma unroll
      for (int nt = 0; nt < 4; ++nt) {
        const float e = expf(sacc[t][nt][r] - mx);
        sacc[t][nt][r] = e;
        sum += e;
      }
      sum += __shfl_xor(sum, 1);
      sum += __shfl_xor(sum, 2);
      sum += __shfl_xor(sum, 4);
      sum += __shfl_xor(sum, 8);
      rinv[t][r] = 1.f / sum;
    }
  }

#pragma unroll
  for (int t = 0; t < 2; ++t)
#pragma unroll
    for (int nt = 0; nt < 4; ++nt)
#pragma unroll
      for (int r = 0; r < 4; ++r) {
        const int row = wave * 32 + t * 16 + kg * 4 + r;
        Ph[row * 76 + nt * 16 + lr] = f2h_bits(sacc[t][nt][r] * rinv[t][r]);
      }
  __syncthreads();

  f32x4 oacc[2][4];
#pragma unroll
  for (int t = 0; t < 2; ++t)
#pragma unroll
    for (int dt = 0; dt < 4; ++dt) oacc[t][dt] = (f32x4){0.f, 0.f, 0.f, 0.f};
#pragma unroll
  for (int kk = 0; kk < 2; ++kk) {
    f16x8 pa[2];
#pragma unroll
    for (int t = 0; t < 2; ++t)
      pa[t] = *(const f16x8*)&Ph[(wave * 32 + t * 16 + lr) * 76 + kk * 32 + kg * 8];
#pragma unroll
    for (int dt = 0; dt < 4; ++dt) {
      const f16x8 wh = *(const f16x8*)&W2Th[(dt * 16 + lr) * 76 + kk * 32 + kg * 8];
      const f16x8 wl = *(const f16x8*)&W2Tl[(dt * 16 + lr) * 76 + kk * 32 + kg * 8];
#pragma unroll
      for (int t = 0; t < 2; ++t) {
        oacc[t][dt] = __builtin_amdgcn_mfma_f32_16x16x32_f16(pa[t], wh, oacc[t][dt], 0, 0, 0);
        oacc[t][dt] = __builtin_amdgcn_mfma_f32_16x16x32_f16(pa[t], wl, oacc[t][dt], 0, 0, 0);
      }
    }
  }
  __syncthreads();

  float* O = (float*)smem;
#pragma unroll
  for (int t = 0; t < 2; ++t)
#pragma unroll
    for (int dt = 0; dt < 4; ++dt)
#pragma unroll
      for (int r = 0; r < 4; ++r) {
        const int row = wave * 32 + t * 16 + kg * 4 + r;
        O[row * 68 + dt * 16 + lr] = oacc[t][dt][r];
      }
  __syncthreads();

  const int d = tid & 63, rg = tid >> 6;
  const int rbase = s0 + rg * 32;
  const u16* Vd = Vh + (size_t)bh * S_ * 64 + d;

  float v[40];
#pragma unroll
  for (int j = 0; j < 40; ++j) {
    const int sv = rbase - 16 + j;
    v[j] = (sv >= 0 && sv < S_) ? h2f(Vd[(size_t)sv * 64]) : 0.f;
  }

#pragma clang loop unroll(disable)
  for (int c = 0; c < 4; ++c) {
#pragma unroll
    for (int rr = 0; rr < 8; ++rr) {
      float acc = 0.f;
#pragma unroll
      for (int t = 0; t < 33; ++t) acc += v[rr + t] * cws[t];
      const int row = rg * 32 + c * 8 + rr;
      const float oo = O[row * 68 + d] + acc;
      const size_t idx = ((size_t)(b * S_ + s0 + row)) * HID_ + h * 64 + d;
      const u16 hh = f2h_bits(oo);
      Xch[idx] = hh;
      Xcl[idx] = f2h_bits(oo - h2f(hh));
    }
    if (c < 3) {
#pragma unroll
      for (int j = 0; j < 32; ++j) v[j] = v[j + 8];
#pragma unroll
      for (int j = 0; j < 8; ++j) {
        const int sv = rbase + 24 + c * 8 + j;
        v[32 + j] = (sv >= 0 && sv < S_) ? h2f(Vd[(size_t)sv * 64]) : 0.f;
      }
    }
  }
}

// =============================================================
extern "C" void kernel_launch(void* const* d_in, const int* in_sizes, int n_in,
                              void* d_out, int out_size, void* d_ws, size_t ws_size,
                              hipStream_t stream)
{
  (void)in_sizes; (void)n_in; (void)out_size; (void)ws_size;
  const float* x      = (const float*)d_in[0];
  const float* qkv_w  = (const float*)d_in[1];
  const float* qkv_b  = (const float*)d_in[2];
  const float* conv_w = (const float*)d_in[3];
  const float* out_w  = (const float*)d_in[4];
  const float* out_b  = (const float*)d_in[5];
  float* out = (float*)d_out;

  float* ws = (float*)d_ws;
  u16* Qh = (u16*)ws;
  u16* Kh = Qh + 6291456;
  u16* Vh = Kh + 6291456;
  float* Ql = ws + 9437184;
  float* Kl = Ql + 98304;
  float* K2 = Kl + 98304;
  float* W2 = K2 + 98304;
  float* colmax = W2 + 98304;
  float* rowmax = colmax + 32;
  u16* Klh = (u16*)(rowmax + 32);
  float* nxt = rowmax + 32 + 49152;
  u16* Xh  = (u16*)nxt;
  u16* Xl  = Xh + 6291456;
  u16* Wqh = Xl + 6291456;
  u16* Woh = Wqh + 1769472;
  u16* Xch = Xh;
  u16* Xcl = Xl;
  float* Opart = (float*)Xh;
  float* mpart = (float*)Xl;
  float* lpart = mpart + BH_ * NCH_ * 64;

  split3<<<(N8X + N8WQ + N8WO + 255) / 256, 256, 0, stream>>>(
      x, qkv_w, out_w, Xh, Wqh, Woh);

  gemm_mfma<0, 1><<<dim3(36, 64), 256, 0, stream>>>(
      Xh, nullptr, Wqh, qkv_b, nullptr, Qh, Kh, Vh, Ql, Kl, Klh);

  kernel2_softmax<<<BH_, 256, 0, stream>>>(Ql, Kl, K2, colmax, rowmax);

  k3v_pass1<<<dim3(NCH_, BH_), 256, 0, stream>>>(Ql, Kh, Vh, Opart, mpart, lpart);

  newton_combine<<<BH_, 512, 0, stream>>>(K2, colmax, rowmax,
                                          Opart, mpart, lpart, W2);

  attn_conv_fused<<<dim3(NCH_, BH_), 256, 0, stream>>>(
      Qh, Klh, W2, Vh, conv_w, Xch, Xcl);

  gemm_mfma<1, 2><<<dim3(6, 128), 256, 0, stream>>>(
      Xch, Xcl, Woh, out_b, out, nullptr, nullptr, nullptr,
      nullptr, nullptr, nullptr);
}

// Round 13
// 212.277 us; speedup vs baseline: 1.3153x; 1.1254x over previous
//
#include <hip/hip_runtime.h>
#include <math.h>

#define B_   2
#define S_   4096
#define HID_ 768
#define H_   12
#define D_   64
#define M_   64
#define CK_  33
#define BH_  (B_*H_)   // 24
#define KD_  768
#define NCH_ 32        // S-chunks (128 rows each)
#define SC_  128       // keys per chunk

typedef float  f32x4  __attribute__((ext_vector_type(4)));
typedef _Float16 f16x8 __attribute__((ext_vector_type(8)));
typedef unsigned short u16;

__device__ __forceinline__ u16 f2h_bits(float f) {
  union { _Float16 h; u16 u; } c; c.h = (_Float16)f; return c.u;
}
__device__ __forceinline__ float h2f(u16 b) {
  union { _Float16 h; u16 u; } c; c.u = b; return (float)c.h;
}
__device__ __forceinline__ void cvt8_hl(const float4 a, const float4 b,
                                        f16x8* hi, f16x8* lo) {
  const float v[8] = {a.x, a.y, a.z, a.w, b.x, b.y, b.z, b.w};
  f16x8 H, L;
#pragma unroll
  for (int e = 0; e < 8; ++e) {
    const _Float16 hh = (_Float16)v[e];
    H[e] = hh;
    L[e] = (_Float16)(v[e] - (float)hh);
  }
  *hi = H; *lo = L;
}
// split write: v -> fp16 hi + fp16 residual
__device__ __forceinline__ void wsplit(u16* Hh, u16* Hl, int idx, float v) {
  const _Float16 hh = (_Float16)v;
  Hh[idx] = f2h_bits(v);
  Hl[idx] = f2h_bits(v - (float)hh);
}

__device__ __forceinline__ void gld16(const void* g, void* l) {
  __builtin_amdgcn_global_load_lds(
      (const __attribute__((address_space(1))) void*)g,
      (__attribute__((address_space(3))) void*)l, 16, 0, 0);
}

// =============================================================
// Downcast: x -> Xh, qkv_w -> Wqh, out_w -> Woh (fp16 hi only)
// =============================================================
#define N8X  786432
#define N8WQ 221184
#define N8WO 73728
__global__ __launch_bounds__(256) void split3(
    const float* __restrict__ x, const float* __restrict__ qkv_w,
    const float* __restrict__ out_w,
    u16* __restrict__ Xh, u16* __restrict__ Wqh, u16* __restrict__ Woh)
{
  const int i = blockIdx.x * 256 + threadIdx.x;
  const float* src; u16* dst; int j;
  if (i < N8X)                 { src = x;     dst = Xh;  j = i; }
  else if (i < N8X + N8WQ)     { src = qkv_w; dst = Wqh; j = i - N8X; }
  else if (i < N8X + N8WQ + N8WO) { src = out_w; dst = Woh; j = i - N8X - N8WQ; }
  else return;
  const float4 a = ((const float4*)src)[2 * j], b = ((const float4*)src)[2 * j + 1];
  const float v[8] = {a.x, a.y, a.z, a.w, b.x, b.y, b.z, b.w};
  union { u16 u[8]; uint4 q; } hv;
#pragma unroll
  for (int e = 0; e < 8; ++e) hv.u[e] = f2h_bits(v[e]);
  ((uint4*)dst)[j] = hv.q;
}

// =============================================================
// fp16 MFMA GEMM (unchanged from round 12)
// =============================================================
template<int MODE, int PROD>
__global__ __launch_bounds__(256) void gemm_mfma(
    const u16* __restrict__ Ahg, const u16* __restrict__ Alg,
    const u16* __restrict__ Bhg,
    const float* __restrict__ bias,
    float* __restrict__ oF, u16* __restrict__ oQ, u16* __restrict__ oK,
    u16* __restrict__ oV,
    float* __restrict__ Ql, float* __restrict__ Kl, u16* __restrict__ Klh)
{
  constexpr int BM = (MODE == 0) ? 128 : 64;
  constexpr int BN = (MODE == 0) ? 64 : 128;
  constexpr int NBX = (MODE == 0) ? 36 : 6;
  constexpr int WM = BM / 2, WN = BN / 2;
  constexpr int MF = WM / 16, NF = WN / 16;
  constexpr int AINST = BM / 64, BINST = BN / 64;
  constexpr int ABUF = BM * 32;
  constexpr int BUFSZ = ABUF * PROD + BN * 32;
  constexpr int NT = KD_ / 32;
  constexpr int NWG = NBX * (8192 / BM);
  constexpr int CPX = NWG / 8;
  constexpr int NLOADS = AINST * PROD + BINST;

  __shared__ __align__(16) u16 lds[2][BUFSZ];

  const int tid = threadIdx.x;
  const int lin = blockIdx.y * NBX + blockIdx.x;
  const int swb = (lin & 7) * CPX + (lin >> 3);
  const int m0 = (swb / NBX) * BM;
  const int n0 = (swb % NBX) * BN;

  const int wave = tid >> 6, lane = tid & 63;
  const int wm = wave >> 1, wn = wave & 1;
  const int lr = lane & 15, kg = lane >> 4;

  const int srow = tid >> 2;
  const int swz_s = (tid >> 3) & 3;
  const int sk = ((tid & 3) ^ swz_s) * 8;

  const u16* pAh = Ahg + (size_t)(m0 + srow) * KD_ + sk;
  const u16* pAl = (PROD == 2) ? (Alg + (size_t)(m0 + srow) * KD_ + sk) : nullptr;
  const u16* pBh = Bhg + (size_t)(n0 + srow) * KD_ + sk;

  f32x4 acc[MF][NF];
#pragma unroll
  for (int i = 0; i < MF; ++i)
#pragma unroll
    for (int j = 0; j < NF; ++j) acc[i][j] = (f32x4){0.f, 0.f, 0.f, 0.f};

  const int rsw = (lr >> 1) & 3;
  const int kq = (kg ^ rsw) * 8;
  const int abase = (wm * WM + lr) * 32 + kq;
  const int bbase = (wn * WN + lr) * 32 + kq;

#define STAGE_(buf, kt) do {                                              \
    const size_t go_ = (size_t)(kt) * 32;                                 \
    u16* L_ = &lds[buf][0];                                               \
    gld16(pAh + go_, L_ + tid * 8);                                       \
    if (AINST == 2) gld16(pAh + go_ + 64 * KD_, L_ + 2048 + tid * 8);     \
    if (PROD == 2) {                                                      \
      gld16(pAl + go_, L_ + ABUF + tid * 8);                              \
      if (AINST == 2) gld16(pAl + go_ + 64 * KD_, L_ + ABUF + 2048 + tid * 8); \
    }                                                                     \
    gld16(pBh + go_, L_ + ABUF * PROD + tid * 8);                         \
    if (BINST == 2) gld16(pBh + go_ + 64 * KD_, L_ + ABUF * PROD + 2048 + tid * 8); \
  } while (0)

  STAGE_(0, 0);

  int cur = 0;
  for (int kt = 0; kt < NT; ++kt) {
    if (kt + 1 < NT) {
      STAGE_(cur ^ 1, kt + 1);
      if constexpr (NLOADS == 3)
        asm volatile("s_waitcnt vmcnt(3)" ::: "memory");
      else
        asm volatile("s_waitcnt vmcnt(4)" ::: "memory");
    } else {
      asm volatile("s_waitcnt vmcnt(0)" ::: "memory");
    }
    __builtin_amdgcn_s_barrier();
    __builtin_amdgcn_sched_barrier(0);

    const u16* L_ = &lds[cur][0];
    f16x8 ah[MF], al[MF], bh[NF];
#pragma unroll
    for (int i = 0; i < MF; ++i) {
      ah[i] = *(const f16x8*)&L_[abase + i * 512];
      if (PROD == 2) al[i] = *(const f16x8*)&L_[ABUF + abase + i * 512];
    }
#pragma unroll
    for (int j = 0; j < NF; ++j)
      bh[j] = *(const f16x8*)&L_[ABUF * PROD + bbase + j * 512];
#pragma unroll
    for (int i = 0; i < MF; ++i)
#pragma unroll
      for (int j = 0; j < NF; ++j) {
        acc[i][j] = __builtin_amdgcn_mfma_f32_16x16x32_f16(ah[i], bh[j], acc[i][j], 0, 0, 0);
        if (PROD == 2)
          acc[i][j] = __builtin_amdgcn_mfma_f32_16x16x32_f16(al[i], bh[j], acc[i][j], 0, 0, 0);
      }

    __builtin_amdgcn_sched_barrier(0);
    __builtin_amdgcn_s_barrier();
    cur ^= 1;
  }
#undef STAGE_

  if (MODE == 0) {
    const int part = n0 / 768;
    const int h0 = (n0 - part * 768) >> 6;
    u16* base = (part == 0) ? oQ : ((part == 1) ? oK : oV);
#pragma unroll
    for (int i = 0; i < MF; ++i) {
      const int mbase = m0 + wm * WM + i * 16 + kg * 4;
#pragma unroll
      for (int j = 0; j < NF; ++j) {
        const int d = wn * WN + j * 16 + lr;
        const float bv = bias[n0 + d];
#pragma unroll
        for (int r = 0; r < 4; ++r) {
          const int row = mbase + r;
          const int b = row >> 12, s = row & (S_ - 1);
          base[(((size_t)(b * H_ + h0) * S_ + s) << 6) + d] = f2h_bits(acc[i][j][r] + bv);
        }
      }
    }
    if (part < 2) {
      const int rowseg = m0 + wm * WM;
      const int b = rowseg >> 12;
      const int seg = (rowseg & (S_ - 1)) >> 6;
      const int bhh = b * H_ + h0;
      float* dst = (part == 0) ? Ql : Kl;
#pragma unroll
      for (int j = 0; j < NF; ++j) {
        float sj = 0.f;
#pragma unroll
        for (int i = 0; i < MF; ++i)
#pragma unroll
          for (int r = 0; r < 4; ++r) sj += acc[i][j][r];
        sj += __shfl_xor(sj, 16);
        sj += __shfl_xor(sj, 32);
        if (kg == 0) {
          const int d = wn * WN + j * 16 + lr;
          const float lm = sj * (1.f / 64.f) + bias[n0 + d];
          dst[((size_t)bhh * M_ + seg) * 64 + d] = lm;
          if (part == 1) Klh[((size_t)bhh * M_ + seg) * 64 + d] = f2h_bits(lm);
        }
      }
    }
  } else {
#pragma unroll
    for (int i = 0; i < MF; ++i) {
      const int mbase = m0 + wm * WM + i * 16 + kg * 4;
#pragma unroll
      for (int j = 0; j < NF; ++j) {
        const int ncol = n0 + wn * WN + j * 16 + lr;
        const float bv = bias[ncol];
#pragma unroll
        for (int r = 0; r < 4; ++r) {
          const int row = mbase + r;
          oF[(size_t)row * HID_ + ncol] = acc[i][j][r] + bv;
        }
      }
    }
  }
}

// =============================================================
// kernel_2 softmax + per-(b,h) max col/row sums (unchanged)
// =============================================================
__global__ __launch_bounds__(256) void kernel2_softmax(
    const float* __restrict__ Ql, const float* __restrict__ Kl,
    float* __restrict__ K2, float* __restrict__ colmax, float* __restrict__ rowmax)
{
  __shared__ float Qs[64][68], Ks[64][68], S2[64][68];
  __shared__ float red1[64], red2[64];
  const int bh = blockIdx.x, tid = threadIdx.x;
  for (int idx = tid; idx < 4096; idx += 256) {
    const int r = idx >> 6, c = idx & 63;
    Qs[r][c] = Ql[(size_t)bh * 4096 + idx];
    Ks[r][c] = Kl[(size_t)bh * 4096 + idx];
  }
  __syncthreads();
  for (int idx = tid; idx < 4096; idx += 256) {
    const int r = idx >> 6, c = idx & 63;
    float dot = 0.f;
#pragma unroll
    for (int k = 0; k < 64; k += 4) {
      const float4 a = *(const float4*)&Qs[r][k];
      const float4 b = *(const float4*)&Ks[c][k];
      dot += a.x * b.x + a.y * b.y + a.z * b.z + a.w * b.w;
    }
    S2[r][c] = dot * 0.125f;
  }
  __syncthreads();
  if (tid < 64) {
    const int r = tid;
    float mx = -1e30f;
    for (int c = 0; c < 64; ++c) mx = fmaxf(mx, S2[r][c]);
    float sum = 0.f;
    for (int c = 0; c < 64; ++c) { const float e = expf(S2[r][c] - mx); S2[r][c] = e; sum += e; }
    const float inv = 1.f / sum;
    for (int c = 0; c < 64; ++c) S2[r][c] *= inv;
  }
  __syncthreads();
  for (int idx = tid; idx < 4096; idx += 256)
    K2[(size_t)bh * 4096 + idx] = S2[idx >> 6][idx & 63];
  if (tid < 64) {
    float cs = 0.f, rs = 0.f;
    for (int m = 0; m < 64; ++m) { cs += S2[m][tid]; rs += S2[tid][m]; }
    red1[tid] = cs; red2[tid] = rs;
  }
  __syncthreads();
  if (tid == 0) {
    float mc = 0.f, mr = 0.f;
    for (int i = 0; i < 64; ++i) { mc = fmaxf(mc, red1[i]); mr = fmaxf(mr, red2[i]); }
    colmax[bh] = mc; rowmax[bh] = mr;
  }
}

// =============================================================
// MFMA Newton-Schulz + combine + W2, one block per bh, 256 thr.
// All 64x64 matmuls on the matrix pipe via 3-product split fp16.
// LDS matrices stride 88 u16 (16B-aligned rows, ~2-way banks).
//   A-operand: row-split [m][k];  B-operand: transposed-split [n][k].
// Epilogues write the NEXT matmul's operand layout from C fragments.
// =============================================================
#define NST 88
__device__ __forceinline__ void mfma64x64(
    const u16* Ah, const u16* Al, const u16* Bh, const u16* Bl,
    int wave, int lr, int kg, f32x4 C[4])
{
#pragma unroll
  for (int j = 0; j < 4; ++j) C[j] = (f32x4){0.f, 0.f, 0.f, 0.f};
#pragma unroll
  for (int kk = 0; kk < 2; ++kk) {
    const int ao = (wave * 16 + lr) * NST + kk * 32 + kg * 8;
    const f16x8 ah = *(const f16x8*)&Ah[ao];
    const f16x8 al = *(const f16x8*)&Al[ao];
#pragma unroll
    for (int j = 0; j < 4; ++j) {
      const int bo = (j * 16 + lr) * NST + kk * 32 + kg * 8;
      const f16x8 bh = *(const f16x8*)&Bh[bo];
      const f16x8 bl = *(const f16x8*)&Bl[bo];
      C[j] = __builtin_amdgcn_mfma_f32_16x16x32_f16(ah, bh, C[j], 0, 0, 0);
      C[j] = __builtin_amdgcn_mfma_f32_16x16x32_f16(ah, bl, C[j], 0, 0, 0);
      C[j] = __builtin_amdgcn_mfma_f32_16x16x32_f16(al, bh, C[j], 0, 0, 0);
    }
  }
}

__global__ __launch_bounds__(256) void newton_combine(
    const float* __restrict__ K2, const float* __restrict__ colmax,
    const float* __restrict__ rowmax,
    const float* __restrict__ Opart, const float* __restrict__ mpart,
    const float* __restrict__ lpart, float* __restrict__ W2)
{
  __shared__ __align__(16) u16 K2h[64*NST], K2l[64*NST];   // also W1T overlay
  __shared__ __align__(16) u16 Vh_[64*NST], Vl_[64*NST];
  __shared__ __align__(16) u16 VTh[64*NST], VTl[64*NST];
  __shared__ __align__(16) u16 KVh[64*NST], KVl[64*NST];
  __shared__ __align__(16) u16 TTh[64*NST], TTl[64*NST];
  __shared__ float w_[64][33];
  __shared__ float scale_s;

  const int bh = blockIdx.x, tid = threadIdx.x;
  const int wave = tid >> 6, lane = tid & 63;
  const int lr = lane & 15, kg = lane >> 4;

  if (tid == 0) {
    float mc = 0.f, mr = 0.f;
    for (int i = 0; i < BH_; ++i) { mc = fmaxf(mc, colmax[i]); mr = fmaxf(mr, rowmax[i]); }
    scale_s = 1.f / (mc * mr);
  }
  __syncthreads();
  const float scale = scale_s;

  // setup: K2 row-split; V0 = s*K2^T  =>  VT = s*K2 (same layout), V = s*K2^T
  for (int idx = tid; idx < 4096; idx += 256) {
    const int r = idx >> 6, c = idx & 63;
    const float v = K2[(size_t)bh * 4096 + idx];
    wsplit(K2h, K2l, r * NST + c, v);
    const float sv = scale * v;
    wsplit(VTh, VTl, r * NST + c, sv);
    wsplit(Vh_, Vl_, c * NST + r, sv);
  }
  __syncthreads();

  f32x4 C[4];
  for (int it = 0; it < 6; ++it) {
    // mm1: KV = K2 @ V   (B = VT)
    mfma64x64(K2h, K2l, VTh, VTl, wave, lr, kg, C);
#pragma unroll
    for (int j = 0; j < 4; ++j)
#pragma unroll
      for (int r = 0; r < 4; ++r) {
        const int row = wave * 16 + kg * 4 + r, col = j * 16 + lr;
        const float kv = C[j][r];
        wsplit(KVh, KVl, row * NST + col, kv);
        wsplit(TTh, TTl, col * NST + row, (row == col ? 7.f : 0.f) - kv);
      }
    __syncthreads();
    // mm2: U1 = KV @ T1  (B = TT)
    mfma64x64(KVh, KVl, TTh, TTl, wave, lr, kg, C);
    __syncthreads();                      // all TT reads done before overwrite
#pragma unroll
    for (int j = 0; j < 4; ++j)
#pragma unroll
      for (int r = 0; r < 4; ++r) {
        const int row = wave * 16 + kg * 4 + r, col = j * 16 + lr;
        wsplit(TTh, TTl, col * NST + row, (row == col ? 15.f : 0.f) - C[j][r]);
      }
    __syncthreads();
    // mm3: U2 = KV @ T2
    mfma64x64(KVh, KVl, TTh, TTl, wave, lr, kg, C);
    __syncthreads();
#pragma unroll
    for (int j = 0; j < 4; ++j)
#pragma unroll
      for (int r = 0; r < 4; ++r) {
        const int row = wave * 16 + kg * 4 + r, col = j * 16 + lr;
        wsplit(TTh, TTl, col * NST + row, (row == col ? 13.f : 0.f) - C[j][r]);
      }
    __syncthreads();
    // mm4: V' = 0.25 * V @ T3
    mfma64x64(Vh_, Vl_, TTh, TTl, wave, lr, kg, C);
#pragma unroll
    for (int j = 0; j < 4; ++j)
#pragma unroll
      for (int r = 0; r < 4; ++r) {
        const int row = wave * 16 + kg * 4 + r, col = j * 16 + lr;
        const float v = 0.25f * C[j][r];
        wsplit(Vh_, Vl_, row * NST + col, v);
        wsplit(VTh, VTl, col * NST + row, v);
      }
    __syncthreads();
  }

  // combine: W1[m][d] = sum_j w[m][j] * Opart[j][m][d]; write W1^T split
  if (tid < 64) {
    const int m = tid;
    float Mx = -1e30f;
    for (int j = 0; j < NCH_; ++j)
      Mx = fmaxf(Mx, mpart[((size_t)bh * NCH_ + j) * 64 + m]);
    float denom = 0.f;
    for (int j = 0; j < NCH_; ++j)
      denom += expf(mpart[((size_t)bh * NCH_ + j) * 64 + m] - Mx) *
               lpart[((size_t)bh * NCH_ + j) * 64 + m];
    const float inv = 1.f / denom;
    for (int j = 0; j < NCH_; ++j)
      w_[m][j] = expf(mpart[((size_t)bh * NCH_ + j) * 64 + m] - Mx) * inv;
  }
  __syncthreads();
  u16* W1Th = K2h;                        // K2 dead -> overlay
  u16* W1Tl = K2l;
  {
    const int mg = tid >> 4, dq = (tid & 15) * 4;
#pragma unroll
    for (int i = 0; i < 4; ++i) {
      const int m = mg * 4 + i;
      float4 acc = make_float4(0.f, 0.f, 0.f, 0.f);
      for (int j = 0; j < NCH_; ++j) {
        const float ww = w_[m][j];
        const float4 o = *(const float4*)&Opart[(((size_t)bh * NCH_ + j) * 64 + m) * 64 + dq];
        acc.x += ww * o.x; acc.y += ww * o.y; acc.z += ww * o.z; acc.w += ww * o.w;
      }
      wsplit(W1Th, W1Tl, (dq + 0) * NST + m, acc.x);
      wsplit(W1Th, W1Tl, (dq + 1) * NST + m, acc.y);
      wsplit(W1Th, W1Tl, (dq + 2) * NST + m, acc.z);
      wsplit(W1Th, W1Tl, (dq + 3) * NST + m, acc.w);
    }
  }
  __syncthreads();
  // mm5: W2 = Vinv @ W1  (A = V row-split, B = W1T)
  mfma64x64(Vh_, Vl_, W1Th, W1Tl, wave, lr, kg, C);
#pragma unroll
  for (int j = 0; j < 4; ++j)
#pragma unroll
    for (int r = 0; r < 4; ++r) {
      const int row = wave * 16 + kg * 4 + r, col = j * 16 + lr;
      W2[(size_t)bh * 4096 + row * 64 + col] = C[j][r];
    }
}

// =============================================================
// k3v pass 1 (unchanged)
// =============================================================
__global__ __launch_bounds__(256) void k3v_pass1(
    const float* __restrict__ Ql, const u16* __restrict__ Kh,
    const u16* __restrict__ Vh, float* __restrict__ Opart,
    float* __restrict__ mpart, float* __restrict__ lpart)
{
  __shared__ float P[64][129];
  __shared__ float red1[64][4], red2[64][4];

  const int ch = blockIdx.x;
  const int bh = blockIdx.y;
  const int tid = threadIdx.x;
  const int wave = tid >> 6, lane = tid & 63;
  const int lr = lane & 15, kg = lane >> 4;

  const float* Qlb = Ql + (size_t)bh * 4096;
  const u16*   Kb  = Kh + (size_t)bh * S_ * 64;
  const u16*   Vb  = Vh + (size_t)bh * S_ * 64;

  f16x8 ah[4][2], al[4][2];
#pragma unroll
  for (int mt = 0; mt < 4; ++mt)
#pragma unroll
    for (int kk = 0; kk < 2; ++kk) {
      const float* qr = Qlb + (size_t)(mt * 16 + lr) * 64 + kk * 32 + kg * 8;
      cvt8_hl(*(const float4*)qr, *(const float4*)(qr + 4), &ah[mt][kk], &al[mt][kk]);
    }

#pragma unroll
  for (int t = 0; t < 2; ++t) {
    const int s0 = (wave * 2 + t) * 16;
    const int srow = ch * SC_ + s0 + lr;
    f32x4 acc[4];
#pragma unroll
    for (int mt = 0; mt < 4; ++mt) acc[mt] = (f32x4){0.f, 0.f, 0.f, 0.f};
#pragma unroll
    for (int kk = 0; kk < 2; ++kk) {
      const f16x8 bhf = *(const f16x8*)&Kb[(size_t)srow * 64 + kk * 32 + kg * 8];
#pragma unroll
      for (int mt = 0; mt < 4; ++mt) {
        acc[mt] = __builtin_amdgcn_mfma_f32_16x16x32_f16(ah[mt][kk], bhf, acc[mt], 0, 0, 0);
        acc[mt] = __builtin_amdgcn_mfma_f32_16x16x32_f16(al[mt][kk], bhf, acc[mt], 0, 0, 0);
      }
    }
#pragma unroll
    for (int mt = 0; mt < 4; ++mt)
#pragma unroll
      for (int r = 0; r < 4; ++r)
        P[mt * 16 + kg * 4 + r][s0 + lr] = acc[mt][r] * 0.125f;
  }
  __syncthreads();

  const int r = tid >> 2, q = tid & 3;
  {
    float mx = -1e30f;
#pragma unroll
    for (int s = 0; s < 32; ++s) mx = fmaxf(mx, P[r][q * 32 + s]);
    red1[r][q] = mx;
  }
  __syncthreads();
  const float rowmax = fmaxf(fmaxf(red1[r][0], red1[r][1]),
                             fmaxf(red1[r][2], red1[r][3]));
  {
    float sum = 0.f;
#pragma unroll
    for (int s = 0; s < 32; ++s) {
      const float e = expf(P[r][q * 32 + s] - rowmax);
      P[r][q * 32 + s] = e;
      sum += e;
    }
    red2[r][q] = sum;
  }
  __syncthreads();
  if (q == 0) {
    const float rowsum = red2[r][0] + red2[r][1] + red2[r][2] + red2[r][3];
    mpart[((size_t)bh * NCH_ + ch) * 64 + r] = rowmax;
    lpart[((size_t)bh * NCH_ + ch) * 64 + r] = rowsum;
  }

  const int mg = tid >> 4, dq = (tid & 15) * 4;
  float4 oacc[4];
#pragma unroll
  for (int i = 0; i < 4; ++i) oacc[i] = make_float4(0.f, 0.f, 0.f, 0.f);
  for (int s = 0; s < SC_; ++s) {
    const ushort4 vv = *(const ushort4*)&Vb[(size_t)(ch * SC_ + s) * 64 + dq];
    const float4 v = make_float4(h2f(vv.x), h2f(vv.y), h2f(vv.z), h2f(vv.w));
#pragma unroll
    for (int i = 0; i < 4; ++i) {
      const float p = P[mg * 4 + i][s];
      oacc[i].x += p * v.x; oacc[i].y += p * v.y;
      oacc[i].z += p * v.z; oacc[i].w += p * v.w;
    }
  }
#pragma unroll
  for (int i = 0; i < 4; ++i) {
    const size_t o = (((size_t)bh * NCH_ + ch) * 64 + mg * 4 + i) * 64 + dq;
    *(float4*)&Opart[o] = oacc[i];
  }
}

// =============================================================
// FUSED attention + conv v4 (unchanged)
// =============================================================
__global__ __launch_bounds__(256) void attn_conv_fused(
    const u16* __restrict__ Qh, const u16* __restrict__ Klh,
    const float* __restrict__ W2, const u16* __restrict__ Vh,
    const float* __restrict__ cw,
    u16* __restrict__ Xch, u16* __restrict__ Xcl)
{
  __shared__ __align__(16) u16 smem[19456];
  __shared__ float cws[33];

  const int ch = blockIdx.x;
  const int bh = blockIdx.y;
  const int tid = threadIdx.x;
  const int wave = tid >> 6, lane = tid & 63;
  const int lr = lane & 15, kg = lane >> 4;
  const int b = bh / H_, h = bh % H_;
  const int s0 = ch * 128;

  u16* Ph   = smem;
  u16* W2Th = smem + 9728;
  u16* W2Tl = smem + 14592;

  if (tid < 33) cws[tid] = cw[h * 33 + tid];
  for (int idx = tid; idx < 4096; idx += 256) {
    const int m = idx >> 6, d = idx & 63;
    const float w = W2[(size_t)bh * 4096 + idx];
    const _Float16 hh = (_Float16)w;
    W2Th[d * 76 + m] = f2h_bits(w);
    W2Tl[d * 76 + m] = f2h_bits(w - (float)hh);
  }

  const u16* Klb = Klh + (size_t)bh * 4096;
  const u16* Qb  = Qh + (size_t)bh * S_ * 64;
  f16x8 bf[4][2];
#pragma unroll
  for (int nt = 0; nt < 4; ++nt)
#pragma unroll
    for (int kk = 0; kk < 2; ++kk)
      bf[nt][kk] = *(const f16x8*)&Klb[(size_t)(nt * 16 + lr) * 64 + kk * 32 + kg * 8];

  f32x4 sacc[2][4];
#pragma unroll
  for (int t = 0; t < 2; ++t) {
#pragma unroll
    for (int nt = 0; nt < 4; ++nt) sacc[t][nt] = (f32x4){0.f, 0.f, 0.f, 0.f};
    const int rloc = wave * 32 + t * 16;
    f16x8 af[2];
#pragma unroll
    for (int kk = 0; kk < 2; ++kk)
      af[kk] = *(const f16x8*)&Qb[(size_t)(s0 + rloc + lr) * 64 + kk * 32 + kg * 8];
#pragma unroll
    for (int kk = 0; kk < 2; ++kk)
#pragma unroll
      for (int nt = 0; nt < 4; ++nt)
        sacc[t][nt] = __builtin_amdgcn_mfma_f32_16x16x32_f16(af[kk], bf[nt][kk], sacc[t][nt], 0, 0, 0);
  }

#pragma unroll
  for (int t = 0; t < 2; ++t)
#pragma unroll
    for (int nt = 0; nt < 4; ++nt)
      sacc[t][nt] *= 0.125f;

  float rinv[2][4];
#pragma unroll
  for (int t = 0; t < 2; ++t) {
#pragma unroll
    for (int r = 0; r < 4; ++r) {
      float mx = fmaxf(fmaxf(sacc[t][0][r], sacc[t][1][r]),
                       fmaxf(sacc[t][2][r], sacc[t][3][r]));
      mx = fmaxf(mx, __shfl_xor(mx, 1));
      mx = fmaxf(mx, __shfl_xor(mx, 2));
      mx = fmaxf(mx, __shfl_xor(mx, 4));
      mx = fmaxf(mx, __shfl_xor(mx, 8));
      float sum = 0.f;
#pragma unroll
      for (int nt = 0; nt < 4; ++nt) {
        const float e = expf(sacc[t][nt][r] - mx);
        sacc[t][nt][r] = e;
        sum += e;
      }
      sum += __shfl_xor(sum, 1);
      sum += __shfl_xor(sum, 2);
      sum += __shfl_xor(sum, 4);
      sum += __shfl_xor(sum, 8);
      rinv[t][r] = 1.f / sum;
    }
  }

#pragma unroll
  for (int t = 0; t < 2; ++t)
#pragma unroll
    for (int nt = 0; nt < 4; ++nt)
#pragma unroll
      for (int r = 0; r < 4; ++r) {
        const int row = wave * 32 + t * 16 + kg * 4 + r;
        Ph[row * 76 + nt * 16 + lr] = f2h_bits(sacc[t][nt][r] * rinv[t][r]);
      }
  __syncthreads();

  f32x4 oacc[2][4];
#pragma unroll
  for (int t = 0; t < 2; ++t)
#pragma unroll
    for (int dt = 0; dt < 4; ++dt) oacc[t][dt] = (f32x4){0.f, 0.f, 0.f, 0.f};
#pragma unroll
  for (int kk = 0; kk < 2; ++kk) {
    f16x8 pa[2];
#pragma unroll
    for (int t = 0; t < 2; ++t)
      pa[t] = *(const f16x8*)&Ph[(wave * 32 + t * 16 + lr) * 76 + kk * 32 + kg * 8];
#pragma unroll
    for (int dt = 0; dt < 4; ++dt) {
      const f16x8 wh = *(const f16x8*)&W2Th[(dt * 16 + lr) * 76 + kk * 32 + kg * 8];
      const f16x8 wl = *(const f16x8*)&W2Tl[(dt * 16 + lr) * 76 + kk * 32 + kg * 8];
#pragma unroll
      for (int t = 0; t < 2; ++t) {
        oacc[t][dt] = __builtin_amdgcn_mfma_f32_16x16x32_f16(pa[t], wh, oacc[t][dt], 0, 0, 0);
        oacc[t][dt] = __builtin_amdgcn_mfma_f32_16x16x32_f16(pa[t], wl, oacc[t][dt], 0, 0, 0);
      }
    }
  }
  __syncthreads();

  float* O = (float*)smem;
#pragma unroll
  for (int t = 0; t < 2; ++t)
#pragma unroll
    for (int dt = 0; dt < 4; ++dt)
#pragma unroll
      for (int r = 0; r < 4; ++r) {
        const int row = wave * 32 + t * 16 + kg * 4 + r;
        O[row * 68 + dt * 16 + lr] = oacc[t][dt][r];
      }
  __syncthreads();

  const int d = tid & 63, rg = tid >> 6;
  const int rbase = s0 + rg * 32;
  const u16* Vd = Vh + (size_t)bh * S_ * 64 + d;

  float v[40];
#pragma unroll
  for (int j = 0; j < 40; ++j) {
    const int sv = rbase - 16 + j;
    v[j] = (sv >= 0 && sv < S_) ? h2f(Vd[(size_t)sv * 64]) : 0.f;
  }

#pragma clang loop unroll(disable)
  for (int c = 0; c < 4; ++c) {
#pragma unroll
    for (int rr = 0; rr < 8; ++rr) {
      float acc = 0.f;
#pragma unroll
      for (int t = 0; t < 33; ++t) acc += v[rr + t] * cws[t];
      const int row = rg * 32 + c * 8 + rr;
      const float oo = O[row * 68 + d] + acc;
      const size_t idx = ((size_t)(b * S_ + s0 + row)) * HID_ + h * 64 + d;
      const u16 hh = f2h_bits(oo);
      Xch[idx] = hh;
      Xcl[idx] = f2h_bits(oo - h2f(hh));
    }
    if (c < 3) {
#pragma unroll
      for (int j = 0; j < 32; ++j) v[j] = v[j + 8];
#pragma unroll
      for (int j = 0; j < 8; ++j) {
        const int sv = rbase + 24 + c * 8 + j;
        v[32 + j] = (sv >= 0 && sv < S_) ? h2f(Vd[(size_t)sv * 64]) : 0.f;
      }
    }
  }
}

// =============================================================
extern "C" void kernel_launch(void* const* d_in, const int* in_sizes, int n_in,
                              void* d_out, int out_size, void* d_ws, size_t ws_size,
                              hipStream_t stream)
{
  (void)in_sizes; (void)n_in; (void)out_size; (void)ws_size;
  const float* x      = (const float*)d_in[0];
  const float* qkv_w  = (const float*)d_in[1];
  const float* qkv_b  = (const float*)d_in[2];
  const float* conv_w = (const float*)d_in[3];
  const float* out_w  = (const float*)d_in[4];
  const float* out_b  = (const float*)d_in[5];
  float* out = (float*)d_out;

  float* ws = (float*)d_ws;
  u16* Qh = (u16*)ws;
  u16* Kh = Qh + 6291456;
  u16* Vh = Kh + 6291456;
  float* Ql = ws + 9437184;
  float* Kl = Ql + 98304;
  float* K2 = Kl + 98304;
  float* W2 = K2 + 98304;
  float* colmax = W2 + 98304;
  float* rowmax = colmax + 32;
  u16* Klh = (u16*)(rowmax + 32);
  float* nxt = rowmax + 32 + 49152;
  u16* Xh  = (u16*)nxt;
  u16* Xl  = Xh + 6291456;
  u16* Wqh = Xl + 6291456;
  u16* Woh = Wqh + 1769472;
  u16* Xch = Xh;
  u16* Xcl = Xl;
  float* Opart = (float*)Xh;
  float* mpart = (float*)Xl;
  float* lpart = mpart + BH_ * NCH_ * 64;

  split3<<<(N8X + N8WQ + N8WO + 255) / 256, 256, 0, stream>>>(
      x, qkv_w, out_w, Xh, Wqh, Woh);

  gemm_mfma<0, 1><<<dim3(36, 64), 256, 0, stream>>>(
      Xh, nullptr, Wqh, qkv_b, nullptr, Qh, Kh, Vh, Ql, Kl, Klh);

  kernel2_softmax<<<BH_, 256, 0, stream>>>(Ql, Kl, K2, colmax, rowmax);

  k3v_pass1<<<dim3(NCH_, BH_), 256, 0, stream>>>(Ql, Kh, Vh, Opart, mpart, lpart);

  newton_combine<<<BH_, 256, 0, stream>>>(K2, colmax, rowmax,
                                          Opart, mpart, lpart, W2);

  attn_conv_fused<<<dim3(NCH_, BH_), 256, 0, stream>>>(
      Qh, Klh, W2, Vh, conv_w, Xch, Xcl);

  gemm_mfma<1, 2><<<dim3(6, 128), 256, 0, stream>>>(
      Xch, Xcl, Woh, out_b, out, nullptr, nullptr, nullptr,
      nullptr, nullptr, nullptr);
}

// Round 15
// 211.744 us; speedup vs baseline: 1.3186x; 1.0025x over previous
//
#include <hip/hip_runtime.h>
#include <math.h>

#define B_   2
#define S_   4096
#define HID_ 768
#define H_   12
#define D_   64
#define M_   64
#define CK_  33
#define BH_  (B_*H_)   // 24
#define KD_  768
#define NCH_ 32        // S-chunks (128 rows each)
#define SC_  128       // keys per chunk

typedef float  f32x4  __attribute__((ext_vector_type(4)));
typedef _Float16 f16x8 __attribute__((ext_vector_type(8)));
typedef unsigned short u16;

__device__ __forceinline__ u16 f2h_bits(float f) {
  union { _Float16 h; u16 u; } c; c.h = (_Float16)f; return c.u;
}
__device__ __forceinline__ float h2f(u16 b) {
  union { _Float16 h; u16 u; } c; c.u = b; return (float)c.h;
}
__device__ __forceinline__ void cvt8_hl(const float4 a, const float4 b,
                                        f16x8* hi, f16x8* lo) {
  const float v[8] = {a.x, a.y, a.z, a.w, b.x, b.y, b.z, b.w};
  f16x8 H, L;
#pragma unroll
  for (int e = 0; e < 8; ++e) {
    const _Float16 hh = (_Float16)v[e];
    H[e] = hh;
    L[e] = (_Float16)(v[e] - (float)hh);
  }
  *hi = H; *lo = L;
}
__device__ __forceinline__ void wsplit(u16* Hh, u16* Hl, int idx, float v) {
  const _Float16 hh = (_Float16)v;
  Hh[idx] = f2h_bits(v);
  Hl[idx] = f2h_bits(v - (float)hh);
}

__device__ __forceinline__ void gld16(const void* g, void* l) {
  __builtin_amdgcn_global_load_lds(
      (const __attribute__((address_space(1))) void*)g,
      (__attribute__((address_space(3))) void*)l, 16, 0, 0);
}

// =============================================================
// Downcast: x -> Xh, qkv_w -> Wqh, out_w -> Woh (fp16 hi only)
// =============================================================
#define N8X  786432
#define N8WQ 221184
#define N8WO 73728
__global__ __launch_bounds__(256) void split3(
    const float* __restrict__ x, const float* __restrict__ qkv_w,
    const float* __restrict__ out_w,
    u16* __restrict__ Xh, u16* __restrict__ Wqh, u16* __restrict__ Woh)
{
  const int i = blockIdx.x * 256 + threadIdx.x;
  const float* src; u16* dst; int j;
  if (i < N8X)                 { src = x;     dst = Xh;  j = i; }
  else if (i < N8X + N8WQ)     { src = qkv_w; dst = Wqh; j = i - N8X; }
  else if (i < N8X + N8WQ + N8WO) { src = out_w; dst = Woh; j = i - N8X - N8WQ; }
  else return;
  const float4 a = ((const float4*)src)[2 * j], b = ((const float4*)src)[2 * j + 1];
  const float v[8] = {a.x, a.y, a.z, a.w, b.x, b.y, b.z, b.w};
  union { u16 u[8]; uint4 q; } hv;
#pragma unroll
  for (int e = 0; e < 8; ++e) hv.u[e] = f2h_bits(v[e]);
  ((uint4*)dst)[j] = hv.q;
}

// =============================================================
// WAVE-AUTONOMOUS fp16 MFMA GEMM: C = A @ W^T (+bias)
// Block = 128x128 tile = 4 waves x private 64x64 tiles.
// Per-wave private dbuf LDS (A 64x32 + B 64x32 per buf) -> ZERO
// barriers; sync is per-wave counted s_waitcnt vmcnt(8) only.
// MODE 0: scatter Q/K/V fp16, fused landmarks (wave = 1 segment x 1 head).
// MODE 1: row-major f32 out.
// =============================================================
template<int MODE>
__global__ __launch_bounds__(256) void gemm_wave(
    const u16* __restrict__ Ahg, const u16* __restrict__ Bhg,
    const float* __restrict__ bias,
    float* __restrict__ oF, u16* __restrict__ oQ, u16* __restrict__ oK,
    u16* __restrict__ oV,
    float* __restrict__ Ql, float* __restrict__ Kl, u16* __restrict__ Klh)
{
  constexpr int NBX = (MODE == 0) ? 18 : 6;
  constexpr int NT  = KD_ / 32;             // 24
  constexpr int NWG = NBX * 64;
  constexpr int CPX = NWG / 8;

  __shared__ __align__(16) u16 lds[4][2][2][2048];  // [wave][buf][A,B][64x32]

  const int tid = threadIdx.x;
  const int lin = blockIdx.y * NBX + blockIdx.x;
  const int swb = (lin & 7) * CPX + (lin >> 3);     // XCD-contiguous chunks
  const int m0 = (swb / NBX) * 128;
  const int n0 = (swb % NBX) * 128;

  const int wave = tid >> 6, lane = tid & 63;
  const int wm = wave >> 1, wn = wave & 1;
  const int lr = lane & 15, kg = lane >> 4;

  // staging: inst i covers rows i*16 + (lane>>2); dest offset == lane*8.
  // source pre-swizzled: sk = (q ^ (row>>1)&3)*8 with (row>>1)&3 == (lane>>3)&3
  const int srow = lane >> 2;
  const int sk = ((lane & 3) ^ ((lane >> 3) & 3)) * 8;

  const u16* pA = Ahg + (size_t)(m0 + wm * 64 + srow) * KD_ + sk;
  const u16* pB = Bhg + (size_t)(n0 + wn * 64 + srow) * KD_ + sk;

  u16* wbase = &lds[wave][0][0][0];                 // buf stride 4096 u16

  f32x4 acc[4][4];
#pragma unroll
  for (int i = 0; i < 4; ++i)
#pragma unroll
    for (int j = 0; j < 4; ++j) acc[i][j] = (f32x4){0.f, 0.f, 0.f, 0.f};

  // fragment read: logical quad kg of row lr lives at phys quad kg ^ ((lr>>1)&3)
  const int kq = (kg ^ ((lr >> 1) & 3)) * 8;

#define WSTAGE_(buf, kt) do {                                   \
    const size_t go_ = (size_t)(kt) * 32;                       \
    u16* La_ = wbase + (buf) * 4096 + lane * 8;                 \
    u16* Lb_ = La_ + 2048;                                      \
    gld16(pA + go_,              La_);                          \
    gld16(pA + go_ + 16 * KD_,   La_ + 512);                    \
    gld16(pA + go_ + 32 * KD_,   La_ + 1024);                   \
    gld16(pA + go_ + 48 * KD_,   La_ + 1536);                   \
    gld16(pB + go_,              Lb_);                          \
    gld16(pB + go_ + 16 * KD_,   Lb_ + 512);                    \
    gld16(pB + go_ + 32 * KD_,   Lb_ + 1024);                   \
    gld16(pB + go_ + 48 * KD_,   Lb_ + 1536);                   \
  } while (0)

  WSTAGE_(0, 0);

  int cur = 0;
  for (int kt = 0; kt < NT; ++kt) {
    if (kt + 1 < NT) {
      WSTAGE_(cur ^ 1, kt + 1);
      asm volatile("s_waitcnt vmcnt(8)" ::: "memory");  // prev stage done; new in flight
    } else {
      asm volatile("s_waitcnt vmcnt(0)" ::: "memory");
    }
    __builtin_amdgcn_sched_barrier(0);

    const u16* Abuf = wbase + cur * 4096;
    const u16* Bbuf = Abuf + 2048;
    f16x8 af[4], bf[4];
#pragma unroll
    for (int i = 0; i < 4; ++i) af[i] = *(const f16x8*)&Abuf[(i * 16 + lr) * 32 + kq];
#pragma unroll
    for (int j = 0; j < 4; ++j) bf[j] = *(const f16x8*)&Bbuf[(j * 16 + lr) * 32 + kq];
#pragma unroll
    for (int i = 0; i < 4; ++i)
#pragma unroll
      for (int j = 0; j < 4; ++j)
        acc[i][j] = __builtin_amdgcn_mfma_f32_16x16x32_f16(af[i], bf[j], acc[i][j], 0, 0, 0);

    cur ^= 1;
  }
#undef WSTAGE_

  if (MODE == 0) {
    const int part = n0 / 768;
    const int within0 = n0 + wn * 64 - part * 768;
    const int h0 = within0 >> 6;
    u16* base = (part == 0) ? oQ : ((part == 1) ? oK : oV);
#pragma unroll
    for (int i = 0; i < 4; ++i) {
      const int mbase = m0 + wm * 64 + i * 16 + kg * 4;
#pragma unroll
      for (int j = 0; j < 4; ++j) {
        const int d = j * 16 + lr;
        const float bv = bias[n0 + wn * 64 + d];
#pragma unroll
        for (int r = 0; r < 4; ++r) {
          const int row = mbase + r;
          const int b = row >> 12, s = row & (S_ - 1);
          base[(((size_t)(b * H_ + h0) * S_ + s) << 6) + d] = f2h_bits(acc[i][j][r] + bv);
        }
      }
    }
    // landmarks: wave's 64 rows = one full segment of one (b, h0)
    if (part < 2) {
      const int rowseg = m0 + wm * 64;
      const int b = rowseg >> 12;
      const int seg = (rowseg & (S_ - 1)) >> 6;
      const int bhh = b * H_ + h0;
      float* dst = (part == 0) ? Ql : Kl;
#pragma unroll
      for (int j = 0; j < 4; ++j) {
        float sj = 0.f;
#pragma unroll
        for (int i = 0; i < 4; ++i)
#pragma unroll
          for (int r = 0; r < 4; ++r) sj += acc[i][j][r];
        sj += __shfl_xor(sj, 16);
        sj += __shfl_xor(sj, 32);
        if (kg == 0) {
          const int d = j * 16 + lr;
          const float lm = sj * (1.f / 64.f) + bias[n0 + wn * 64 + d];
          dst[((size_t)bhh * M_ + seg) * 64 + d] = lm;
          if (part == 1) Klh[((size_t)bhh * M_ + seg) * 64 + d] = f2h_bits(lm);
        }
      }
    }
  } else {
#pragma unroll
    for (int i = 0; i < 4; ++i) {
      const int mbase = m0 + wm * 64 + i * 16 + kg * 4;
#pragma unroll
      for (int j = 0; j < 4; ++j) {
        const int ncol = n0 + wn * 64 + j * 16 + lr;
        const float bv = bias[ncol];
#pragma unroll
        for (int r = 0; r < 4; ++r) {
          const int row = mbase + r;
          oF[(size_t)row * HID_ + ncol] = acc[i][j][r] + bv;
        }
      }
    }
  }
}

// =============================================================
// kernel_2 softmax + per-(b,h) max col/row sums (unchanged)
// =============================================================
__global__ __launch_bounds__(256) void kernel2_softmax(
    const float* __restrict__ Ql, const float* __restrict__ Kl,
    float* __restrict__ K2, float* __restrict__ colmax, float* __restrict__ rowmax)
{
  __shared__ float Qs[64][68], Ks[64][68], S2[64][68];
  __shared__ float red1[64], red2[64];
  const int bh = blockIdx.x, tid = threadIdx.x;
  for (int idx = tid; idx < 4096; idx += 256) {
    const int r = idx >> 6, c = idx & 63;
    Qs[r][c] = Ql[(size_t)bh * 4096 + idx];
    Ks[r][c] = Kl[(size_t)bh * 4096 + idx];
  }
  __syncthreads();
  for (int idx = tid; idx < 4096; idx += 256) {
    const int r = idx >> 6, c = idx & 63;
    float dot = 0.f;
#pragma unroll
    for (int k = 0; k < 64; k += 4) {
      const float4 a = *(const float4*)&Qs[r][k];
      const float4 b = *(const float4*)&Ks[c][k];
      dot += a.x * b.x + a.y * b.y + a.z * b.z + a.w * b.w;
    }
    S2[r][c] = dot * 0.125f;
  }
  __syncthreads();
  if (tid < 64) {
    const int r = tid;
    float mx = -1e30f;
    for (int c = 0; c < 64; ++c) mx = fmaxf(mx, S2[r][c]);
    float sum = 0.f;
    for (int c = 0; c < 64; ++c) { const float e = expf(S2[r][c] - mx); S2[r][c] = e; sum += e; }
    const float inv = 1.f / sum;
    for (int c = 0; c < 64; ++c) S2[r][c] *= inv;
  }
  __syncthreads();
  for (int idx = tid; idx < 4096; idx += 256)
    K2[(size_t)bh * 4096 + idx] = S2[idx >> 6][idx & 63];
  if (tid < 64) {
    float cs = 0.f, rs = 0.f;
    for (int m = 0; m < 64; ++m) { cs += S2[m][tid]; rs += S2[tid][m]; }
    red1[tid] = cs; red2[tid] = rs;
  }
  __syncthreads();
  if (tid == 0) {
    float mc = 0.f, mr = 0.f;
    for (int i = 0; i < 64; ++i) { mc = fmaxf(mc, red1[i]); mr = fmaxf(mr, red2[i]); }
    colmax[bh] = mc; rowmax[bh] = mr;
  }
}

// =============================================================
// MFMA Newton-Schulz + combine + W2 (unchanged from round 13)
// =============================================================
#define NST 88
__device__ __forceinline__ void mfma64x64(
    const u16* Ah, const u16* Al, const u16* Bh, const u16* Bl,
    int wave, int lr, int kg, f32x4 C[4])
{
#pragma unroll
  for (int j = 0; j < 4; ++j) C[j] = (f32x4){0.f, 0.f, 0.f, 0.f};
#pragma unroll
  for (int kk = 0; kk < 2; ++kk) {
    const int ao = (wave * 16 + lr) * NST + kk * 32 + kg * 8;
    const f16x8 ah = *(const f16x8*)&Ah[ao];
    const f16x8 al = *(const f16x8*)&Al[ao];
#pragma unroll
    for (int j = 0; j < 4; ++j) {
      const int bo = (j * 16 + lr) * NST + kk * 32 + kg * 8;
      const f16x8 bh = *(const f16x8*)&Bh[bo];
      const f16x8 bl = *(const f16x8*)&Bl[bo];
      C[j] = __builtin_amdgcn_mfma_f32_16x16x32_f16(ah, bh, C[j], 0, 0, 0);
      C[j] = __builtin_amdgcn_mfma_f32_16x16x32_f16(ah, bl, C[j], 0, 0, 0);
      C[j] = __builtin_amdgcn_mfma_f32_16x16x32_f16(al, bh, C[j], 0, 0, 0);
    }
  }
}

__global__ __launch_bounds__(256) void newton_combine(
    const float* __restrict__ K2, const float* __restrict__ colmax,
    const float* __restrict__ rowmax,
    const float* __restrict__ Opart, const float* __restrict__ mpart,
    const float* __restrict__ lpart, float* __restrict__ W2)
{
  __shared__ __align__(16) u16 K2h[64*NST], K2l[64*NST];
  __shared__ __align__(16) u16 Vh_[64*NST], Vl_[64*NST];
  __shared__ __align__(16) u16 VTh[64*NST], VTl[64*NST];
  __shared__ __align__(16) u16 KVh[64*NST], KVl[64*NST];
  __shared__ __align__(16) u16 TTh[64*NST], TTl[64*NST];
  __shared__ float w_[64][33];
  __shared__ float scale_s;

  const int bh = blockIdx.x, tid = threadIdx.x;
  const int wave = tid >> 6, lane = tid & 63;
  const int lr = lane & 15, kg = lane >> 4;

  if (tid == 0) {
    float mc = 0.f, mr = 0.f;
    for (int i = 0; i < BH_; ++i) { mc = fmaxf(mc, colmax[i]); mr = fmaxf(mr, rowmax[i]); }
    scale_s = 1.f / (mc * mr);
  }
  __syncthreads();
  const float scale = scale_s;

  for (int idx = tid; idx < 4096; idx += 256) {
    const int r = idx >> 6, c = idx & 63;
    const float v = K2[(size_t)bh * 4096 + idx];
    wsplit(K2h, K2l, r * NST + c, v);
    const float sv = scale * v;
    wsplit(VTh, VTl, r * NST + c, sv);
    wsplit(Vh_, Vl_, c * NST + r, sv);
  }
  __syncthreads();

  f32x4 C[4];
  for (int it = 0; it < 6; ++it) {
    mfma64x64(K2h, K2l, VTh, VTl, wave, lr, kg, C);
#pragma unroll
    for (int j = 0; j < 4; ++j)
#pragma unroll
      for (int r = 0; r < 4; ++r) {
        const int row = wave * 16 + kg * 4 + r, col = j * 16 + lr;
        const float kv = C[j][r];
        wsplit(KVh, KVl, row * NST + col, kv);
        wsplit(TTh, TTl, col * NST + row, (row == col ? 7.f : 0.f) - kv);
      }
    __syncthreads();
    mfma64x64(KVh, KVl, TTh, TTl, wave, lr, kg, C);
    __syncthreads();
#pragma unroll
    for (int j = 0; j < 4; ++j)
#pragma unroll
      for (int r = 0; r < 4; ++r) {
        const int row = wave * 16 + kg * 4 + r, col = j * 16 + lr;
        wsplit(TTh, TTl, col * NST + row, (row == col ? 15.f : 0.f) - C[j][r]);
      }
    __syncthreads();
    mfma64x64(KVh, KVl, TTh, TTl, wave, lr, kg, C);
    __syncthreads();
#pragma unroll
    for (int j = 0; j < 4; ++j)
#pragma unroll
      for (int r = 0; r < 4; ++r) {
        const int row = wave * 16 + kg * 4 + r, col = j * 16 + lr;
        wsplit(TTh, TTl, col * NST + row, (row == col ? 13.f : 0.f) - C[j][r]);
      }
    __syncthreads();
    mfma64x64(Vh_, Vl_, TTh, TTl, wave, lr, kg, C);
#pragma unroll
    for (int j = 0; j < 4; ++j)
#pragma unroll
      for (int r = 0; r < 4; ++r) {
        const int row = wave * 16 + kg * 4 + r, col = j * 16 + lr;
        const float v = 0.25f * C[j][r];
        wsplit(Vh_, Vl_, row * NST + col, v);
        wsplit(VTh, VTl, col * NST + row, v);
      }
    __syncthreads();
  }

  if (tid < 64) {
    const int m = tid;
    float Mx = -1e30f;
    for (int j = 0; j < NCH_; ++j)
      Mx = fmaxf(Mx, mpart[((size_t)bh * NCH_ + j) * 64 + m]);
    float denom = 0.f;
    for (int j = 0; j < NCH_; ++j)
      denom += expf(mpart[((size_t)bh * NCH_ + j) * 64 + m] - Mx) *
               lpart[((size_t)bh * NCH_ + j) * 64 + m];
    const float inv = 1.f / denom;
    for (int j = 0; j < NCH_; ++j)
      w_[m][j] = expf(mpart[((size_t)bh * NCH_ + j) * 64 + m] - Mx) * inv;
  }
  __syncthreads();
  u16* W1Th = K2h;
  u16* W1Tl = K2l;
  {
    const int mg = tid >> 4, dq = (tid & 15) * 4;
#pragma unroll
    for (int i = 0; i < 4; ++i) {
      const int m = mg * 4 + i;
      float4 acc = make_float4(0.f, 0.f, 0.f, 0.f);
      for (int j = 0; j < NCH_; ++j) {
        const float ww = w_[m][j];
        const float4 o = *(const float4*)&Opart[(((size_t)bh * NCH_ + j) * 64 + m) * 64 + dq];
        acc.x += ww * o.x; acc.y += ww * o.y; acc.z += ww * o.z; acc.w += ww * o.w;
      }
      wsplit(W1Th, W1Tl, (dq + 0) * NST + m, acc.x);
      wsplit(W1Th, W1Tl, (dq + 1) * NST + m, acc.y);
      wsplit(W1Th, W1Tl, (dq + 2) * NST + m, acc.z);
      wsplit(W1Th, W1Tl, (dq + 3) * NST + m, acc.w);
    }
  }
  __syncthreads();
  mfma64x64(Vh_, Vl_, W1Th, W1Tl, wave, lr, kg, C);
#pragma unroll
  for (int j = 0; j < 4; ++j)
#pragma unroll
    for (int r = 0; r < 4; ++r) {
      const int row = wave * 16 + kg * 4 + r, col = j * 16 + lr;
      W2[(size_t)bh * 4096 + row * 64 + col] = C[j][r];
    }
}

// =============================================================
// k3v pass 1 (unchanged)
// =============================================================
__global__ __launch_bounds__(256) void k3v_pass1(
    const float* __restrict__ Ql, const u16* __restrict__ Kh,
    const u16* __restrict__ Vh, float* __restrict__ Opart,
    float* __restrict__ mpart, float* __restrict__ lpart)
{
  __shared__ float P[64][129];
  __shared__ float red1[64][4], red2[64][4];

  const int ch = blockIdx.x;
  const int bh = blockIdx.y;
  const int tid = threadIdx.x;
  const int wave = tid >> 6, lane = tid & 63;
  const int lr = lane & 15, kg = lane >> 4;

  const float* Qlb = Ql + (size_t)bh * 4096;
  const u16*   Kb  = Kh + (size_t)bh * S_ * 64;
  const u16*   Vb  = Vh + (size_t)bh * S_ * 64;

  f16x8 ah[4][2], al[4][2];
#pragma unroll
  for (int mt = 0; mt < 4; ++mt)
#pragma unroll
    for (int kk = 0; kk < 2; ++kk) {
      const float* qr = Qlb + (size_t)(mt * 16 + lr) * 64 + kk * 32 + kg * 8;
      cvt8_hl(*(const float4*)qr, *(const float4*)(qr + 4), &ah[mt][kk], &al[mt][kk]);
    }

#pragma unroll
  for (int t = 0; t < 2; ++t) {
    const int s0 = (wave * 2 + t) * 16;
    const int srow = ch * SC_ + s0 + lr;
    f32x4 acc[4];
#pragma unroll
    for (int mt = 0; mt < 4; ++mt) acc[mt] = (f32x4){0.f, 0.f, 0.f, 0.f};
#pragma unroll
    for (int kk = 0; kk < 2; ++kk) {
      const f16x8 bhf = *(const f16x8*)&Kb[(size_t)srow * 64 + kk * 32 + kg * 8];
#pragma unroll
      for (int mt = 0; mt < 4; ++mt) {
        acc[mt] = __builtin_amdgcn_mfma_f32_16x16x32_f16(ah[mt][kk], bhf, acc[mt], 0, 0, 0);
        acc[mt] = __builtin_amdgcn_mfma_f32_16x16x32_f16(al[mt][kk], bhf, acc[mt], 0, 0, 0);
      }
    }
#pragma unroll
    for (int mt = 0; mt < 4; ++mt)
#pragma unroll
      for (int r = 0; r < 4; ++r)
        P[mt * 16 + kg * 4 + r][s0 + lr] = acc[mt][r] * 0.125f;
  }
  __syncthreads();

  const int r = tid >> 2, q = tid & 3;
  {
    float mx = -1e30f;
#pragma unroll
    for (int s = 0; s < 32; ++s) mx = fmaxf(mx, P[r][q * 32 + s]);
    red1[r][q] = mx;
  }
  __syncthreads();
  const float rowmax = fmaxf(fmaxf(red1[r][0], red1[r][1]),
                             fmaxf(red1[r][2], red1[r][3]));
  {
    float sum = 0.f;
#pragma unroll
    for (int s = 0; s < 32; ++s) {
      const float e = expf(P[r][q * 32 + s] - rowmax);
      P[r][q * 32 + s] = e;
      sum += e;
    }
    red2[r][q] = sum;
  }
  __syncthreads();
  if (q == 0) {
    const float rowsum = red2[r][0] + red2[r][1] + red2[r][2] + red2[r][3];
    mpart[((size_t)bh * NCH_ + ch) * 64 + r] = rowmax;
    lpart[((size_t)bh * NCH_ + ch) * 64 + r] = rowsum;
  }

  const int mg = tid >> 4, dq = (tid & 15) * 4;
  float4 oacc[4];
#pragma unroll
  for (int i = 0; i < 4; ++i) oacc[i] = make_float4(0.f, 0.f, 0.f, 0.f);
  for (int s = 0; s < SC_; ++s) {
    const ushort4 vv = *(const ushort4*)&Vb[(size_t)(ch * SC_ + s) * 64 + dq];
    const float4 v = make_float4(h2f(vv.x), h2f(vv.y), h2f(vv.z), h2f(vv.w));
#pragma unroll
    for (int i = 0; i < 4; ++i) {
      const float p = P[mg * 4 + i][s];
      oacc[i].x += p * v.x; oacc[i].y += p * v.y;
      oacc[i].z += p * v.z; oacc[i].w += p * v.w;
    }
  }
#pragma unroll
  for (int i = 0; i < 4; ++i) {
    const size_t o = (((size_t)bh * NCH_ + ch) * 64 + mg * 4 + i) * 64 + dq;
    *(float4*)&Opart[o] = oacc[i];
  }
}

// =============================================================
// FUSED attention + conv v4 (Xcl write dropped: out-GEMM is 1-product)
// =============================================================
__global__ __launch_bounds__(256) void attn_conv_fused(
    const u16* __restrict__ Qh, const u16* __restrict__ Klh,
    const float* __restrict__ W2, const u16* __restrict__ Vh,
    const float* __restrict__ cw, u16* __restrict__ Xch)
{
  __shared__ __align__(16) u16 smem[19456];
  __shared__ float cws[33];

  const int ch = blockIdx.x;
  const int bh = blockIdx.y;
  const int tid = threadIdx.x;
  const int wave = tid >> 6, lane = tid & 63;
  const int lr = lane & 15, kg = lane >> 4;
  const int b = bh / H_, h = bh % H_;
  const int s0 = ch * 128;

  u16* Ph   = smem;
  u16* W2Th = smem + 9728;
  u16* W2Tl = smem + 14592;

  if (tid < 33) cws[tid] = cw[h * 33 + tid];
  for (int idx = tid; idx < 4096; idx += 256) {
    const int m = idx >> 6, d = idx & 63;
    const float w = W2[(size_t)bh * 4096 + idx];
    const _Float16 hh = (_Float16)w;
    W2Th[d * 76 + m] = f2h_bits(w);
    W2Tl[d * 76 + m] = f2h_bits(w - (float)hh);
  }

  const u16* Klb = Klh + (size_t)bh * 4096;
  const u16* Qb  = Qh + (size_t)bh * S_ * 64;
  f16x8 bf[4][2];
#pragma unroll
  for (int nt = 0; nt < 4; ++nt)
#pragma unroll
    for (int kk = 0; kk < 2; ++kk)
      bf[nt][kk] = *(const f16x8*)&Klb[(size_t)(nt * 16 + lr) * 64 + kk * 32 + kg * 8];

  f32x4 sacc[2][4];
#pragma unroll
  for (int t = 0; t < 2; ++t) {
#pragma unroll
    for (int nt = 0; nt < 4; ++nt) sacc[t][nt] = (f32x4){0.f, 0.f, 0.f, 0.f};
    const int rloc = wave * 32 + t * 16;
    f16x8 af[2];
#pragma unroll
    for (int kk = 0; kk < 2; ++kk)
      af[kk] = *(const f16x8*)&Qb[(size_t)(s0 + rloc + lr) * 64 + kk * 32 + kg * 8];
#pragma unroll
    for (int kk = 0; kk < 2; ++kk)
#pragma unroll
      for (int nt = 0; nt < 4; ++nt)
        sacc[t][nt] = __builtin_amdgcn_mfma_f32_16x16x32_f16(af[kk], bf[nt][kk], sacc[t][nt], 0, 0, 0);
  }

#pragma unroll
  for (int t = 0; t < 2; ++t)
#pragma unroll
    for (int nt = 0; nt < 4; ++nt)
      sacc[t][nt] *= 0.125f;

  float rinv[2][4];
#pragma unroll
  for (int t = 0; t < 2; ++t) {
#pragma unroll
    for (int r = 0; r < 4; ++r) {
      float mx = fmaxf(fmaxf(sacc[t][0][r], sacc[t][1][r]),
                       fmaxf(sacc[t][2][r], sacc[t][3][r]));
      mx = fmaxf(mx, __shfl_xor(mx, 1));
      mx = fmaxf(mx, __shfl_xor(mx, 2));
      mx = fmaxf(mx, __shfl_xor(mx, 4));
      mx = fmaxf(mx, __shfl_xor(mx, 8));
      float sum = 0.f;
#pragma unroll
      for (int nt = 0; nt < 4; ++nt) {
        const float e = expf(sacc[t][nt][r] - mx);
        sacc[t][nt][r] = e;
        sum += e;
      }
      sum += __shfl_xor(sum, 1);
      sum += __shfl_xor(sum, 2);
      sum += __shfl_xor(sum, 4);
      sum += __shfl_xor(sum, 8);
      rinv[t][r] = 1.f / sum;
    }
  }

#pragma unroll
  for (int t = 0; t < 2; ++t)
#pragma unroll
    for (int nt = 0; nt < 4; ++nt)
#pragma unroll
      for (int r = 0; r < 4; ++r) {
        const int row = wave * 32 + t * 16 + kg * 4 + r;
        Ph[row * 76 + nt * 16 + lr] = f2h_bits(sacc[t][nt][r] * rinv[t][r]);
      }
  __syncthreads();

  f32x4 oacc[2][4];
#pragma unroll
  for (int t = 0; t < 2; ++t)
#pragma unroll
    for (int dt = 0; dt < 4; ++dt) oacc[t][dt] = (f32x4){0.f, 0.f, 0.f, 0.f};
#pragma unroll
  for (int kk = 0; kk < 2; ++kk) {
    f16x8 pa[2];
#pragma unroll
    for (int t = 0; t < 2; ++t)
      pa[t] = *(const f16x8*)&Ph[(wave * 32 + t * 16 + lr) * 76 + kk * 32 + kg * 8];
#pragma unroll
    for (int dt = 0; dt < 4; ++dt) {
      const f16x8 wh = *(const f16x8*)&W2Th[(dt * 16 + lr) * 76 + kk * 32 + kg * 8];
      const f16x8 wl = *(const f16x8*)&W2Tl[(dt * 16 + lr) * 76 + kk * 32 + kg * 8];
#pragma unroll
      for (int t = 0; t < 2; ++t) {
        oacc[t][dt] = __builtin_amdgcn_mfma_f32_16x16x32_f16(pa[t], wh, oacc[t][dt], 0, 0, 0);
        oacc[t][dt] = __builtin_amdgcn_mfma_f32_16x16x32_f16(pa[t], wl, oacc[t][dt], 0, 0, 0);
      }
    }
  }
  __syncthreads();

  float* O = (float*)smem;
#pragma unroll
  for (int t = 0; t < 2; ++t)
#pragma unroll
    for (int dt = 0; dt < 4; ++dt)
#pragma unroll
      for (int r = 0; r < 4; ++r) {
        const int row = wave * 32 + t * 16 + kg * 4 + r;
        O[row * 68 + dt * 16 + lr] = oacc[t][dt][r];
      }
  __syncthreads();

  const int d = tid & 63, rg = tid >> 6;
  const int rbase = s0 + rg * 32;
  const u16* Vd = Vh + (size_t)bh * S_ * 64 + d;

  float v[40];
#pragma unroll
  for (int j = 0; j < 40; ++j) {
    const int sv = rbase - 16 + j;
    v[j] = (sv >= 0 && sv < S_) ? h2f(Vd[(size_t)sv * 64]) : 0.f;
  }

#pragma clang loop unroll(disable)
  for (int c = 0; c < 4; ++c) {
#pragma unroll
    for (int rr = 0; rr < 8; ++rr) {
      float acc = 0.f;
#pragma unroll
      for (int t = 0; t < 33; ++t) acc += v[rr + t] * cws[t];
      const int row = rg * 32 + c * 8 + rr;
      const float oo = O[row * 68 + d] + acc;
      const size_t idx = ((size_t)(b * S_ + s0 + row)) * HID_ + h * 64 + d;
      Xch[idx] = f2h_bits(oo);
    }
    if (c < 3) {
#pragma unroll
      for (int j = 0; j < 32; ++j) v[j] = v[j + 8];
#pragma unroll
      for (int j = 0; j < 8; ++j) {
        const int sv = rbase + 24 + c * 8 + j;
        v[32 + j] = (sv >= 0 && sv < S_) ? h2f(Vd[(size_t)sv * 64]) : 0.f;
      }
    }
  }
}

// =============================================================
extern "C" void kernel_launch(void* const* d_in, const int* in_sizes, int n_in,
                              void* d_out, int out_size, void* d_ws, size_t ws_size,
                              hipStream_t stream)
{
  (void)in_sizes; (void)n_in; (void)out_size; (void)ws_size;
  const float* x      = (const float*)d_in[0];
  const float* qkv_w  = (const float*)d_in[1];
  const float* qkv_b  = (const float*)d_in[2];
  const float* conv_w = (const float*)d_in[3];
  const float* out_w  = (const float*)d_in[4];
  const float* out_b  = (const float*)d_in[5];
  float* out = (float*)d_out;

  float* ws = (float*)d_ws;
  u16* Qh = (u16*)ws;
  u16* Kh = Qh + 6291456;
  u16* Vh = Kh + 6291456;
  float* Ql = ws + 9437184;
  float* Kl = Ql + 98304;
  float* K2 = Kl + 98304;
  float* W2 = K2 + 98304;
  float* colmax = W2 + 98304;
  float* rowmax = colmax + 32;
  u16* Klh = (u16*)(rowmax + 32);
  float* nxt = rowmax + 32 + 49152;
  u16* Xh  = (u16*)nxt;
  u16* Xl  = Xh + 6291456;
  u16* Wqh = Xl + 6291456;
  u16* Woh = Wqh + 1769472;
  u16* Xch = Xh;
  float* Opart = (float*)Xh;
  float* mpart = (float*)Xl;
  float* lpart = mpart + BH_ * NCH_ * 64;

  split3<<<(N8X + N8WQ + N8WO + 255) / 256, 256, 0, stream>>>(
      x, qkv_w, out_w, Xh, Wqh, Woh);

  gemm_wave<0><<<dim3(18, 64), 256, 0, stream>>>(
      Xh, Wqh, qkv_b, nullptr, Qh, Kh, Vh, Ql, Kl, Klh);

  kernel2_softmax<<<BH_, 256, 0, stream>>>(Ql, Kl, K2, colmax, rowmax);

  k3v_pass1<<<dim3(NCH_, BH_), 256, 0, stream>>>(Ql, Kh, Vh, Opart, mpart, lpart);

  newton_combine<<<BH_, 256, 0, stream>>>(K2, colmax, rowmax,
                                          Opart, mpart, lpart, W2);

  attn_conv_fused<<<dim3(NCH_, BH_), 256, 0, stream>>>(
      Qh, Klh, W2, Vh, conv_w, Xch);

  gemm_wave<1><<<dim3(6, 64), 256, 0, stream>>>(
      Xch, Woh, out_b, out, nullptr, nullptr, nullptr,
      nullptr, nullptr, nullptr);
}